// Round 9
// baseline (1316.679 us; speedup 1.0000x reference)
//
#include <hip/hip_runtime.h>

#define NN 50000
#define NE 400000
#define NT 300000
#define NQ 200000
#define DM 256
#define FIN 128
#define NRBF 40
#define BETA_RBF 40.0f
#define TOTALP 397569

#define WSWZ_N (56 * 16 * 64 * 8)  // 458752 u16 swizzled-weight elements (out GEMM)
#define PSWZ_N (4 * 2 * 4 * 16 * 64 * 8)  // 262144 u16 swizzled proj weights

// fused-pass batching: consecutive nodes per wave, ~64 edges/batch
#define NPB1 8
#define NPB2 8
#define NPB3 16
#define NBT1 (NN / NPB1)          // 6250
#define NBT2 (NN / NPB2)          // 6250
#define NBT3 (NN / NPB3)          // 3125
#define NBT (NBT1 + NBT2 + NBT3)  // 15625

typedef unsigned int u32;
typedef unsigned short u16;
typedef __attribute__((ext_vector_type(8))) short bf16x8;
typedef __attribute__((ext_vector_type(4))) float f32x4;

// ---- bf16 helpers ----
static __device__ __forceinline__ float bf2f(u16 h) {
  return __uint_as_float(((u32)h) << 16);
}
static __device__ __forceinline__ u16 f2bf(float f) {
  u32 u = __float_as_uint(f);
  u32 r = (u + 0x7FFFu + ((u >> 16) & 1u)) >> 16;  // RNE
  return (u16)r;
}
static __device__ __forceinline__ float4 ld4f(const float* p) {
  return *reinterpret_cast<const float4*>(p);
}
static __device__ __forceinline__ float ldsc(const void* p, int isf, size_t i) {
  return isf ? ((const float*)p)[i] : bf2f(((const u16*)p)[i]);
}
static __device__ __forceinline__ float lk(float t) { return t >= 0.f ? t : 0.2f * t; }
static __device__ __forceinline__ u32 f2o(float f) {
  u32 u = __float_as_uint(f);
  return (u & 0x80000000u) ? ~u : (u | 0x80000000u);
}

struct F3 { float x, y, z; };
static __device__ __forceinline__ F3 ldp(const float* pos, int i) {
  return F3{pos[3 * i], pos[3 * i + 1], pos[3 * i + 2]};
}
static __device__ __forceinline__ F3 sub3(F3 a, F3 b) { return F3{a.x - b.x, a.y - b.y, a.z - b.z}; }
static __device__ __forceinline__ float dot3(F3 a, F3 b) { return a.x * b.x + a.y * b.y + a.z * b.z; }
static __device__ __forceinline__ F3 cross3(F3 a, F3 b) {
  return F3{a.y * b.z - a.z * b.y, a.z * b.x - a.x * b.z, a.x * b.y - a.y * b.x};
}
static __device__ __forceinline__ float norm3(F3 v) { return sqrtf(dot3(v, v) + 1e-12f); }
static __device__ __forceinline__ float angle_at(F3 a, F3 m, F3 b) {
  F3 u = sub3(a, m), v = sub3(b, m);
  float c = dot3(u, v) / (norm3(u) * norm3(v) + 1e-12f);
  c = fminf(fmaxf(c, -1.f + 1e-7f), 1.f - 1e-7f);
  return acosf(c);
}
static __device__ __forceinline__ float dihedral_f(F3 p0, F3 p1, F3 p2, F3 p3) {
  F3 b1 = sub3(p1, p0), b2 = sub3(p2, p1), b3 = sub3(p3, p2);
  F3 n1 = cross3(b1, b2), n2 = cross3(b2, b3);
  float nb2 = norm3(b2) + 1e-12f;
  F3 b2n{b2.x / nb2, b2.y / nb2, b2.z / nb2};
  F3 m1 = cross3(n1, b2n);
  return atan2f(dot3(m1, n2), dot3(n1, n2) + 1e-12f);
}

// phase A: scalar RBF window + 8 coefficients for ONE edge (per lane).
static __device__ __forceinline__ int rbf_coef(float d, float* c) {
  int j = (int)floorf(d * 4.0f) - 3;
  j = (j < 0) ? 0 : ((j > NRBF - 8) ? (NRBF - 8) : j);
  float t0 = d - 0.25f * (float)j;
#pragma unroll
  for (int k = 0; k < 8; ++k) {
    float t = t0 - 0.25f * (float)k;
    c[k] = __expf(-BETA_RBF * t * t);
  }
  return j;
}

// phase B with PRELOADED Wu rows (registers): identical FMA order to original.
static __device__ __forceinline__ float4 rbf_apply_r(const float4* w,
                                                     float4 c0, float4 c1, float4 dm) {
  dm.x = fmaf(c0.x, w[0].x, dm.x); dm.y = fmaf(c0.x, w[0].y, dm.y);
  dm.z = fmaf(c0.x, w[0].z, dm.z); dm.w = fmaf(c0.x, w[0].w, dm.w);
  dm.x = fmaf(c0.y, w[1].x, dm.x); dm.y = fmaf(c0.y, w[1].y, dm.y);
  dm.z = fmaf(c0.y, w[1].z, dm.z); dm.w = fmaf(c0.y, w[1].w, dm.w);
  dm.x = fmaf(c0.z, w[2].x, dm.x); dm.y = fmaf(c0.z, w[2].y, dm.y);
  dm.z = fmaf(c0.z, w[2].z, dm.z); dm.w = fmaf(c0.z, w[2].w, dm.w);
  dm.x = fmaf(c0.w, w[3].x, dm.x); dm.y = fmaf(c0.w, w[3].y, dm.y);
  dm.z = fmaf(c0.w, w[3].z, dm.z); dm.w = fmaf(c0.w, w[3].w, dm.w);
  dm.x = fmaf(c1.x, w[4].x, dm.x); dm.y = fmaf(c1.x, w[4].y, dm.y);
  dm.z = fmaf(c1.x, w[4].z, dm.z); dm.w = fmaf(c1.x, w[4].w, dm.w);
  dm.x = fmaf(c1.y, w[5].x, dm.x); dm.y = fmaf(c1.y, w[5].y, dm.y);
  dm.z = fmaf(c1.y, w[5].z, dm.z); dm.w = fmaf(c1.y, w[5].w, dm.w);
  dm.x = fmaf(c1.z, w[6].x, dm.x); dm.y = fmaf(c1.z, w[6].y, dm.y);
  dm.z = fmaf(c1.z, w[6].z, dm.z); dm.w = fmaf(c1.z, w[6].w, dm.w);
  dm.x = fmaf(c1.w, w[7].x, dm.x); dm.y = fmaf(c1.w, w[7].y, dm.y);
  dm.z = fmaf(c1.w, w[7].z, dm.z); dm.w = fmaf(c1.w, w[7].w, dm.w);
  return dm;
}

static __device__ __forceinline__ ushort4 g512(const u16* p, int idx, int c4) {
  return *reinterpret_cast<const ushort4*>(p + (size_t)(u32)idx * DM + c4);
}
static __device__ __forceinline__ float4 cvt4(ushort4 v) {
  return float4{bf2f(v.x), bf2f(v.y), bf2f(v.z), bf2f(v.w)};
}

// param staging table: 30 tensors, cumulative offsets
__device__ const int g_off[31] = {
  0, 32768, 65536, 98304, 131072, 131584, 131840, 142080, 142336, 152576,
  152832, 163072, 163328, 163840, 164096, 165632, 165888, 231424, 231680,
  297216, 297472, 363008, 363264, 363520, 363776, 364032, 396800, 397056,
  397312, 397568, 397569};
struct PtrTab { const void* p[30]; };

// ---- init ----
__global__ __launch_bounds__(256) void init_detect(const u32* __restrict__ aw,
                                                   const u32* __restrict__ lng,
                                                   u32* __restrict__ gmax,
                                                   int* __restrict__ flags) {
  __shared__ int s_int, s_f32, s_bf;
  if (threadIdx.x == 0) { s_int = 1; s_f32 = 1; s_bf = 1; }
  __syncthreads();
  int li = 1, lf = 1, lb = 1;
  for (int i = threadIdx.x; i < 1024; i += 256) {
    u32 w = aw[i];
    if (w > 1u) li = 0;
    if (w != 0u && w != 0x3F800000u) lf = 0;
    u32 h0 = w & 0xFFFFu, h1 = w >> 16;
    if ((h0 != 0u && h0 != 0x3F80u) || (h1 != 0u && h1 != 0x3F80u)) lb = 0;
  }
  if (!li) atomicAnd(&s_int, 0);
  if (!lf) atomicAnd(&s_f32, 0);
  if (!lb) atomicAnd(&s_bf, 0);
  __syncthreads();
  if (threadIdx.x == 0) {
    flags[0] = s_int ? 0 : (s_f32 ? 2 : (s_bf ? 3 : 1));
    flags[1] = ((lng[0] & 0xFFFFu) == 0x3F80u) ? 0 : 1;  // 1 = fp32 inputs
    gmax[0] = f2o(-INFINITY);
    gmax[1] = f2o(-INFINITY);
    gmax[2] = f2o(-INFINITY);
    gmax[3] = 0u;  // fused-pass work-steal counter
  }
}

__global__ __launch_bounds__(256) void convert_params(PtrTab tab,
                                                      const int* __restrict__ flags,
                                                      float* __restrict__ dst) {
  const int isf = flags[1];
  for (int i = blockIdx.x * blockDim.x + threadIdx.x; i < TOTALP;
       i += gridDim.x * blockDim.x) {
    int t = 0;
    while (i >= g_off[t + 1]) ++t;
    dst[i] = ldsc(tab.p[t], isf, i - g_off[t]);
  }
}
__global__ __launch_bounds__(256) void convert_pos(const void* __restrict__ pos,
                                                   const int* __restrict__ flags,
                                                   float* __restrict__ posf) {
  const int isf = flags[1];
  for (int i = blockIdx.x * blockDim.x + threadIdx.x; i < NN * 3;
       i += gridDim.x * blockDim.x)
    posf[i] = ldsc(pos, isf, i);
}

static __device__ __forceinline__ int read_eattr(const void* p, int flag, int e) {
  if (flag == 1) return ((const unsigned char*)p)[e];
  if (flag == 2) return (((const float*)p)[e] != 0.f);
  if (flag == 3) return (((const u16*)p)[e] != 0);
  return ((const int*)p)[e];
}

// ---- weight swizzle for output-GEMM MFMA B-fragments ----
__global__ __launch_bounds__(256) void swizzle_w(const float* __restrict__ fp,
                                                 u16* __restrict__ wswz) {
  int idx = blockIdx.x * 256 + threadIdx.x;
  if (idx >= WSWZ_N) return;
  int jj = idx & 7;
  int lane = (idx >> 3) & 63;
  int nb = (idx >> 9) & 15;
  int s = idx >> 13;
  int kl = (lane >> 4) * 8 + jj;
  int col = nb * 16 + (lane & 15);
  float w;
  int lo;
  if (s < 48) {
    int sr = (s < 24) ? s : (s - 24);
    lo = (s >= 24);
    int K = sr * 32 + kl;
    int base = (K < 256) ? 165888 : ((K < 512) ? 231680 : 297472);
    w = fp[base + (K & 255) * 256 + col];
  } else {
    int sr = (s < 52) ? (s - 48) : (s - 52);
    lo = (s >= 52);
    int K = sr * 32 + kl;
    w = fp[364032 + K * 256 + col];
  }
  u16 hi = f2bf(w);
  wswz[idx] = lo ? f2bf(w - bf2f(hi)) : hi;
}

// ---- projection weight swizzle: 4 mats (src,mid2,mid1,dst) x hi/lo x K=128 ----
__global__ __launch_bounds__(256) void swizzle_pw(const float* __restrict__ fp,
                                                  u16* __restrict__ pswz) {
  int idx = blockIdx.x * 256 + threadIdx.x;
  if (idx >= PSWZ_N) return;
  int jj = idx & 7;
  int lane = (idx >> 3) & 63;
  int nb = (idx >> 9) & 15;
  int ks = (idx >> 13) & 3;
  int hilo = (idx >> 15) & 1;
  int mat = idx >> 16;
  const int mb[4] = {0, 98304, 65536, 32768};  // W_src, W_mid2, W_mid1, W_dst
  int K = ks * 32 + (lane >> 4) * 8 + jj;
  int col = nb * 16 + (lane & 15);
  float w = fp[mb[mat] + K * 256 + col];
  u16 hi = f2bf(w);
  pswz[idx] = hilo ? f2bf(w - bf2f(hi)) : hi;
}

// ---- x hi/lo split into Xs[NN][256] (cols 0..127 hi, 128..255 lo) ----
__global__ __launch_bounds__(256) void xsplit(const void* __restrict__ x,
                                              const int* __restrict__ flags,
                                              u16* __restrict__ Xs) {
  const int isf = flags[1];
  for (int i = blockIdx.x * blockDim.x + threadIdx.x; i < NN * FIN;
       i += gridDim.x * blockDim.x) {
    int n = i >> 7, k = i & 127;
    float v = ldsc(x, isf, i);
    u16 hi = f2bf(v);
    Xs[(size_t)n * 256 + k] = hi;
    Xs[(size_t)n * 256 + 128 + k] = f2bf(v - bf2f(hi));
  }
}

// ---- MFMA 4-way projection + sinusoidal PE ----
__global__ __launch_bounds__(256) void proj_mfma(
    const u16* __restrict__ Xs, const u16* __restrict__ pswz,
    u16* __restrict__ o0, u16* __restrict__ o1,
    u16* __restrict__ o2, u16* __restrict__ o3) {
  const int tid = threadIdx.x;
  const int wid = tid >> 6, lane = tid & 63;
  const int g = lane >> 4, l15 = lane & 15;
  const int m0 = blockIdx.x * 32;
  const int cb = wid * 64;

  int rr0 = m0 + l15; if (rr0 > NN - 1) rr0 = NN - 1;
  int rr1 = m0 + 16 + l15; if (rr1 > NN - 1) rr1 = NN - 1;
  const u16* x0p = Xs + (size_t)rr0 * 256 + g * 8;
  const u16* x1p = Xs + (size_t)rr1 * 256 + g * 8;

  bf16x8 xh0[4], xh1[4], xl0[4], xl1[4];
#pragma unroll
  for (int ks = 0; ks < 4; ++ks) {
    xh0[ks] = *reinterpret_cast<const bf16x8*>(x0p + ks * 32);
    xh1[ks] = *reinterpret_cast<const bf16x8*>(x1p + ks * 32);
    xl0[ks] = *reinterpret_cast<const bf16x8*>(x0p + 128 + ks * 32);
    xl1[ks] = *reinterpret_cast<const bf16x8*>(x1p + 128 + ks * 32);
  }

  u16* const outs[4] = {o0, o1, o2, o3};
#pragma unroll 1
  for (int mat = 0; mat < 4; ++mat) {
    f32x4 acc[2][4];
#pragma unroll
    for (int nf = 0; nf < 4; ++nf) {
      int c = cb + nf * 16 + l15;
      float dv = expf(-logf(10000.f) * (float)(c & ~1) / 256.f);
      float ang = (float)mat * dv;
      float p = (c & 1) ? cosf(ang) : sinf(ang);
      acc[0][nf] = f32x4{p, p, p, p};
      acc[1][nf] = f32x4{p, p, p, p};
    }
    const u16* wbm = pswz + (size_t)mat * 65536 + (size_t)lane * 8;
#pragma unroll
    for (int ks = 0; ks < 4; ++ks) {
#pragma unroll
      for (int nf = 0; nf < 4; ++nf) {
        const u16* bbase = wbm + (size_t)ks * 8192 + (wid * 4 + nf) * 512;
        bf16x8 bh = *reinterpret_cast<const bf16x8*>(bbase);
        bf16x8 bl = *reinterpret_cast<const bf16x8*>(bbase + 32768);
        acc[0][nf] = __builtin_amdgcn_mfma_f32_16x16x32_bf16(xh0[ks], bh, acc[0][nf], 0, 0, 0);
        acc[1][nf] = __builtin_amdgcn_mfma_f32_16x16x32_bf16(xh1[ks], bh, acc[1][nf], 0, 0, 0);
        acc[0][nf] = __builtin_amdgcn_mfma_f32_16x16x32_bf16(xh0[ks], bl, acc[0][nf], 0, 0, 0);
        acc[1][nf] = __builtin_amdgcn_mfma_f32_16x16x32_bf16(xh1[ks], bl, acc[1][nf], 0, 0, 0);
        acc[0][nf] = __builtin_amdgcn_mfma_f32_16x16x32_bf16(xl0[ks], bh, acc[0][nf], 0, 0, 0);
        acc[1][nf] = __builtin_amdgcn_mfma_f32_16x16x32_bf16(xl1[ks], bh, acc[1][nf], 0, 0, 0);
      }
    }
    u16* op = outs[mat];
#pragma unroll
    for (int nf = 0; nf < 4; ++nf) {
      int c = cb + nf * 16 + l15;
#pragma unroll
      for (int mf = 0; mf < 2; ++mf) {
#pragma unroll
        for (int reg = 0; reg < 4; ++reg) {
          int row = m0 + mf * 16 + g * 4 + reg;
          if (row < NN) op[(size_t)row * 256 + c] = f2bf(acc[mf][nf][reg]);
        }
      }
    }
  }
}

// ---- fused CSR build over the 3 hops ----
__global__ __launch_bounds__(256) void hist_all(const int* __restrict__ ed,
                                                const int* __restrict__ td,
                                                const int* __restrict__ qd,
                                                int* __restrict__ deg) {
  const int M = NE + NT + NQ;
  for (int i = blockIdx.x * blockDim.x + threadIdx.x; i < M; i += gridDim.x * blockDim.x) {
    if (i < NE) atomicAdd(&deg[ed[i]], 1);
    else if (i < NE + NT) atomicAdd(&deg[NN + td[i - NE]], 1);
    else atomicAdd(&deg[2 * NN + qd[i - NE - NT]], 1);
  }
}
__global__ __launch_bounds__(1024) void scan_all(const int* __restrict__ degall,
                                                 int* __restrict__ offall,
                                                 int* __restrict__ curall) {
  __shared__ int part[1024];
  const int b = blockIdx.x;
  const int* deg = degall + (size_t)b * NN;
  int* off = offall + (size_t)b * (NN + 1);
  int* cur = curall + (size_t)b * NN;
  const int CH = (NN + 1023) / 1024;
  const int t = threadIdx.x;
  const int base = t * CH;
  int s = 0;
  for (int i = 0; i < CH; ++i) { int idx = base + i; if (idx < NN) s += deg[idx]; }
  part[t] = s;
  __syncthreads();
  for (int d = 1; d < 1024; d <<= 1) {
    int v = (t >= d) ? part[t - d] : 0;
    __syncthreads();
    part[t] += v;
    __syncthreads();
  }
  int run = (t == 0) ? 0 : part[t - 1];
  for (int i = 0; i < CH; ++i) {
    int idx = base + i;
    if (idx < NN) { off[idx] = run; cur[idx] = run; run += deg[idx]; }
  }
  if (t == 1023) off[NN] = run;
}
__global__ __launch_bounds__(256) void fill_all(const int* __restrict__ ed,
                                                const int* __restrict__ td,
                                                const int* __restrict__ qd,
                                                int* __restrict__ cur,
                                                int* __restrict__ eid) {
  const int M = NE + NT + NQ;
  for (int i = blockIdx.x * blockDim.x + threadIdx.x; i < M; i += gridDim.x * blockDim.x) {
    if (i < NE) {
      int p = atomicAdd(&cur[ed[i]], 1);
      eid[p] = i;
    } else if (i < NE + NT) {
      int il = i - NE;
      int p = atomicAdd(&cur[NN + td[il]], 1);
      eid[NE + p] = il;
    } else {
      int il = i - NE - NT;
      int p = atomicAdd(&cur[2 * NN + qd[il]], 1);
      eid[NE + NT + p] = il;
    }
  }
}

// finalize current node's online-softmax state into Abuf, reset state
#define FINALIZE(node, hopoff)                                         \
  {                                                                    \
    float inv = 1.f / (den + 1e-16f);                                  \
    ushort4 o;                                                         \
    o.x = f2bf(acc.x * inv); o.y = f2bf(acc.y * inv);                  \
    o.z = f2bf(acc.z * inv); o.w = f2bf(acc.w * inv);                  \
    *reinterpret_cast<ushort4*>(Abuf + (size_t)(node) * 768 +          \
                                (hopoff) + c4) = o;                    \
    den = 0.f; mrun = -INFINITY;                                       \
    acc = float4{0.f, 0.f, 0.f, 0.f};                                  \
  }

// ---- fused score + per-node softmax + aggregate, node-batched ----
// Phase B pipeline: depth-2 for feature gathers, depth-1 REGISTER prefetch for
// the 8 Wu rows (wave-uniform row index). Wu loads are issued BEFORE the
// gathers within each iteration so that, under vmcnt's FIFO semantics, the
// wait for Wu(e) does NOT drain the in-flight gather prefetches.
__global__ __launch_bounds__(64) void fused_score_agg(
    const float* __restrict__ pos,
    const int* __restrict__ eidx, const int* __restrict__ tdx, const int* __restrict__ qdx,
    const void* __restrict__ eattr, const int* __restrict__ flags,
    const u16* __restrict__ p_src, const u16* __restrict__ p_mid2,
    const u16* __restrict__ p_mid1, const u16* __restrict__ p_dst,
    const float* __restrict__ fp,
    const int* __restrict__ offall, const int* __restrict__ eidall,
    u32* __restrict__ gmax, u16* __restrict__ Abuf) {
  __shared__ __align__(16) float slds[64 * 20];
  const int lane = threadIdx.x & 63;
  float* sw = slds;
  const int c4 = lane * 4;
  const int flag = flags[0];

  for (int it = 0; it <= NBT; ++it) {
    u32 bl = 0;
    if (lane == 0) bl = atomicAdd(gmax + 3, 1u);
    u32 b = (u32)__builtin_amdgcn_readfirstlane((int)bl);
    if (b >= NBT) break;

    if (b < NBT1) {
      // ================= hop 1: 8 nodes/batch =================
      const int n0 = (int)b * NPB1;
      const int* offp = offall;
      const int* eidp = eidall;
      int offreg = offp[n0 + ((lane <= NPB1) ? lane : NPB1)];
      const int gs = __shfl(offreg, 0, 64);
      const int ge = __shfl(offreg, NPB1, 64);
      const float* Wu = fp + 131840;
      float4 av = ld4f(fp + 363264 + c4);
      float4 bbv = ld4f(fp + 131584 + c4), buv = ld4f(fp + 142080 + c4);
      float4 bsum{bbv.x + buv.x, bbv.y + buv.y, bbv.z + buv.z, bbv.w + buv.w};
      float4 wb0 = ld4f(fp + 131072 + c4), wb1 = ld4f(fp + 131072 + DM + c4);
      int kcur = 0;
      float mrun = -INFINITY, den = 0.f;
      float4 acc{0.f, 0.f, 0.f, 0.f};
      for (int cb = gs; cb < ge; cb += 64) {
        const int cl = (ge - cb < 64) ? (ge - cb) : 64;
        const int idx = cb + lane;
        int k = 0;
#pragma unroll
        for (int kk = 1; kk < NPB1; ++kk) {
          int v = __shfl(offreg, kk, 64);
          if (idx >= v) k = kk;
        }
        if (lane < cl) {  // phase A
          int e = eidp[idx];
          int es = eidx[e];
          int ea = read_eattr(eattr, flag, e);
          F3 Ps = ldp(pos, es), Pd = ldp(pos, n0 + k);
          float d1 = norm3(sub3(Ps, Pd));
          float c[8]; int j = 0; float f0, f1;
          if (ea) {
            float dc = fminf(fmaxf(d1, 0.05f), 10.f);
            j = rbf_coef(dc, c);
            f0 = 0.f; f1 = 0.f;
          } else {
#pragma unroll
            for (int kk = 0; kk < 8; ++kk) c[kk] = 0.f;
            f0 = d1; f1 = d1 * d1;
          }
          float* sp = sw + lane * 20;
          *reinterpret_cast<int4*>(sp) = int4{es, ea, j, k};
          *reinterpret_cast<float4*>(sp + 4) = float4{c[0], c[1], c[2], c[3]};
          *reinterpret_cast<float4*>(sp + 8) = float4{c[4], c[5], c[6], c[7]};
          *reinterpret_cast<float4*>(sp + 12) = float4{f0, f1, 0.f, 0.f};
        }
        // phase B (depth-2 gathers + depth-1 register Wu prefetch)
        int4 I0{0, 0, 0, 0}, I1{0, 0, 0, 0};
        ushort4 gm0{0, 0, 0, 0}, gdd0{0, 0, 0, 0}, gm1{0, 0, 0, 0}, gdd1{0, 0, 0, 0};
        if (cl > 0) {
          I0 = *reinterpret_cast<const int4*>(sw);
          gm0 = g512(p_mid1, I0.x, c4);
          gdd0 = g512(p_dst, n0 + I0.w, c4);
        }
        if (cl > 1) {
          I1 = *reinterpret_cast<const int4*>(sw + 20);
          gm1 = g512(p_mid1, I1.x, c4);
          gdd1 = g512(p_dst, n0 + I1.w, c4);
        }
        float4 wu[8];
        {
          const float* wbase = Wu + I0.z * DM + c4;
#pragma unroll
          for (int kk = 0; kk < 8; ++kk) wu[kk] = ld4f(wbase + kk * DM);
        }
#pragma unroll 1
        for (int e = 0; e < cl; ++e) {
          int4 I2{0, 0, 0, 0};
          ushort4 gm2{0, 0, 0, 0}, gdd2{0, 0, 0, 0};
          if (e + 2 < cl) I2 = *reinterpret_cast<const int4*>(sw + (e + 2) * 20);
          // Wu prefetch for e+1 — issued BEFORE the e+2 gathers
          float4 wuN[8];
          {
            const float* wbase = Wu + I1.z * DM + c4;
#pragma unroll
            for (int kk = 0; kk < 8; ++kk) wuN[kk] = ld4f(wbase + kk * DM);
          }
          if (e + 2 < cl) {
            gm2 = g512(p_mid1, I2.x, c4);
            gdd2 = g512(p_dst, n0 + I2.w, c4);
          }
          while (kcur < I0.w) { FINALIZE(n0 + kcur, 0); ++kcur; }
          const float* sp = sw + e * 20;
          float4 dm = bsum;
          if (I0.y) {
            float4 cc0 = *reinterpret_cast<const float4*>(sp + 4);
            float4 cc1 = *reinterpret_cast<const float4*>(sp + 8);
            dm = rbf_apply_r(wu, cc0, cc1, dm);
          } else {
            float4 f = *reinterpret_cast<const float4*>(sp + 12);
            dm.x = fmaf(f.x, wb0.x, fmaf(f.y, wb1.x, dm.x));
            dm.y = fmaf(f.x, wb0.y, fmaf(f.y, wb1.y, dm.y));
            dm.z = fmaf(f.x, wb0.z, fmaf(f.y, wb1.z, dm.z));
            dm.w = fmaf(f.x, wb0.w, fmaf(f.y, wb1.w, dm.w));
          }
          float4 mv = cvt4(gm0), dd = cvt4(gdd0);
          float t0 = lk((mv.x + dd.x) * dm.x);
          float t1 = lk((mv.y + dd.y) * dm.y);
          float t2 = lk((mv.z + dd.z) * dm.z);
          float t3 = lk((mv.w + dd.w) * dm.w);
          float part = av.x * t0 + av.y * t1 + av.z * t2 + av.w * t3;
          part += __shfl_xor(part, 1, 64);
          part += __shfl_xor(part, 2, 64);
          part += __shfl_xor(part, 4, 64);
          float mn = fmaxf(mrun, part);
          float r = __expf(mrun - mn);
          float ew = __expf(part - mn);
          den = den * r + ew;
          acc.x = fmaf(acc.x, r, ew * mv.x);
          acc.y = fmaf(acc.y, r, ew * mv.y);
          acc.z = fmaf(acc.z, r, ew * mv.z);
          acc.w = fmaf(acc.w, r, ew * mv.w);
          mrun = mn;
          I0 = I1; gm0 = gm1; gdd0 = gdd1;
          I1 = I2; gm1 = gm2; gdd1 = gdd2;
#pragma unroll
          for (int kk = 0; kk < 8; ++kk) wu[kk] = wuN[kk];
        }
      }
      while (kcur < NPB1) { FINALIZE(n0 + kcur, 0); ++kcur; }
    } else if (b < NBT1 + NBT2) {
      // ================= hop 2: 8 nodes/batch =================
      const int n0 = ((int)b - NBT1) * NPB2;
      const int* offp = offall + (NN + 1);
      const int* eidp = eidall + NE;
      int offreg = offp[n0 + ((lane <= NPB2) ? lane : NPB2)];
      const int gs = __shfl(offreg, 0, 64);
      const int ge = __shfl(offreg, NPB2, 64);
      const float* Wu1 = fp + 142336;
      float4 av = ld4f(fp + 363520 + c4);
      float4 b1v = ld4f(fp + 152576 + c4), b2v = ld4f(fp + 163840 + c4);
      float4 bsum{b1v.x + b2v.x, b1v.y + b2v.y, b1v.z + b2v.z, b1v.w + b2v.w};
      float4 wa0 = ld4f(fp + 163328 + c4), wa1 = ld4f(fp + 163328 + DM + c4);
      int kcur = 0;
      float mrun = -INFINITY, den = 0.f;
      float4 acc{0.f, 0.f, 0.f, 0.f};
      for (int cb = gs; cb < ge; cb += 64) {
        const int cl = (ge - cb < 64) ? (ge - cb) : 64;
        const int idx = cb + lane;
        int k = 0;
#pragma unroll
        for (int kk = 1; kk < NPB2; ++kk) {
          int v = __shfl(offreg, kk, 64);
          if (idx >= v) k = kk;
        }
        if (lane < cl) {  // phase A
          int t = eidp[idx];
          int ts = tdx[t], tm = tdx[NT + t];
          F3 Ps = ldp(pos, ts), Pm = ldp(pos, tm), Pd = ldp(pos, n0 + k);
          float d2 = fminf(fmaxf(norm3(sub3(Ps, Pd)), 0.05f), 10.f);
          float c[8];
          int j = rbf_coef(d2, c);
          float ang = angle_at(Ps, Pm, Pd);
          float* sp = sw + lane * 20;
          *reinterpret_cast<int4*>(sp) = int4{ts, tm, j, k};
          *reinterpret_cast<float4*>(sp + 4) = float4{c[0], c[1], c[2], c[3]};
          *reinterpret_cast<float4*>(sp + 8) = float4{c[4], c[5], c[6], c[7]};
          *reinterpret_cast<float4*>(sp + 12) = float4{ang, ang * ang, 0.f, 0.f};
        }
        // phase B (depth-2 gathers + depth-1 register Wu prefetch)
        int4 I0{0, 0, 0, 0}, I1{0, 0, 0, 0};
        ushort4 g00{0, 0, 0, 0}, g10{0, 0, 0, 0}, gdd0{0, 0, 0, 0};
        ushort4 g01{0, 0, 0, 0}, g11{0, 0, 0, 0}, gdd1{0, 0, 0, 0};
        if (cl > 0) {
          I0 = *reinterpret_cast<const int4*>(sw);
          g00 = g512(p_mid2, I0.x, c4);
          g10 = g512(p_mid1, I0.y, c4);
          gdd0 = g512(p_dst, n0 + I0.w, c4);
        }
        if (cl > 1) {
          I1 = *reinterpret_cast<const int4*>(sw + 20);
          g01 = g512(p_mid2, I1.x, c4);
          g11 = g512(p_mid1, I1.y, c4);
          gdd1 = g512(p_dst, n0 + I1.w, c4);
        }
        float4 wu[8];
        {
          const float* wbase = Wu1 + I0.z * DM + c4;
#pragma unroll
          for (int kk = 0; kk < 8; ++kk) wu[kk] = ld4f(wbase + kk * DM);
        }
#pragma unroll 1
        for (int e = 0; e < cl; ++e) {
          int4 I2{0, 0, 0, 0};
          ushort4 g02{0, 0, 0, 0}, g12{0, 0, 0, 0}, gdd2{0, 0, 0, 0};
          if (e + 2 < cl) I2 = *reinterpret_cast<const int4*>(sw + (e + 2) * 20);
          float4 wuN[8];
          {
            const float* wbase = Wu1 + I1.z * DM + c4;
#pragma unroll
            for (int kk = 0; kk < 8; ++kk) wuN[kk] = ld4f(wbase + kk * DM);
          }
          if (e + 2 < cl) {
            g02 = g512(p_mid2, I2.x, c4);
            g12 = g512(p_mid1, I2.y, c4);
            gdd2 = g512(p_dst, n0 + I2.w, c4);
          }
          while (kcur < I0.w) { FINALIZE(n0 + kcur, 256); ++kcur; }
          const float* sp = sw + e * 20;
          float4 f = *reinterpret_cast<const float4*>(sp + 12);
          float4 cc0 = *reinterpret_cast<const float4*>(sp + 4);
          float4 cc1 = *reinterpret_cast<const float4*>(sp + 8);
          float4 dm;
          dm.x = fmaf(f.x, wa0.x, fmaf(f.y, wa1.x, bsum.x));
          dm.y = fmaf(f.x, wa0.y, fmaf(f.y, wa1.y, bsum.y));
          dm.z = fmaf(f.x, wa0.z, fmaf(f.y, wa1.z, bsum.z));
          dm.w = fmaf(f.x, wa0.w, fmaf(f.y, wa1.w, bsum.w));
          dm = rbf_apply_r(wu, cc0, cc1, dm);
          float4 v0 = cvt4(g00), v2 = cvt4(g10), dd = cvt4(gdd0);
          float t0 = lk((v0.x + dd.x + v2.x) * dm.x);
          float t1 = lk((v0.y + dd.y + v2.y) * dm.y);
          float t2 = lk((v0.z + dd.z + v2.z) * dm.z);
          float t3 = lk((v0.w + dd.w + v2.w) * dm.w);
          float part = av.x * t0 + av.y * t1 + av.z * t2 + av.w * t3;
          part += __shfl_xor(part, 1, 64);
          part += __shfl_xor(part, 2, 64);
          part += __shfl_xor(part, 4, 64);
          float mn = fmaxf(mrun, part);
          float r = __expf(mrun - mn);
          float ew = __expf(part - mn);
          den = den * r + ew;
          acc.x = fmaf(acc.x, r, ew * v0.x);
          acc.y = fmaf(acc.y, r, ew * v0.y);
          acc.z = fmaf(acc.z, r, ew * v0.z);
          acc.w = fmaf(acc.w, r, ew * v0.w);
          mrun = mn;
          I0 = I1; g00 = g01; g10 = g11; gdd0 = gdd1;
          I1 = I2; g01 = g02; g11 = g12; gdd1 = gdd2;
#pragma unroll
          for (int kk = 0; kk < 8; ++kk) wu[kk] = wuN[kk];
        }
      }
      while (kcur < NPB2) { FINALIZE(n0 + kcur, 256); ++kcur; }
    } else {
      // ================= hop 3: 16 nodes/batch =================
      const int n0 = ((int)b - NBT1 - NBT2) * NPB3;
      const int* offp = offall + 2 * (NN + 1);
      const int* eidp = eidall + NE + NT;
      int offreg = offp[n0 + ((lane <= NPB3) ? lane : NPB3)];
      const int gs = __shfl(offreg, 0, 64);
      const int ge = __shfl(offreg, NPB3, 64);
      const float* Wu2 = fp + 152832;
      const float* Wd = fp + 164096;
      float4 av = ld4f(fp + 363776 + c4);
      float4 b1v = ld4f(fp + 163072 + c4), b2v = ld4f(fp + 165632 + c4);
      float4 bsum{b1v.x + b2v.x, b1v.y + b2v.y, b1v.z + b2v.z, b1v.w + b2v.w};
      float4 wd0 = ld4f(Wd + c4), wd1 = ld4f(Wd + DM + c4), wd2 = ld4f(Wd + 2 * DM + c4);
      float4 wd3 = ld4f(Wd + 3 * DM + c4), wd4 = ld4f(Wd + 4 * DM + c4), wd5 = ld4f(Wd + 5 * DM + c4);
      int kcur = 0;
      float mrun = -INFINITY, den = 0.f;
      float4 acc{0.f, 0.f, 0.f, 0.f};
      for (int cb = gs; cb < ge; cb += 64) {
        const int cl = (ge - cb < 64) ? (ge - cb) : 64;
        const int idx = cb + lane;
        int k = 0;
#pragma unroll
        for (int kk = 1; kk < NPB3; ++kk) {
          int v = __shfl(offreg, kk, 64);
          if (idx >= v) k = kk;
        }
        if (lane < cl) {  // phase A (k stored in int4.w; j stored in float slot)
          int q = eidp[idx];
          int qs = qdx[q], q2 = qdx[NQ + q], q1 = qdx[2 * NQ + q];
          F3 P0 = ldp(pos, qs), P1 = ldp(pos, q2), P2 = ldp(pos, q1);
          F3 Pd = ldp(pos, n0 + k);
          float d3 = fminf(fmaxf(norm3(sub3(P0, Pd)), 0.05f), 10.f);
          float c[8];
          int j = rbf_coef(d3, c);
          float a1f = angle_at(P0, P1, P2);
          float a2f = angle_at(P1, P2, Pd);
          float dh = dihedral_f(P0, P1, P2, Pd);
          float* sp = sw + lane * 20;
          *reinterpret_cast<int4*>(sp) = int4{qs, q2, q1, k};
          *reinterpret_cast<float4*>(sp + 4) = float4{c[0], c[1], c[2], c[3]};
          *reinterpret_cast<float4*>(sp + 8) = float4{c[4], c[5], c[6], c[7]};
          *reinterpret_cast<float4*>(sp + 12) = float4{a1f, a1f * a1f, a2f, a2f * a2f};
          *reinterpret_cast<float4*>(sp + 16) = float4{dh, dh * dh, __int_as_float(j), 0.f};
        }
        // phase B (depth-2 gathers + depth-1 register Wu prefetch)
        int4 I0{0, 0, 0, 0}, I1{0, 0, 0, 0};
        float4 fb0{0.f, 0.f, 0.f, 0.f}, fb1{0.f, 0.f, 0.f, 0.f};
        ushort4 g00{0, 0, 0, 0}, g10{0, 0, 0, 0}, g20{0, 0, 0, 0}, gdd0{0, 0, 0, 0};
        ushort4 g01{0, 0, 0, 0}, g11{0, 0, 0, 0}, g21{0, 0, 0, 0}, gdd1{0, 0, 0, 0};
        if (cl > 0) {
          I0 = *reinterpret_cast<const int4*>(sw);
          fb0 = *reinterpret_cast<const float4*>(sw + 16);
          g00 = g512(p_src, I0.x, c4);
          g10 = g512(p_mid2, I0.y, c4);
          g20 = g512(p_mid1, I0.z, c4);
          gdd0 = g512(p_dst, n0 + I0.w, c4);
        }
        if (cl > 1) {
          I1 = *reinterpret_cast<const int4*>(sw + 20);
          fb1 = *reinterpret_cast<const float4*>(sw + 20 + 16);
          g01 = g512(p_src, I1.x, c4);
          g11 = g512(p_mid2, I1.y, c4);
          g21 = g512(p_mid1, I1.z, c4);
          gdd1 = g512(p_dst, n0 + I1.w, c4);
        }
        float4 wu[8];
        {
          const float* wbase = Wu2 + __float_as_int(fb0.z) * DM + c4;
#pragma unroll
          for (int kk = 0; kk < 8; ++kk) wu[kk] = ld4f(wbase + kk * DM);
        }
#pragma unroll 1
        for (int e = 0; e < cl; ++e) {
          int4 I2{0, 0, 0, 0};
          float4 fb2{0.f, 0.f, 0.f, 0.f};
          ushort4 g02{0, 0, 0, 0}, g12{0, 0, 0, 0}, g22{0, 0, 0, 0}, gdd2{0, 0, 0, 0};
          if (e + 2 < cl) {
            I2 = *reinterpret_cast<const int4*>(sw + (e + 2) * 20);
            fb2 = *reinterpret_cast<const float4*>(sw + (e + 2) * 20 + 16);
          }
          float4 wuN[8];
          {
            const float* wbase = Wu2 + __float_as_int(fb1.z) * DM + c4;
#pragma unroll
            for (int kk = 0; kk < 8; ++kk) wuN[kk] = ld4f(wbase + kk * DM);
          }
          if (e + 2 < cl) {
            g02 = g512(p_src, I2.x, c4);
            g12 = g512(p_mid2, I2.y, c4);
            g22 = g512(p_mid1, I2.z, c4);
            gdd2 = g512(p_dst, n0 + I2.w, c4);
          }
          while (kcur < I0.w) { FINALIZE(n0 + kcur, 512); ++kcur; }
          const float* sp = sw + e * 20;
          float4 cc0 = *reinterpret_cast<const float4*>(sp + 4);
          float4 cc1 = *reinterpret_cast<const float4*>(sp + 8);
          float4 f = *reinterpret_cast<const float4*>(sp + 12);
          float4 dm;
          dm.x = bsum.x + f.x * wd0.x + f.y * wd1.x + f.z * wd2.x + f.w * wd3.x + fb0.x * wd4.x + fb0.y * wd5.x;
          dm.y = bsum.y + f.x * wd0.y + f.y * wd1.y + f.z * wd2.y + f.w * wd3.y + fb0.x * wd4.y + fb0.y * wd5.y;
          dm.z = bsum.z + f.x * wd0.z + f.y * wd1.z + f.z * wd2.z + f.w * wd3.z + fb0.x * wd4.z + fb0.y * wd5.z;
          dm.w = bsum.w + f.x * wd0.w + f.y * wd1.w + f.z * wd2.w + f.w * wd3.w + fb0.x * wd4.w + fb0.y * wd5.w;
          dm = rbf_apply_r(wu, cc0, cc1, dm);
          float4 v0 = cvt4(g00), v1 = cvt4(g10), v2 = cvt4(g20), dd = cvt4(gdd0);
          float t0 = lk((v0.x + v1.x + v2.x + dd.x) * dm.x);
          float t1 = lk((v0.y + v1.y + v2.y + dd.y) * dm.y);
          float t2 = lk((v0.z + v1.z + v2.z + dd.z) * dm.z);
          float t3 = lk((v0.w + v1.w + v2.w + dd.w) * dm.w);
          float part = av.x * t0 + av.y * t1 + av.z * t2 + av.w * t3;
          part += __shfl_xor(part, 1, 64);
          part += __shfl_xor(part, 2, 64);
          part += __shfl_xor(part, 4, 64);
          float mn = fmaxf(mrun, part);
          float r = __expf(mrun - mn);
          float ew = __expf(part - mn);
          den = den * r + ew;
          acc.x = fmaf(acc.x, r, ew * v0.x);
          acc.y = fmaf(acc.y, r, ew * v0.y);
          acc.z = fmaf(acc.z, r, ew * v0.z);
          acc.w = fmaf(acc.w, r, ew * v0.w);
          mrun = mn;
          I0 = I1; fb0 = fb1; g00 = g01; g10 = g11; g20 = g21; gdd0 = gdd1;
          I1 = I2; fb1 = fb2; g01 = g02; g11 = g12; g21 = g22; gdd1 = gdd2;
#pragma unroll
          for (int kk = 0; kk < 8; ++kk) wu[kk] = wuN[kk];
        }
      }
      while (kcur < NPB3) { FINALIZE(n0 + kcur, 512); ++kcur; }
    }
  }
}

// ---- MFMA output GEMM + LayerNorm + PReLU ----
__global__ __launch_bounds__(256) void gemm_mfma_ln(
    const u16* __restrict__ Abuf, const u16* __restrict__ Xs,
    const u16* __restrict__ wswz, const float* __restrict__ fp,
    float* __restrict__ outp) {
  __shared__ float sS[4][32], sQ[4][32], sMu[32], sRs[32];
  const int tid = threadIdx.x;
  const int wid = tid >> 6, lane = tid & 63;
  const int g = lane >> 4, l15 = lane & 15;
  const int m0 = blockIdx.x * 32;
  const int cb = wid * 64;

  f32x4 acc[2][4];
#pragma unroll
  for (int nf = 0; nf < 4; ++nf) {
    int c = cb + nf * 16 + l15;
    float bs = fp[231424 + c] + fp[297216 + c] + fp[363008 + c] + fp[396800 + c];
    acc[0][nf] = f32x4{bs, bs, bs, bs};
    acc[1][nf] = f32x4{bs, bs, bs, bs};
  }
  int rr0 = m0 + l15; if (rr0 > NN - 1) rr0 = NN - 1;
  int rr1 = m0 + 16 + l15; if (rr1 > NN - 1) rr1 = NN - 1;
  const u16* a0p = Abuf + (size_t)rr0 * 768 + g * 8;
  const u16* a1p = Abuf + (size_t)rr1 * 768 + g * 8;
  const u16* x0p = Xs + (size_t)rr0 * 256 + g * 8;
  const u16* x1p = Xs + (size_t)rr1 * 256 + g * 8;
  const u16* wb = wswz + (size_t)(wid * 4 * 64 + lane) * 8;

#pragma unroll 2
  for (int ks = 0; ks < 24; ++ks) {
    bf16x8 a0 = *reinterpret_cast<const bf16x8*>(a0p + ks * 32);
    bf16x8 a1 = *reinterpret_cast<const bf16x8*>(a1p + ks * 32);
#pragma unroll
    for (int nf = 0; nf < 4; ++nf) {
      bf16x8 bh = *reinterpret_cast<const bf16x8*>(wb + (size_t)ks * 8192 + nf * 512);
      bf16x8 bl = *reinterpret_cast<const bf16x8*>(wb + (size_t)(ks + 24) * 8192 + nf * 512);
      acc[0][nf] = __builtin_amdgcn_mfma_f32_16x16x32_bf16(a0, bh, acc[0][nf], 0, 0, 0);
      acc[1][nf] = __builtin_amdgcn_mfma_f32_16x16x32_bf16(a1, bh, acc[1][nf], 0, 0, 0);
      acc[0][nf] = __builtin_amdgcn_mfma_f32_16x16x32_bf16(a0, bl, acc[0][nf], 0, 0, 0);
      acc[1][nf] = __builtin_amdgcn_mfma_f32_16x16x32_bf16(a1, bl, acc[1][nf], 0, 0, 0);
    }
  }
#pragma unroll
  for (int ks = 0; ks < 4; ++ks) {
    bf16x8 xh0 = *reinterpret_cast<const bf16x8*>(x0p + ks * 32);
    bf16x8 xh1 = *reinterpret_cast<const bf16x8*>(x1p + ks * 32);
    bf16x8 xl0 = *reinterpret_cast<const bf16x8*>(x0p + 128 + ks * 32);
    bf16x8 xl1 = *reinterpret_cast<const bf16x8*>(x1p + 128 + ks * 32);
#pragma unroll
    for (int nf = 0; nf < 4; ++nf) {
      bf16x8 bh = *reinterpret_cast<const bf16x8*>(wb + (size_t)(48 + ks) * 8192 + nf * 512);
      bf16x8 bl = *reinterpret_cast<const bf16x8*>(wb + (size_t)(52 + ks) * 8192 + nf * 512);
      acc[0][nf] = __builtin_amdgcn_mfma_f32_16x16x32_bf16(xh0, bh, acc[0][nf], 0, 0, 0);
      acc[1][nf] = __builtin_amdgcn_mfma_f32_16x16x32_bf16(xh1, bh, acc[1][nf], 0, 0, 0);
      acc[0][nf] = __builtin_amdgcn_mfma_f32_16x16x32_bf16(xh0, bl, acc[0][nf], 0, 0, 0);
      acc[1][nf] = __builtin_amdgcn_mfma_f32_16x16x32_bf16(xh1, bl, acc[1][nf], 0, 0, 0);
      acc[0][nf] = __builtin_amdgcn_mfma_f32_16x16x32_bf16(xl0, bh, acc[0][nf], 0, 0, 0);
      acc[1][nf] = __builtin_amdgcn_mfma_f32_16x16x32_bf16(xl1, bh, acc[1][nf], 0, 0, 0);
    }
  }

#pragma unroll
  for (int mf = 0; mf < 2; ++mf) {
#pragma unroll
    for (int reg = 0; reg < 4; ++reg) {
      float sp = acc[mf][0][reg] + acc[mf][1][reg] + acc[mf][2][reg] + acc[mf][3][reg];
      float qp = acc[mf][0][reg] * acc[mf][0][reg] + acc[mf][1][reg] * acc[mf][1][reg] +
                 acc[mf][2][reg] * acc[mf][2][reg] + acc[mf][3][reg] * acc[mf][3][reg];
      for (int m = 8; m; m >>= 1) {
        sp += __shfl_xor(sp, m, 64);
        qp += __shfl_xor(qp, m, 64);
      }
      if (l15 == 0) {
        sS[wid][mf * 16 + g * 4 + reg] = sp;
        sQ[wid][mf * 16 + g * 4 + reg] = qp;
      }
    }
  }
  __syncthreads();
  if (tid < 32) {
    float S = sS[0][tid] + sS[1][tid] + sS[2][tid] + sS[3][tid];
    float Q = sQ[0][tid] + sQ[1][tid] + sQ[2][tid] + sQ[3][tid];
    float mu = S * (1.f / 256.f);
    float var = fmaxf(Q * (1.f / 256.f) - mu * mu, 0.f);
    sMu[tid] = mu;
    sRs[tid] = rsqrtf(var + 1e-5f);
  }
  __syncthreads();
  float pw = fp[397568];
#pragma unroll
  for (int nf = 0; nf < 4; ++nf) {
    int c = cb + nf * 16 + l15;
    float gc = fp[397056 + c], bc = fp[397312 + c];
#pragma unroll
    for (int mf = 0; mf < 2; ++mf) {
#pragma unroll
      for (int reg = 0; reg < 4; ++reg) {
        int rl = mf * 16 + g * 4 + reg;
        int row = m0 + rl;
        if (row < NN) {
          float y = (acc[mf][nf][reg] - sMu[rl]) * sRs[rl] * gc + bc;
          outp[(size_t)row * 256 + c] = (y >= 0.f) ? y : pw * y;
        }
      }
    }
  }
}

extern "C" void kernel_launch(void* const* d_in, const int* in_sizes, int n_in,
                              void* d_out, int out_size, void* d_ws, size_t ws_size,
                              hipStream_t stream) {
  const void* x = d_in[0];
  const void* pos = d_in[1];
  const int* eidx = (const int*)d_in[2];
  const int* tdx = (const int*)d_in[3];
  const int* qdx = (const int*)d_in[4];
  const void* eattr = d_in[5];
  float* outp = (float*)d_out;

  // workspace layout (~214 MB; proven safe <= ~221 MB)
  u16* p_src = (u16*)d_ws;
  u16* p_mid2 = p_src + (size_t)NN * DM;
  u16* p_mid1 = p_mid2 + (size_t)NN * DM;
  u16* p_dst = p_mid1 + (size_t)NN * DM;
  u16* Abuf = p_dst + (size_t)NN * DM;                // NN x 768 bf16 (A1|A2|A3)
  u16* Xs = Abuf + (size_t)NN * 768;                  // NN x 256 bf16 (xhi|xlo)
  float* posf = (float*)(Xs + (size_t)NN * 256);      // NN*3
  float* fp = posf + (size_t)NN * 3;                  // staged params
  u16* wswz = (u16*)(fp + TOTALP + 3);                // out-GEMM swizzled W
  u16* pswz = wswz + WSWZ_N;                          // proj swizzled W
  int* deg = (int*)(pswz + PSWZ_N);                   // 3*NN
  int* off = deg + 3 * NN;                            // 3*(NN+1)
  int* cur = off + 3 * (NN + 1);                      // 3*NN
  int* eid = cur + 3 * NN;                            // NE+NT+NQ
  u32* gmax = (u32*)(eid + NE + NT + NQ);
  int* flags = (int*)(gmax + 4);

  init_detect<<<1, 256, 0, stream>>>((const u32*)eattr, (const u32*)d_in[33], gmax, flags);

  PtrTab tab;
  for (int i = 0; i < 30; ++i) tab.p[i] = d_in[6 + i];
  convert_params<<<512, 256, 0, stream>>>(tab, flags, fp);
  convert_pos<<<587, 256, 0, stream>>>(pos, flags, posf);
  swizzle_w<<<WSWZ_N / 256, 256, 0, stream>>>(fp, wswz);
  swizzle_pw<<<PSWZ_N / 256, 256, 0, stream>>>(fp, pswz);

  // x hi/lo split (dedicated buffer; feeds both proj_mfma and gemm_mfma_ln)
  xsplit<<<2048, 256, 0, stream>>>(x, flags, Xs);

  // MFMA 4-way projection + PE
  proj_mfma<<<(NN + 31) / 32, 256, 0, stream>>>(Xs, pswz, p_src, p_mid2, p_mid1, p_dst);

  // CSR for all 3 hops
  hipMemsetAsync(deg, 0, (size_t)3 * NN * 4, stream);
  hist_all<<<1024, 256, 0, stream>>>(eidx + NE, tdx + 2 * NT, qdx + 3 * NQ, deg);
  scan_all<<<3, 1024, 0, stream>>>(deg, off, cur);
  fill_all<<<1024, 256, 0, stream>>>(eidx + NE, tdx + 2 * NT, qdx + 3 * NQ, cur, eid);

  // fused score + per-node softmax + aggregate (1-wave workgroups, Wu prefetch)
  fused_score_agg<<<8192, 64, 0, stream>>>(posf, eidx, tdx, qdx, eattr, flags,
                                           p_src, p_mid2, p_mid1, p_dst, fp,
                                           off, eid, gmax, Abuf);

  // MFMA output GEMM + LN + PReLU
  gemm_mfma_ln<<<(NN + 31) / 32, 256, 0, stream>>>(Abuf, Xs, wswz, fp, outp);
}

// Round 10
// 1145.386 us; speedup vs baseline: 1.1496x; 1.1496x over previous
//
#include <hip/hip_runtime.h>

#define NN 50000
#define NE 400000
#define NT 300000
#define NQ 200000
#define DM 256
#define FIN 128
#define NRBF 40
#define BETA_RBF 40.0f
#define TOTALP 397569

#define WSWZ_N (56 * 16 * 64 * 8)  // 458752 u16 swizzled-weight elements (out GEMM)
#define PSWZ_N (4 * 2 * 4 * 16 * 64 * 8)  // 262144 u16 swizzled proj weights

// fused-pass batching: consecutive nodes per wave, ~64 edges/batch
#define NPB1 8
#define NPB2 8
#define NPB3 16
#define NBT1 (NN / NPB1)          // 6250
#define NBT2 (NN / NPB2)          // 6250
#define NBT3 (NN / NPB3)          // 3125
#define NBT (NBT1 + NBT2 + NBT3)  // 15625

typedef unsigned int u32;
typedef unsigned short u16;
typedef __attribute__((ext_vector_type(8))) short bf16x8;
typedef __attribute__((ext_vector_type(4))) float f32x4;

// ---- bf16 helpers ----
static __device__ __forceinline__ float bf2f(u16 h) {
  return __uint_as_float(((u32)h) << 16);
}
static __device__ __forceinline__ u16 f2bf(float f) {
  u32 u = __float_as_uint(f);
  u32 r = (u + 0x7FFFu + ((u >> 16) & 1u)) >> 16;  // RNE
  return (u16)r;
}
static __device__ __forceinline__ float4 ld4f(const float* p) {
  return *reinterpret_cast<const float4*>(p);
}
static __device__ __forceinline__ float ldsc(const void* p, int isf, size_t i) {
  return isf ? ((const float*)p)[i] : bf2f(((const u16*)p)[i]);
}
static __device__ __forceinline__ float lk(float t) { return t >= 0.f ? t : 0.2f * t; }
static __device__ __forceinline__ u32 f2o(float f) {
  u32 u = __float_as_uint(f);
  return (u & 0x80000000u) ? ~u : (u | 0x80000000u);
}

struct F3 { float x, y, z; };
static __device__ __forceinline__ F3 ldp(const float* pos, int i) {
  return F3{pos[3 * i], pos[3 * i + 1], pos[3 * i + 2]};
}
static __device__ __forceinline__ F3 sub3(F3 a, F3 b) { return F3{a.x - b.x, a.y - b.y, a.z - b.z}; }
static __device__ __forceinline__ float dot3(F3 a, F3 b) { return a.x * b.x + a.y * b.y + a.z * b.z; }
static __device__ __forceinline__ F3 cross3(F3 a, F3 b) {
  return F3{a.y * b.z - a.z * b.y, a.z * b.x - a.x * b.z, a.x * b.y - a.y * b.x};
}
static __device__ __forceinline__ float norm3(F3 v) { return sqrtf(dot3(v, v) + 1e-12f); }
static __device__ __forceinline__ float angle_at(F3 a, F3 m, F3 b) {
  F3 u = sub3(a, m), v = sub3(b, m);
  float c = dot3(u, v) / (norm3(u) * norm3(v) + 1e-12f);
  c = fminf(fmaxf(c, -1.f + 1e-7f), 1.f - 1e-7f);
  return acosf(c);
}
static __device__ __forceinline__ float dihedral_f(F3 p0, F3 p1, F3 p2, F3 p3) {
  F3 b1 = sub3(p1, p0), b2 = sub3(p2, p1), b3 = sub3(p3, p2);
  F3 n1 = cross3(b1, b2), n2 = cross3(b2, b3);
  float nb2 = norm3(b2) + 1e-12f;
  F3 b2n{b2.x / nb2, b2.y / nb2, b2.z / nb2};
  F3 m1 = cross3(n1, b2n);
  return atan2f(dot3(m1, n2), dot3(n1, n2) + 1e-12f);
}

// phase A: scalar RBF window + 8 coefficients for ONE edge (per lane).
static __device__ __forceinline__ int rbf_coef(float d, float* c) {
  int j = (int)floorf(d * 4.0f) - 3;
  j = (j < 0) ? 0 : ((j > NRBF - 8) ? (NRBF - 8) : j);
  float t0 = d - 0.25f * (float)j;
#pragma unroll
  for (int k = 0; k < 8; ++k) {
    float t = t0 - 0.25f * (float)k;
    c[k] = __expf(-BETA_RBF * t * t);
  }
  return j;
}

// phase B: dm += sum_k c_k * Wu[j+k][c4..c4+3]
static __device__ __forceinline__ float4 rbf_apply(const float* __restrict__ base,
                                                   float4 c0, float4 c1, float4 dm) {
  float4 w;
  w = ld4f(base + 0 * DM);
  dm.x = fmaf(c0.x, w.x, dm.x); dm.y = fmaf(c0.x, w.y, dm.y);
  dm.z = fmaf(c0.x, w.z, dm.z); dm.w = fmaf(c0.x, w.w, dm.w);
  w = ld4f(base + 1 * DM);
  dm.x = fmaf(c0.y, w.x, dm.x); dm.y = fmaf(c0.y, w.y, dm.y);
  dm.z = fmaf(c0.y, w.z, dm.z); dm.w = fmaf(c0.y, w.w, dm.w);
  w = ld4f(base + 2 * DM);
  dm.x = fmaf(c0.z, w.x, dm.x); dm.y = fmaf(c0.z, w.y, dm.y);
  dm.z = fmaf(c0.z, w.z, dm.z); dm.w = fmaf(c0.z, w.w, dm.w);
  w = ld4f(base + 3 * DM);
  dm.x = fmaf(c0.w, w.x, dm.x); dm.y = fmaf(c0.w, w.y, dm.y);
  dm.z = fmaf(c0.w, w.z, dm.z); dm.w = fmaf(c0.w, w.w, dm.w);
  w = ld4f(base + 4 * DM);
  dm.x = fmaf(c1.x, w.x, dm.x); dm.y = fmaf(c1.x, w.y, dm.y);
  dm.z = fmaf(c1.x, w.z, dm.z); dm.w = fmaf(c1.x, w.w, dm.w);
  w = ld4f(base + 5 * DM);
  dm.x = fmaf(c1.y, w.x, dm.x); dm.y = fmaf(c1.y, w.y, dm.y);
  dm.z = fmaf(c1.y, w.z, dm.z); dm.w = fmaf(c1.y, w.w, dm.w);
  w = ld4f(base + 6 * DM);
  dm.x = fmaf(c1.z, w.x, dm.x); dm.y = fmaf(c1.z, w.y, dm.y);
  dm.z = fmaf(c1.z, w.z, dm.z); dm.w = fmaf(c1.z, w.w, dm.w);
  w = ld4f(base + 7 * DM);
  dm.x = fmaf(c1.w, w.x, dm.x); dm.y = fmaf(c1.w, w.y, dm.y);
  dm.z = fmaf(c1.w, w.z, dm.z); dm.w = fmaf(c1.w, w.w, dm.w);
  return dm;
}

static __device__ __forceinline__ ushort4 g512(const u16* p, int idx, int c4) {
  return *reinterpret_cast<const ushort4*>(p + (size_t)(u32)idx * DM + c4);
}
static __device__ __forceinline__ float4 cvt4(ushort4 v) {
  return float4{bf2f(v.x), bf2f(v.y), bf2f(v.z), bf2f(v.w)};
}

// param staging table: 30 tensors, cumulative offsets
__device__ const int g_off[31] = {
  0, 32768, 65536, 98304, 131072, 131584, 131840, 142080, 142336, 152576,
  152832, 163072, 163328, 163840, 164096, 165632, 165888, 231424, 231680,
  297216, 297472, 363008, 363264, 363520, 363776, 364032, 396800, 397056,
  397312, 397568, 397569};
struct PtrTab { const void* p[30]; };

// ---- init ----
__global__ __launch_bounds__(256) void init_detect(const u32* __restrict__ aw,
                                                   const u32* __restrict__ lng,
                                                   u32* __restrict__ gmax,
                                                   int* __restrict__ flags) {
  __shared__ int s_int, s_f32, s_bf;
  if (threadIdx.x == 0) { s_int = 1; s_f32 = 1; s_bf = 1; }
  __syncthreads();
  int li = 1, lf = 1, lb = 1;
  for (int i = threadIdx.x; i < 1024; i += 256) {
    u32 w = aw[i];
    if (w > 1u) li = 0;
    if (w != 0u && w != 0x3F800000u) lf = 0;
    u32 h0 = w & 0xFFFFu, h1 = w >> 16;
    if ((h0 != 0u && h0 != 0x3F80u) || (h1 != 0u && h1 != 0x3F80u)) lb = 0;
  }
  if (!li) atomicAnd(&s_int, 0);
  if (!lf) atomicAnd(&s_f32, 0);
  if (!lb) atomicAnd(&s_bf, 0);
  __syncthreads();
  if (threadIdx.x == 0) {
    flags[0] = s_int ? 0 : (s_f32 ? 2 : (s_bf ? 3 : 1));
    flags[1] = ((lng[0] & 0xFFFFu) == 0x3F80u) ? 0 : 1;  // 1 = fp32 inputs
    gmax[0] = f2o(-INFINITY);
    gmax[1] = f2o(-INFINITY);
    gmax[2] = f2o(-INFINITY);
    gmax[3] = 0u;  // fused-pass work-steal counter
  }
}

__global__ __launch_bounds__(256) void convert_params(PtrTab tab,
                                                      const int* __restrict__ flags,
                                                      float* __restrict__ dst) {
  const int isf = flags[1];
  for (int i = blockIdx.x * blockDim.x + threadIdx.x; i < TOTALP;
       i += gridDim.x * blockDim.x) {
    int t = 0;
    while (i >= g_off[t + 1]) ++t;
    dst[i] = ldsc(tab.p[t], isf, i - g_off[t]);
  }
}
__global__ __launch_bounds__(256) void convert_pos(const void* __restrict__ pos,
                                                   const int* __restrict__ flags,
                                                   float* __restrict__ posf) {
  const int isf = flags[1];
  for (int i = blockIdx.x * blockDim.x + threadIdx.x; i < NN * 3;
       i += gridDim.x * blockDim.x)
    posf[i] = ldsc(pos, isf, i);
}

static __device__ __forceinline__ int read_eattr(const void* p, int flag, int e) {
  if (flag == 1) return ((const unsigned char*)p)[e];
  if (flag == 2) return (((const float*)p)[e] != 0.f);
  if (flag == 3) return (((const u16*)p)[e] != 0);
  return ((const int*)p)[e];
}

// ---- weight swizzle for output-GEMM MFMA B-fragments ----
__global__ __launch_bounds__(256) void swizzle_w(const float* __restrict__ fp,
                                                 u16* __restrict__ wswz) {
  int idx = blockIdx.x * 256 + threadIdx.x;
  if (idx >= WSWZ_N) return;
  int jj = idx & 7;
  int lane = (idx >> 3) & 63;
  int nb = (idx >> 9) & 15;
  int s = idx >> 13;
  int kl = (lane >> 4) * 8 + jj;
  int col = nb * 16 + (lane & 15);
  float w;
  int lo;
  if (s < 48) {
    int sr = (s < 24) ? s : (s - 24);
    lo = (s >= 24);
    int K = sr * 32 + kl;
    int base = (K < 256) ? 165888 : ((K < 512) ? 231680 : 297472);
    w = fp[base + (K & 255) * 256 + col];
  } else {
    int sr = (s < 52) ? (s - 48) : (s - 52);
    lo = (s >= 52);
    int K = sr * 32 + kl;
    w = fp[364032 + K * 256 + col];
  }
  u16 hi = f2bf(w);
  wswz[idx] = lo ? f2bf(w - bf2f(hi)) : hi;
}

// ---- projection weight swizzle: 4 mats (src,mid2,mid1,dst) x hi/lo x K=128 ----
__global__ __launch_bounds__(256) void swizzle_pw(const float* __restrict__ fp,
                                                  u16* __restrict__ pswz) {
  int idx = blockIdx.x * 256 + threadIdx.x;
  if (idx >= PSWZ_N) return;
  int jj = idx & 7;
  int lane = (idx >> 3) & 63;
  int nb = (idx >> 9) & 15;
  int ks = (idx >> 13) & 3;
  int hilo = (idx >> 15) & 1;
  int mat = idx >> 16;
  const int mb[4] = {0, 98304, 65536, 32768};  // W_src, W_mid2, W_mid1, W_dst
  int K = ks * 32 + (lane >> 4) * 8 + jj;
  int col = nb * 16 + (lane & 15);
  float w = fp[mb[mat] + K * 256 + col];
  u16 hi = f2bf(w);
  pswz[idx] = hilo ? f2bf(w - bf2f(hi)) : hi;
}

// ---- x hi/lo split into Xs[NN][256] (cols 0..127 hi, 128..255 lo) ----
__global__ __launch_bounds__(256) void xsplit(const void* __restrict__ x,
                                              const int* __restrict__ flags,
                                              u16* __restrict__ Xs) {
  const int isf = flags[1];
  for (int i = blockIdx.x * blockDim.x + threadIdx.x; i < NN * FIN;
       i += gridDim.x * blockDim.x) {
    int n = i >> 7, k = i & 127;
    float v = ldsc(x, isf, i);
    u16 hi = f2bf(v);
    Xs[(size_t)n * 256 + k] = hi;
    Xs[(size_t)n * 256 + 128 + k] = f2bf(v - bf2f(hi));
  }
}

// ---- MFMA 4-way projection + sinusoidal PE ----
__global__ __launch_bounds__(256) void proj_mfma(
    const u16* __restrict__ Xs, const u16* __restrict__ pswz,
    u16* __restrict__ o0, u16* __restrict__ o1,
    u16* __restrict__ o2, u16* __restrict__ o3) {
  const int tid = threadIdx.x;
  const int wid = tid >> 6, lane = tid & 63;
  const int g = lane >> 4, l15 = lane & 15;
  const int m0 = blockIdx.x * 32;
  const int cb = wid * 64;

  int rr0 = m0 + l15; if (rr0 > NN - 1) rr0 = NN - 1;
  int rr1 = m0 + 16 + l15; if (rr1 > NN - 1) rr1 = NN - 1;
  const u16* x0p = Xs + (size_t)rr0 * 256 + g * 8;
  const u16* x1p = Xs + (size_t)rr1 * 256 + g * 8;

  bf16x8 xh0[4], xh1[4], xl0[4], xl1[4];
#pragma unroll
  for (int ks = 0; ks < 4; ++ks) {
    xh0[ks] = *reinterpret_cast<const bf16x8*>(x0p + ks * 32);
    xh1[ks] = *reinterpret_cast<const bf16x8*>(x1p + ks * 32);
    xl0[ks] = *reinterpret_cast<const bf16x8*>(x0p + 128 + ks * 32);
    xl1[ks] = *reinterpret_cast<const bf16x8*>(x1p + 128 + ks * 32);
  }

  u16* const outs[4] = {o0, o1, o2, o3};
#pragma unroll 1
  for (int mat = 0; mat < 4; ++mat) {
    f32x4 acc[2][4];
#pragma unroll
    for (int nf = 0; nf < 4; ++nf) {
      int c = cb + nf * 16 + l15;
      float dv = expf(-logf(10000.f) * (float)(c & ~1) / 256.f);
      float ang = (float)mat * dv;
      float p = (c & 1) ? cosf(ang) : sinf(ang);
      acc[0][nf] = f32x4{p, p, p, p};
      acc[1][nf] = f32x4{p, p, p, p};
    }
    const u16* wbm = pswz + (size_t)mat * 65536 + (size_t)lane * 8;
#pragma unroll
    for (int ks = 0; ks < 4; ++ks) {
#pragma unroll
      for (int nf = 0; nf < 4; ++nf) {
        const u16* bbase = wbm + (size_t)ks * 8192 + (wid * 4 + nf) * 512;
        bf16x8 bh = *reinterpret_cast<const bf16x8*>(bbase);
        bf16x8 bl = *reinterpret_cast<const bf16x8*>(bbase + 32768);
        acc[0][nf] = __builtin_amdgcn_mfma_f32_16x16x32_bf16(xh0[ks], bh, acc[0][nf], 0, 0, 0);
        acc[1][nf] = __builtin_amdgcn_mfma_f32_16x16x32_bf16(xh1[ks], bh, acc[1][nf], 0, 0, 0);
        acc[0][nf] = __builtin_amdgcn_mfma_f32_16x16x32_bf16(xh0[ks], bl, acc[0][nf], 0, 0, 0);
        acc[1][nf] = __builtin_amdgcn_mfma_f32_16x16x32_bf16(xh1[ks], bl, acc[1][nf], 0, 0, 0);
        acc[0][nf] = __builtin_amdgcn_mfma_f32_16x16x32_bf16(xl0[ks], bh, acc[0][nf], 0, 0, 0);
        acc[1][nf] = __builtin_amdgcn_mfma_f32_16x16x32_bf16(xl1[ks], bh, acc[1][nf], 0, 0, 0);
      }
    }
    u16* op = outs[mat];
#pragma unroll
    for (int nf = 0; nf < 4; ++nf) {
      int c = cb + nf * 16 + l15;
#pragma unroll
      for (int mf = 0; mf < 2; ++mf) {
#pragma unroll
        for (int reg = 0; reg < 4; ++reg) {
          int row = m0 + mf * 16 + g * 4 + reg;
          if (row < NN) op[(size_t)row * 256 + c] = f2bf(acc[mf][nf][reg]);
        }
      }
    }
  }
}

// ---- fused CSR build over the 3 hops ----
__global__ __launch_bounds__(256) void hist_all(const int* __restrict__ ed,
                                                const int* __restrict__ td,
                                                const int* __restrict__ qd,
                                                int* __restrict__ deg) {
  const int M = NE + NT + NQ;
  for (int i = blockIdx.x * blockDim.x + threadIdx.x; i < M; i += gridDim.x * blockDim.x) {
    if (i < NE) atomicAdd(&deg[ed[i]], 1);
    else if (i < NE + NT) atomicAdd(&deg[NN + td[i - NE]], 1);
    else atomicAdd(&deg[2 * NN + qd[i - NE - NT]], 1);
  }
}
__global__ __launch_bounds__(1024) void scan_all(const int* __restrict__ degall,
                                                 int* __restrict__ offall,
                                                 int* __restrict__ curall) {
  __shared__ int part[1024];
  const int b = blockIdx.x;
  const int* deg = degall + (size_t)b * NN;
  int* off = offall + (size_t)b * (NN + 1);
  int* cur = curall + (size_t)b * NN;
  const int CH = (NN + 1023) / 1024;
  const int t = threadIdx.x;
  const int base = t * CH;
  int s = 0;
  for (int i = 0; i < CH; ++i) { int idx = base + i; if (idx < NN) s += deg[idx]; }
  part[t] = s;
  __syncthreads();
  for (int d = 1; d < 1024; d <<= 1) {
    int v = (t >= d) ? part[t - d] : 0;
    __syncthreads();
    part[t] += v;
    __syncthreads();
  }
  int run = (t == 0) ? 0 : part[t - 1];
  for (int i = 0; i < CH; ++i) {
    int idx = base + i;
    if (idx < NN) { off[idx] = run; cur[idx] = run; run += deg[idx]; }
  }
  if (t == 1023) off[NN] = run;
}
__global__ __launch_bounds__(256) void fill_all(const int* __restrict__ ed,
                                                const int* __restrict__ td,
                                                const int* __restrict__ qd,
                                                int* __restrict__ cur,
                                                int* __restrict__ eid) {
  const int M = NE + NT + NQ;
  for (int i = blockIdx.x * blockDim.x + threadIdx.x; i < M; i += gridDim.x * blockDim.x) {
    if (i < NE) {
      int p = atomicAdd(&cur[ed[i]], 1);
      eid[p] = i;
    } else if (i < NE + NT) {
      int il = i - NE;
      int p = atomicAdd(&cur[NN + td[il]], 1);
      eid[NE + p] = il;
    } else {
      int il = i - NE - NT;
      int p = atomicAdd(&cur[2 * NN + qd[il]], 1);
      eid[NE + NT + p] = il;
    }
  }
}

// finalize current node's online-softmax state into Abuf, reset state
#define FINALIZE(node, hopoff)                                         \
  {                                                                    \
    float inv = 1.f / (den + 1e-16f);                                  \
    ushort4 o;                                                         \
    o.x = f2bf(acc.x * inv); o.y = f2bf(acc.y * inv);                  \
    o.z = f2bf(acc.z * inv); o.w = f2bf(acc.w * inv);                  \
    *reinterpret_cast<ushort4*>(Abuf + (size_t)(node) * 768 +          \
                                (hopoff) + c4) = o;                    \
    den = 0.f; mrun = -INFINITY;                                       \
    acc = float4{0.f, 0.f, 0.f, 0.f};                                  \
  }

// ---- fused score + per-node softmax + aggregate, node-batched ----
// 1-wave workgroups (64 threads): no intra-block coupling exists (no barriers,
// per-wave LDS slab, per-wave work-steal). Depth-2 gather pipeline. This is
// the round-8 configuration (best measured: 525 us, VGPR 112, 22% occupancy).
// NOTE: VGPR budget sits just under the 128 hardware granule — adding register
// state (e.g. Wu prefetch) crosses it and HALVES occupancy (round-9 regression).
__global__ __launch_bounds__(64) void fused_score_agg(
    const float* __restrict__ pos,
    const int* __restrict__ eidx, const int* __restrict__ tdx, const int* __restrict__ qdx,
    const void* __restrict__ eattr, const int* __restrict__ flags,
    const u16* __restrict__ p_src, const u16* __restrict__ p_mid2,
    const u16* __restrict__ p_mid1, const u16* __restrict__ p_dst,
    const float* __restrict__ fp,
    const int* __restrict__ offall, const int* __restrict__ eidall,
    u32* __restrict__ gmax, u16* __restrict__ Abuf) {
  __shared__ __align__(16) float slds[64 * 20];
  const int lane = threadIdx.x & 63;
  float* sw = slds;
  const int c4 = lane * 4;
  const int flag = flags[0];

  for (int it = 0; it <= NBT; ++it) {
    u32 bl = 0;
    if (lane == 0) bl = atomicAdd(gmax + 3, 1u);
    u32 b = (u32)__builtin_amdgcn_readfirstlane((int)bl);
    if (b >= NBT) break;

    if (b < NBT1) {
      // ================= hop 1: 8 nodes/batch =================
      const int n0 = (int)b * NPB1;
      const int* offp = offall;
      const int* eidp = eidall;
      int offreg = offp[n0 + ((lane <= NPB1) ? lane : NPB1)];
      const int gs = __shfl(offreg, 0, 64);
      const int ge = __shfl(offreg, NPB1, 64);
      const float* Wu = fp + 131840;
      float4 av = ld4f(fp + 363264 + c4);
      float4 bbv = ld4f(fp + 131584 + c4), buv = ld4f(fp + 142080 + c4);
      float4 bsum{bbv.x + buv.x, bbv.y + buv.y, bbv.z + buv.z, bbv.w + buv.w};
      float4 wb0 = ld4f(fp + 131072 + c4), wb1 = ld4f(fp + 131072 + DM + c4);
      int kcur = 0;
      float mrun = -INFINITY, den = 0.f;
      float4 acc{0.f, 0.f, 0.f, 0.f};
      for (int cb = gs; cb < ge; cb += 64) {
        const int cl = (ge - cb < 64) ? (ge - cb) : 64;
        const int idx = cb + lane;
        int k = 0;
#pragma unroll
        for (int kk = 1; kk < NPB1; ++kk) {
          int v = __shfl(offreg, kk, 64);
          if (idx >= v) k = kk;
        }
        if (lane < cl) {  // phase A
          int e = eidp[idx];
          int es = eidx[e];
          int ea = read_eattr(eattr, flag, e);
          F3 Ps = ldp(pos, es), Pd = ldp(pos, n0 + k);
          float d1 = norm3(sub3(Ps, Pd));
          float c[8]; int j = 0; float f0, f1;
          if (ea) {
            float dc = fminf(fmaxf(d1, 0.05f), 10.f);
            j = rbf_coef(dc, c);
            f0 = 0.f; f1 = 0.f;
          } else {
#pragma unroll
            for (int kk = 0; kk < 8; ++kk) c[kk] = 0.f;
            f0 = d1; f1 = d1 * d1;
          }
          float* sp = sw + lane * 20;
          *reinterpret_cast<int4*>(sp) = int4{es, ea, j, k};
          *reinterpret_cast<float4*>(sp + 4) = float4{c[0], c[1], c[2], c[3]};
          *reinterpret_cast<float4*>(sp + 8) = float4{c[4], c[5], c[6], c[7]};
          *reinterpret_cast<float4*>(sp + 12) = float4{f0, f1, 0.f, 0.f};
        }
        // phase B (depth-2 pipeline)
        int4 I0{0, 0, 0, 0}, I1{0, 0, 0, 0};
        ushort4 gm0{0, 0, 0, 0}, gdd0{0, 0, 0, 0}, gm1{0, 0, 0, 0}, gdd1{0, 0, 0, 0};
        if (cl > 0) {
          I0 = *reinterpret_cast<const int4*>(sw);
          gm0 = g512(p_mid1, I0.x, c4);
          gdd0 = g512(p_dst, n0 + I0.w, c4);
        }
        if (cl > 1) {
          I1 = *reinterpret_cast<const int4*>(sw + 20);
          gm1 = g512(p_mid1, I1.x, c4);
          gdd1 = g512(p_dst, n0 + I1.w, c4);
        }
#pragma unroll 1
        for (int e = 0; e < cl; ++e) {
          int4 I2{0, 0, 0, 0};
          ushort4 gm2{0, 0, 0, 0}, gdd2{0, 0, 0, 0};
          if (e + 2 < cl) {
            I2 = *reinterpret_cast<const int4*>(sw + (e + 2) * 20);
            gm2 = g512(p_mid1, I2.x, c4);
            gdd2 = g512(p_dst, n0 + I2.w, c4);
          }
          while (kcur < I0.w) { FINALIZE(n0 + kcur, 0); ++kcur; }
          const float* sp = sw + e * 20;
          float4 dm = bsum;
          if (I0.y) {
            float4 cc0 = *reinterpret_cast<const float4*>(sp + 4);
            float4 cc1 = *reinterpret_cast<const float4*>(sp + 8);
            dm = rbf_apply(Wu + I0.z * DM + c4, cc0, cc1, dm);
          } else {
            float4 f = *reinterpret_cast<const float4*>(sp + 12);
            dm.x = fmaf(f.x, wb0.x, fmaf(f.y, wb1.x, dm.x));
            dm.y = fmaf(f.x, wb0.y, fmaf(f.y, wb1.y, dm.y));
            dm.z = fmaf(f.x, wb0.z, fmaf(f.y, wb1.z, dm.z));
            dm.w = fmaf(f.x, wb0.w, fmaf(f.y, wb1.w, dm.w));
          }
          float4 mv = cvt4(gm0), dd = cvt4(gdd0);
          float t0 = lk((mv.x + dd.x) * dm.x);
          float t1 = lk((mv.y + dd.y) * dm.y);
          float t2 = lk((mv.z + dd.z) * dm.z);
          float t3 = lk((mv.w + dd.w) * dm.w);
          float part = av.x * t0 + av.y * t1 + av.z * t2 + av.w * t3;
          part += __shfl_xor(part, 1, 64);
          part += __shfl_xor(part, 2, 64);
          part += __shfl_xor(part, 4, 64);
          float mn = fmaxf(mrun, part);
          float r = __expf(mrun - mn);
          float ew = __expf(part - mn);
          den = den * r + ew;
          acc.x = fmaf(acc.x, r, ew * mv.x);
          acc.y = fmaf(acc.y, r, ew * mv.y);
          acc.z = fmaf(acc.z, r, ew * mv.z);
          acc.w = fmaf(acc.w, r, ew * mv.w);
          mrun = mn;
          I0 = I1; gm0 = gm1; gdd0 = gdd1;
          I1 = I2; gm1 = gm2; gdd1 = gdd2;
        }
      }
      while (kcur < NPB1) { FINALIZE(n0 + kcur, 0); ++kcur; }
    } else if (b < NBT1 + NBT2) {
      // ================= hop 2: 8 nodes/batch =================
      const int n0 = ((int)b - NBT1) * NPB2;
      const int* offp = offall + (NN + 1);
      const int* eidp = eidall + NE;
      int offreg = offp[n0 + ((lane <= NPB2) ? lane : NPB2)];
      const int gs = __shfl(offreg, 0, 64);
      const int ge = __shfl(offreg, NPB2, 64);
      const float* Wu1 = fp + 142336;
      float4 av = ld4f(fp + 363520 + c4);
      float4 b1v = ld4f(fp + 152576 + c4), b2v = ld4f(fp + 163840 + c4);
      float4 bsum{b1v.x + b2v.x, b1v.y + b2v.y, b1v.z + b2v.z, b1v.w + b2v.w};
      float4 wa0 = ld4f(fp + 163328 + c4), wa1 = ld4f(fp + 163328 + DM + c4);
      int kcur = 0;
      float mrun = -INFINITY, den = 0.f;
      float4 acc{0.f, 0.f, 0.f, 0.f};
      for (int cb = gs; cb < ge; cb += 64) {
        const int cl = (ge - cb < 64) ? (ge - cb) : 64;
        const int idx = cb + lane;
        int k = 0;
#pragma unroll
        for (int kk = 1; kk < NPB2; ++kk) {
          int v = __shfl(offreg, kk, 64);
          if (idx >= v) k = kk;
        }
        if (lane < cl) {  // phase A
          int t = eidp[idx];
          int ts = tdx[t], tm = tdx[NT + t];
          F3 Ps = ldp(pos, ts), Pm = ldp(pos, tm), Pd = ldp(pos, n0 + k);
          float d2 = fminf(fmaxf(norm3(sub3(Ps, Pd)), 0.05f), 10.f);
          float c[8];
          int j = rbf_coef(d2, c);
          float ang = angle_at(Ps, Pm, Pd);
          float* sp = sw + lane * 20;
          *reinterpret_cast<int4*>(sp) = int4{ts, tm, j, k};
          *reinterpret_cast<float4*>(sp + 4) = float4{c[0], c[1], c[2], c[3]};
          *reinterpret_cast<float4*>(sp + 8) = float4{c[4], c[5], c[6], c[7]};
          *reinterpret_cast<float4*>(sp + 12) = float4{ang, ang * ang, 0.f, 0.f};
        }
        // phase B (depth-2 pipeline)
        int4 I0{0, 0, 0, 0}, I1{0, 0, 0, 0};
        ushort4 g00{0, 0, 0, 0}, g10{0, 0, 0, 0}, gdd0{0, 0, 0, 0};
        ushort4 g01{0, 0, 0, 0}, g11{0, 0, 0, 0}, gdd1{0, 0, 0, 0};
        if (cl > 0) {
          I0 = *reinterpret_cast<const int4*>(sw);
          g00 = g512(p_mid2, I0.x, c4);
          g10 = g512(p_mid1, I0.y, c4);
          gdd0 = g512(p_dst, n0 + I0.w, c4);
        }
        if (cl > 1) {
          I1 = *reinterpret_cast<const int4*>(sw + 20);
          g01 = g512(p_mid2, I1.x, c4);
          g11 = g512(p_mid1, I1.y, c4);
          gdd1 = g512(p_dst, n0 + I1.w, c4);
        }
#pragma unroll 1
        for (int e = 0; e < cl; ++e) {
          int4 I2{0, 0, 0, 0};
          ushort4 g02{0, 0, 0, 0}, g12{0, 0, 0, 0}, gdd2{0, 0, 0, 0};
          if (e + 2 < cl) {
            I2 = *reinterpret_cast<const int4*>(sw + (e + 2) * 20);
            g02 = g512(p_mid2, I2.x, c4);
            g12 = g512(p_mid1, I2.y, c4);
            gdd2 = g512(p_dst, n0 + I2.w, c4);
          }
          while (kcur < I0.w) { FINALIZE(n0 + kcur, 256); ++kcur; }
          const float* sp = sw + e * 20;
          float4 cc0 = *reinterpret_cast<const float4*>(sp + 4);
          float4 cc1 = *reinterpret_cast<const float4*>(sp + 8);
          float4 f = *reinterpret_cast<const float4*>(sp + 12);
          float4 dm;
          dm.x = fmaf(f.x, wa0.x, fmaf(f.y, wa1.x, bsum.x));
          dm.y = fmaf(f.x, wa0.y, fmaf(f.y, wa1.y, bsum.y));
          dm.z = fmaf(f.x, wa0.z, fmaf(f.y, wa1.z, bsum.z));
          dm.w = fmaf(f.x, wa0.w, fmaf(f.y, wa1.w, bsum.w));
          dm = rbf_apply(Wu1 + I0.z * DM + c4, cc0, cc1, dm);
          float4 v0 = cvt4(g00), v2 = cvt4(g10), dd = cvt4(gdd0);
          float t0 = lk((v0.x + dd.x + v2.x) * dm.x);
          float t1 = lk((v0.y + dd.y + v2.y) * dm.y);
          float t2 = lk((v0.z + dd.z + v2.z) * dm.z);
          float t3 = lk((v0.w + dd.w + v2.w) * dm.w);
          float part = av.x * t0 + av.y * t1 + av.z * t2 + av.w * t3;
          part += __shfl_xor(part, 1, 64);
          part += __shfl_xor(part, 2, 64);
          part += __shfl_xor(part, 4, 64);
          float mn = fmaxf(mrun, part);
          float r = __expf(mrun - mn);
          float ew = __expf(part - mn);
          den = den * r + ew;
          acc.x = fmaf(acc.x, r, ew * v0.x);
          acc.y = fmaf(acc.y, r, ew * v0.y);
          acc.z = fmaf(acc.z, r, ew * v0.z);
          acc.w = fmaf(acc.w, r, ew * v0.w);
          mrun = mn;
          I0 = I1; g00 = g01; g10 = g11; gdd0 = gdd1;
          I1 = I2; g01 = g02; g11 = g12; gdd1 = gdd2;
        }
      }
      while (kcur < NPB2) { FINALIZE(n0 + kcur, 256); ++kcur; }
    } else {
      // ================= hop 3: 16 nodes/batch =================
      const int n0 = ((int)b - NBT1 - NBT2) * NPB3;
      const int* offp = offall + 2 * (NN + 1);
      const int* eidp = eidall + NE + NT;
      int offreg = offp[n0 + ((lane <= NPB3) ? lane : NPB3)];
      const int gs = __shfl(offreg, 0, 64);
      const int ge = __shfl(offreg, NPB3, 64);
      const float* Wu2 = fp + 152832;
      const float* Wd = fp + 164096;
      float4 av = ld4f(fp + 363776 + c4);
      float4 b1v = ld4f(fp + 163072 + c4), b2v = ld4f(fp + 165632 + c4);
      float4 bsum{b1v.x + b2v.x, b1v.y + b2v.y, b1v.z + b2v.z, b1v.w + b2v.w};
      float4 wd0 = ld4f(Wd + c4), wd1 = ld4f(Wd + DM + c4), wd2 = ld4f(Wd + 2 * DM + c4);
      float4 wd3 = ld4f(Wd + 3 * DM + c4), wd4 = ld4f(Wd + 4 * DM + c4), wd5 = ld4f(Wd + 5 * DM + c4);
      int kcur = 0;
      float mrun = -INFINITY, den = 0.f;
      float4 acc{0.f, 0.f, 0.f, 0.f};
      for (int cb = gs; cb < ge; cb += 64) {
        const int cl = (ge - cb < 64) ? (ge - cb) : 64;
        const int idx = cb + lane;
        int k = 0;
#pragma unroll
        for (int kk = 1; kk < NPB3; ++kk) {
          int v = __shfl(offreg, kk, 64);
          if (idx >= v) k = kk;
        }
        if (lane < cl) {  // phase A (k stored in int4.w; j stored in float slot)
          int q = eidp[idx];
          int qs = qdx[q], q2 = qdx[NQ + q], q1 = qdx[2 * NQ + q];
          F3 P0 = ldp(pos, qs), P1 = ldp(pos, q2), P2 = ldp(pos, q1);
          F3 Pd = ldp(pos, n0 + k);
          float d3 = fminf(fmaxf(norm3(sub3(P0, Pd)), 0.05f), 10.f);
          float c[8];
          int j = rbf_coef(d3, c);
          float a1f = angle_at(P0, P1, P2);
          float a2f = angle_at(P1, P2, Pd);
          float dh = dihedral_f(P0, P1, P2, Pd);
          float* sp = sw + lane * 20;
          *reinterpret_cast<int4*>(sp) = int4{qs, q2, q1, k};
          *reinterpret_cast<float4*>(sp + 4) = float4{c[0], c[1], c[2], c[3]};
          *reinterpret_cast<float4*>(sp + 8) = float4{c[4], c[5], c[6], c[7]};
          *reinterpret_cast<float4*>(sp + 12) = float4{a1f, a1f * a1f, a2f, a2f * a2f};
          *reinterpret_cast<float4*>(sp + 16) = float4{dh, dh * dh, __int_as_float(j), 0.f};
        }
        // phase B (depth-2 pipeline)
        int4 I0{0, 0, 0, 0}, I1{0, 0, 0, 0};
        ushort4 g00{0, 0, 0, 0}, g10{0, 0, 0, 0}, g20{0, 0, 0, 0}, gdd0{0, 0, 0, 0};
        ushort4 g01{0, 0, 0, 0}, g11{0, 0, 0, 0}, g21{0, 0, 0, 0}, gdd1{0, 0, 0, 0};
        if (cl > 0) {
          I0 = *reinterpret_cast<const int4*>(sw);
          g00 = g512(p_src, I0.x, c4);
          g10 = g512(p_mid2, I0.y, c4);
          g20 = g512(p_mid1, I0.z, c4);
          gdd0 = g512(p_dst, n0 + I0.w, c4);
        }
        if (cl > 1) {
          I1 = *reinterpret_cast<const int4*>(sw + 20);
          g01 = g512(p_src, I1.x, c4);
          g11 = g512(p_mid2, I1.y, c4);
          g21 = g512(p_mid1, I1.z, c4);
          gdd1 = g512(p_dst, n0 + I1.w, c4);
        }
#pragma unroll 1
        for (int e = 0; e < cl; ++e) {
          int4 I2{0, 0, 0, 0};
          ushort4 g02{0, 0, 0, 0}, g12{0, 0, 0, 0}, g22{0, 0, 0, 0}, gdd2{0, 0, 0, 0};
          if (e + 2 < cl) {
            I2 = *reinterpret_cast<const int4*>(sw + (e + 2) * 20);
            g02 = g512(p_src, I2.x, c4);
            g12 = g512(p_mid2, I2.y, c4);
            g22 = g512(p_mid1, I2.z, c4);
            gdd2 = g512(p_dst, n0 + I2.w, c4);
          }
          while (kcur < I0.w) { FINALIZE(n0 + kcur, 512); ++kcur; }
          const float* sp = sw + e * 20;
          float4 cc0 = *reinterpret_cast<const float4*>(sp + 4);
          float4 cc1 = *reinterpret_cast<const float4*>(sp + 8);
          float4 f = *reinterpret_cast<const float4*>(sp + 12);
          float4 fb2 = *reinterpret_cast<const float4*>(sp + 16);
          int j = __float_as_int(fb2.z);
          float4 dm;
          dm.x = bsum.x + f.x * wd0.x + f.y * wd1.x + f.z * wd2.x + f.w * wd3.x + fb2.x * wd4.x + fb2.y * wd5.x;
          dm.y = bsum.y + f.x * wd0.y + f.y * wd1.y + f.z * wd2.y + f.w * wd3.y + fb2.x * wd4.y + fb2.y * wd5.y;
          dm.z = bsum.z + f.x * wd0.z + f.y * wd1.z + f.z * wd2.z + f.w * wd3.z + fb2.x * wd4.z + fb2.y * wd5.z;
          dm.w = bsum.w + f.x * wd0.w + f.y * wd1.w + f.z * wd2.w + f.w * wd3.w + fb2.x * wd4.w + fb2.y * wd5.w;
          dm = rbf_apply(Wu2 + j * DM + c4, cc0, cc1, dm);
          float4 v0 = cvt4(g00), v1 = cvt4(g10), v2 = cvt4(g20), dd = cvt4(gdd0);
          float t0 = lk((v0.x + v1.x + v2.x + dd.x) * dm.x);
          float t1 = lk((v0.y + v1.y + v2.y + dd.y) * dm.y);
          float t2 = lk((v0.z + v1.z + v2.z + dd.z) * dm.z);
          float t3 = lk((v0.w + v1.w + v2.w + dd.w) * dm.w);
          float part = av.x * t0 + av.y * t1 + av.z * t2 + av.w * t3;
          part += __shfl_xor(part, 1, 64);
          part += __shfl_xor(part, 2, 64);
          part += __shfl_xor(part, 4, 64);
          float mn = fmaxf(mrun, part);
          float r = __expf(mrun - mn);
          float ew = __expf(part - mn);
          den = den * r + ew;
          acc.x = fmaf(acc.x, r, ew * v0.x);
          acc.y = fmaf(acc.y, r, ew * v0.y);
          acc.z = fmaf(acc.z, r, ew * v0.z);
          acc.w = fmaf(acc.w, r, ew * v0.w);
          mrun = mn;
          I0 = I1; g00 = g01; g10 = g11; g20 = g21; gdd0 = gdd1;
          I1 = I2; g01 = g02; g11 = g12; g21 = g22; gdd1 = gdd2;
        }
      }
      while (kcur < NPB3) { FINALIZE(n0 + kcur, 512); ++kcur; }
    }
  }
}

// ---- MFMA output GEMM + LayerNorm + PReLU ----
__global__ __launch_bounds__(256) void gemm_mfma_ln(
    const u16* __restrict__ Abuf, const u16* __restrict__ Xs,
    const u16* __restrict__ wswz, const float* __restrict__ fp,
    float* __restrict__ outp) {
  __shared__ float sS[4][32], sQ[4][32], sMu[32], sRs[32];
  const int tid = threadIdx.x;
  const int wid = tid >> 6, lane = tid & 63;
  const int g = lane >> 4, l15 = lane & 15;
  const int m0 = blockIdx.x * 32;
  const int cb = wid * 64;

  f32x4 acc[2][4];
#pragma unroll
  for (int nf = 0; nf < 4; ++nf) {
    int c = cb + nf * 16 + l15;
    float bs = fp[231424 + c] + fp[297216 + c] + fp[363008 + c] + fp[396800 + c];
    acc[0][nf] = f32x4{bs, bs, bs, bs};
    acc[1][nf] = f32x4{bs, bs, bs, bs};
  }
  int rr0 = m0 + l15; if (rr0 > NN - 1) rr0 = NN - 1;
  int rr1 = m0 + 16 + l15; if (rr1 > NN - 1) rr1 = NN - 1;
  const u16* a0p = Abuf + (size_t)rr0 * 768 + g * 8;
  const u16* a1p = Abuf + (size_t)rr1 * 768 + g * 8;
  const u16* x0p = Xs + (size_t)rr0 * 256 + g * 8;
  const u16* x1p = Xs + (size_t)rr1 * 256 + g * 8;
  const u16* wb = wswz + (size_t)(wid * 4 * 64 + lane) * 8;

#pragma unroll 2
  for (int ks = 0; ks < 24; ++ks) {
    bf16x8 a0 = *reinterpret_cast<const bf16x8*>(a0p + ks * 32);
    bf16x8 a1 = *reinterpret_cast<const bf16x8*>(a1p + ks * 32);
#pragma unroll
    for (int nf = 0; nf < 4; ++nf) {
      bf16x8 bh = *reinterpret_cast<const bf16x8*>(wb + (size_t)ks * 8192 + nf * 512);
      bf16x8 bl = *reinterpret_cast<const bf16x8*>(wb + (size_t)(ks + 24) * 8192 + nf * 512);
      acc[0][nf] = __builtin_amdgcn_mfma_f32_16x16x32_bf16(a0, bh, acc[0][nf], 0, 0, 0);
      acc[1][nf] = __builtin_amdgcn_mfma_f32_16x16x32_bf16(a1, bh, acc[1][nf], 0, 0, 0);
      acc[0][nf] = __builtin_amdgcn_mfma_f32_16x16x32_bf16(a0, bl, acc[0][nf], 0, 0, 0);
      acc[1][nf] = __builtin_amdgcn_mfma_f32_16x16x32_bf16(a1, bl, acc[1][nf], 0, 0, 0);
    }
  }
#pragma unroll
  for (int ks = 0; ks < 4; ++ks) {
    bf16x8 xh0 = *reinterpret_cast<const bf16x8*>(x0p + ks * 32);
    bf16x8 xh1 = *reinterpret_cast<const bf16x8*>(x1p + ks * 32);
    bf16x8 xl0 = *reinterpret_cast<const bf16x8*>(x0p + 128 + ks * 32);
    bf16x8 xl1 = *reinterpret_cast<const bf16x8*>(x1p + 128 + ks * 32);
#pragma unroll
    for (int nf = 0; nf < 4; ++nf) {
      bf16x8 bh = *reinterpret_cast<const bf16x8*>(wb + (size_t)(48 + ks) * 8192 + nf * 512);
      bf16x8 bl = *reinterpret_cast<const bf16x8*>(wb + (size_t)(52 + ks) * 8192 + nf * 512);
      acc[0][nf] = __builtin_amdgcn_mfma_f32_16x16x32_bf16(xh0, bh, acc[0][nf], 0, 0, 0);
      acc[1][nf] = __builtin_amdgcn_mfma_f32_16x16x32_bf16(xh1, bh, acc[1][nf], 0, 0, 0);
      acc[0][nf] = __builtin_amdgcn_mfma_f32_16x16x32_bf16(xh0, bl, acc[0][nf], 0, 0, 0);
      acc[1][nf] = __builtin_amdgcn_mfma_f32_16x16x32_bf16(xh1, bl, acc[1][nf], 0, 0, 0);
      acc[0][nf] = __builtin_amdgcn_mfma_f32_16x16x32_bf16(xl0, bh, acc[0][nf], 0, 0, 0);
      acc[1][nf] = __builtin_amdgcn_mfma_f32_16x16x32_bf16(xl1, bh, acc[1][nf], 0, 0, 0);
    }
  }

#pragma unroll
  for (int mf = 0; mf < 2; ++mf) {
#pragma unroll
    for (int reg = 0; reg < 4; ++reg) {
      float sp = acc[mf][0][reg] + acc[mf][1][reg] + acc[mf][2][reg] + acc[mf][3][reg];
      float qp = acc[mf][0][reg] * acc[mf][0][reg] + acc[mf][1][reg] * acc[mf][1][reg] +
                 acc[mf][2][reg] * acc[mf][2][reg] + acc[mf][3][reg] * acc[mf][3][reg];
      for (int m = 8; m; m >>= 1) {
        sp += __shfl_xor(sp, m, 64);
        qp += __shfl_xor(qp, m, 64);
      }
      if (l15 == 0) {
        sS[wid][mf * 16 + g * 4 + reg] = sp;
        sQ[wid][mf * 16 + g * 4 + reg] = qp;
      }
    }
  }
  __syncthreads();
  if (tid < 32) {
    float S = sS[0][tid] + sS[1][tid] + sS[2][tid] + sS[3][tid];
    float Q = sQ[0][tid] + sQ[1][tid] + sQ[2][tid] + sQ[3][tid];
    float mu = S * (1.f / 256.f);
    float var = fmaxf(Q * (1.f / 256.f) - mu * mu, 0.f);
    sMu[tid] = mu;
    sRs[tid] = rsqrtf(var + 1e-5f);
  }
  __syncthreads();
  float pw = fp[397568];
#pragma unroll
  for (int nf = 0; nf < 4; ++nf) {
    int c = cb + nf * 16 + l15;
    float gc = fp[397056 + c], bc = fp[397312 + c];
#pragma unroll
    for (int mf = 0; mf < 2; ++mf) {
#pragma unroll
      for (int reg = 0; reg < 4; ++reg) {
        int rl = mf * 16 + g * 4 + reg;
        int row = m0 + rl;
        if (row < NN) {
          float y = (acc[mf][nf][reg] - sMu[rl]) * sRs[rl] * gc + bc;
          outp[(size_t)row * 256 + c] = (y >= 0.f) ? y : pw * y;
        }
      }
    }
  }
}

extern "C" void kernel_launch(void* const* d_in, const int* in_sizes, int n_in,
                              void* d_out, int out_size, void* d_ws, size_t ws_size,
                              hipStream_t stream) {
  const void* x = d_in[0];
  const void* pos = d_in[1];
  const int* eidx = (const int*)d_in[2];
  const int* tdx = (const int*)d_in[3];
  const int* qdx = (const int*)d_in[4];
  const void* eattr = d_in[5];
  float* outp = (float*)d_out;

  // workspace layout (~214 MB; proven safe <= ~221 MB)
  u16* p_src = (u16*)d_ws;
  u16* p_mid2 = p_src + (size_t)NN * DM;
  u16* p_mid1 = p_mid2 + (size_t)NN * DM;
  u16* p_dst = p_mid1 + (size_t)NN * DM;
  u16* Abuf = p_dst + (size_t)NN * DM;                // NN x 768 bf16 (A1|A2|A3)
  u16* Xs = Abuf + (size_t)NN * 768;                  // NN x 256 bf16 (xhi|xlo)
  float* posf = (float*)(Xs + (size_t)NN * 256);      // NN*3
  float* fp = posf + (size_t)NN * 3;                  // staged params
  u16* wswz = (u16*)(fp + TOTALP + 3);                // out-GEMM swizzled W
  u16* pswz = wswz + WSWZ_N;                          // proj swizzled W
  int* deg = (int*)(pswz + PSWZ_N);                   // 3*NN
  int* off = deg + 3 * NN;                            // 3*(NN+1)
  int* cur = off + 3 * (NN + 1);                      // 3*NN
  int* eid = cur + 3 * NN;                            // NE+NT+NQ
  u32* gmax = (u32*)(eid + NE + NT + NQ);
  int* flags = (int*)(gmax + 4);

  init_detect<<<1, 256, 0, stream>>>((const u32*)eattr, (const u32*)d_in[33], gmax, flags);

  PtrTab tab;
  for (int i = 0; i < 30; ++i) tab.p[i] = d_in[6 + i];
  convert_params<<<512, 256, 0, stream>>>(tab, flags, fp);
  convert_pos<<<587, 256, 0, stream>>>(pos, flags, posf);
  swizzle_w<<<WSWZ_N / 256, 256, 0, stream>>>(fp, wswz);
  swizzle_pw<<<PSWZ_N / 256, 256, 0, stream>>>(fp, pswz);

  // x hi/lo split (dedicated buffer; feeds both proj_mfma and gemm_mfma_ln)
  xsplit<<<2048, 256, 0, stream>>>(x, flags, Xs);

  // MFMA 4-way projection + PE
  proj_mfma<<<(NN + 31) / 32, 256, 0, stream>>>(Xs, pswz, p_src, p_mid2, p_mid1, p_dst);

  // CSR for all 3 hops
  hipMemsetAsync(deg, 0, (size_t)3 * NN * 4, stream);
  hist_all<<<1024, 256, 0, stream>>>(eidx + NE, tdx + 2 * NT, qdx + 3 * NQ, deg);
  scan_all<<<3, 1024, 0, stream>>>(deg, off, cur);
  fill_all<<<1024, 256, 0, stream>>>(eidx + NE, tdx + 2 * NT, qdx + 3 * NQ, cur, eid);

  // fused score + per-node softmax + aggregate (1-wave workgroups for TLP)
  fused_score_agg<<<8192, 64, 0, stream>>>(posf, eidx, tdx, qdx, eattr, flags,
                                           p_src, p_mid2, p_mid1, p_dst, fp,
                                           off, eid, gmax, Abuf);

  // MFMA output GEMM + LN + PReLU
  gemm_mfma_ln<<<(NN + 31) / 32, 256, 0, stream>>>(Abuf, Xs, wswz, fp, outp);
}

// Round 11
// 1102.257 us; speedup vs baseline: 1.1945x; 1.0391x over previous
//
#include <hip/hip_runtime.h>

#define NN 50000
#define NE 400000
#define NT 300000
#define NQ 200000
#define DM 256
#define FIN 128
#define NRBF 40
#define BETA_RBF 40.0f
#define TOTALP 397569

#define WSWZ_N (56 * 16 * 64 * 8)  // 458752 u16 swizzled-weight elements (out GEMM)
#define PSWZ_N (4 * 2 * 4 * 16 * 64 * 8)  // 262144 u16 swizzled proj weights

// fused-pass batching: consecutive nodes per wave, ~64 edges/batch
#define NPB1 8
#define NPB2 8
#define NPB3 16
#define NBT1 (NN / NPB1)          // 6250
#define NBT2 (NN / NPB2)          // 6250
#define NBT3 (NN / NPB3)          // 3125
#define NBT (NBT1 + NBT2 + NBT3)  // 15625

typedef unsigned int u32;
typedef unsigned short u16;
typedef __attribute__((ext_vector_type(8))) short bf16x8;
typedef __attribute__((ext_vector_type(4))) float f32x4;

// ---- bf16 helpers ----
static __device__ __forceinline__ float bf2f(u16 h) {
  return __uint_as_float(((u32)h) << 16);
}
static __device__ __forceinline__ u16 f2bf(float f) {
  u32 u = __float_as_uint(f);
  u32 r = (u + 0x7FFFu + ((u >> 16) & 1u)) >> 16;  // RNE
  return (u16)r;
}
static __device__ __forceinline__ float4 ld4f(const float* p) {
  return *reinterpret_cast<const float4*>(p);
}
static __device__ __forceinline__ float ldsc(const void* p, int isf, size_t i) {
  return isf ? ((const float*)p)[i] : bf2f(((const u16*)p)[i]);
}
static __device__ __forceinline__ float lk(float t) { return t >= 0.f ? t : 0.2f * t; }
static __device__ __forceinline__ u32 f2o(float f) {
  u32 u = __float_as_uint(f);
  return (u & 0x80000000u) ? ~u : (u | 0x80000000u);
}

struct F3 { float x, y, z; };
static __device__ __forceinline__ F3 ldp(const float* pos, int i) {
  return F3{pos[3 * i], pos[3 * i + 1], pos[3 * i + 2]};
}
static __device__ __forceinline__ F3 sub3(F3 a, F3 b) { return F3{a.x - b.x, a.y - b.y, a.z - b.z}; }
static __device__ __forceinline__ float dot3(F3 a, F3 b) { return a.x * b.x + a.y * b.y + a.z * b.z; }
static __device__ __forceinline__ F3 cross3(F3 a, F3 b) {
  return F3{a.y * b.z - a.z * b.y, a.z * b.x - a.x * b.z, a.x * b.y - a.y * b.x};
}
static __device__ __forceinline__ float norm3(F3 v) { return sqrtf(dot3(v, v) + 1e-12f); }
static __device__ __forceinline__ float angle_at(F3 a, F3 m, F3 b) {
  F3 u = sub3(a, m), v = sub3(b, m);
  float c = dot3(u, v) / (norm3(u) * norm3(v) + 1e-12f);
  c = fminf(fmaxf(c, -1.f + 1e-7f), 1.f - 1e-7f);
  return acosf(c);
}
static __device__ __forceinline__ float dihedral_f(F3 p0, F3 p1, F3 p2, F3 p3) {
  F3 b1 = sub3(p1, p0), b2 = sub3(p2, p1), b3 = sub3(p3, p2);
  F3 n1 = cross3(b1, b2), n2 = cross3(b2, b3);
  float nb2 = norm3(b2) + 1e-12f;
  F3 b2n{b2.x / nb2, b2.y / nb2, b2.z / nb2};
  F3 m1 = cross3(n1, b2n);
  return atan2f(dot3(m1, n2), dot3(n1, n2) + 1e-12f);
}

// phase A: scalar RBF window + 8 coefficients for ONE edge (per lane).
static __device__ __forceinline__ int rbf_coef(float d, float* c) {
  int j = (int)floorf(d * 4.0f) - 3;
  j = (j < 0) ? 0 : ((j > NRBF - 8) ? (NRBF - 8) : j);
  float t0 = d - 0.25f * (float)j;
#pragma unroll
  for (int k = 0; k < 8; ++k) {
    float t = t0 - 0.25f * (float)k;
    c[k] = __expf(-BETA_RBF * t * t);
  }
  return j;
}

// phase B: dm += sum_k c_k * Wu[j+k][c4..c4+3]
static __device__ __forceinline__ float4 rbf_apply(const float* __restrict__ base,
                                                   float4 c0, float4 c1, float4 dm) {
  float4 w;
  w = ld4f(base + 0 * DM);
  dm.x = fmaf(c0.x, w.x, dm.x); dm.y = fmaf(c0.x, w.y, dm.y);
  dm.z = fmaf(c0.x, w.z, dm.z); dm.w = fmaf(c0.x, w.w, dm.w);
  w = ld4f(base + 1 * DM);
  dm.x = fmaf(c0.y, w.x, dm.x); dm.y = fmaf(c0.y, w.y, dm.y);
  dm.z = fmaf(c0.y, w.z, dm.z); dm.w = fmaf(c0.y, w.w, dm.w);
  w = ld4f(base + 2 * DM);
  dm.x = fmaf(c0.z, w.x, dm.x); dm.y = fmaf(c0.z, w.y, dm.y);
  dm.z = fmaf(c0.z, w.z, dm.z); dm.w = fmaf(c0.z, w.w, dm.w);
  w = ld4f(base + 3 * DM);
  dm.x = fmaf(c0.w, w.x, dm.x); dm.y = fmaf(c0.w, w.y, dm.y);
  dm.z = fmaf(c0.w, w.z, dm.z); dm.w = fmaf(c0.w, w.w, dm.w);
  w = ld4f(base + 4 * DM);
  dm.x = fmaf(c1.x, w.x, dm.x); dm.y = fmaf(c1.x, w.y, dm.y);
  dm.z = fmaf(c1.x, w.z, dm.z); dm.w = fmaf(c1.x, w.w, dm.w);
  w = ld4f(base + 5 * DM);
  dm.x = fmaf(c1.y, w.x, dm.x); dm.y = fmaf(c1.y, w.y, dm.y);
  dm.z = fmaf(c1.y, w.z, dm.z); dm.w = fmaf(c1.y, w.w, dm.w);
  w = ld4f(base + 6 * DM);
  dm.x = fmaf(c1.z, w.x, dm.x); dm.y = fmaf(c1.z, w.y, dm.y);
  dm.z = fmaf(c1.z, w.z, dm.z); dm.w = fmaf(c1.z, w.w, dm.w);
  w = ld4f(base + 7 * DM);
  dm.x = fmaf(c1.w, w.x, dm.x); dm.y = fmaf(c1.w, w.y, dm.y);
  dm.z = fmaf(c1.w, w.z, dm.z); dm.w = fmaf(c1.w, w.w, dm.w);
  return dm;
}

static __device__ __forceinline__ ushort4 g512(const u16* p, int idx, int c4) {
  return *reinterpret_cast<const ushort4*>(p + (size_t)(u32)idx * DM + c4);
}
static __device__ __forceinline__ float4 cvt4(ushort4 v) {
  return float4{bf2f(v.x), bf2f(v.y), bf2f(v.z), bf2f(v.w)};
}

// param staging table: 30 tensors, cumulative offsets
__device__ const int g_off[31] = {
  0, 32768, 65536, 98304, 131072, 131584, 131840, 142080, 142336, 152576,
  152832, 163072, 163328, 163840, 164096, 165632, 165888, 231424, 231680,
  297216, 297472, 363008, 363264, 363520, 363776, 364032, 396800, 397056,
  397312, 397568, 397569};
struct PtrTab { const void* p[30]; };

// ---- init ----
__global__ __launch_bounds__(256) void init_detect(const u32* __restrict__ aw,
                                                   const u32* __restrict__ lng,
                                                   u32* __restrict__ gmax,
                                                   int* __restrict__ flags) {
  __shared__ int s_int, s_f32, s_bf;
  if (threadIdx.x == 0) { s_int = 1; s_f32 = 1; s_bf = 1; }
  __syncthreads();
  int li = 1, lf = 1, lb = 1;
  for (int i = threadIdx.x; i < 1024; i += 256) {
    u32 w = aw[i];
    if (w > 1u) li = 0;
    if (w != 0u && w != 0x3F800000u) lf = 0;
    u32 h0 = w & 0xFFFFu, h1 = w >> 16;
    if ((h0 != 0u && h0 != 0x3F80u) || (h1 != 0u && h1 != 0x3F80u)) lb = 0;
  }
  if (!li) atomicAnd(&s_int, 0);
  if (!lf) atomicAnd(&s_f32, 0);
  if (!lb) atomicAnd(&s_bf, 0);
  __syncthreads();
  if (threadIdx.x == 0) {
    flags[0] = s_int ? 0 : (s_f32 ? 2 : (s_bf ? 3 : 1));
    flags[1] = ((lng[0] & 0xFFFFu) == 0x3F80u) ? 0 : 1;  // 1 = fp32 inputs
    gmax[0] = f2o(-INFINITY);
    gmax[1] = f2o(-INFINITY);
    gmax[2] = f2o(-INFINITY);
    gmax[3] = 0u;  // fused-pass work-steal counter
  }
}

__global__ __launch_bounds__(256) void convert_params(PtrTab tab,
                                                      const int* __restrict__ flags,
                                                      float* __restrict__ dst) {
  const int isf = flags[1];
  for (int i = blockIdx.x * blockDim.x + threadIdx.x; i < TOTALP;
       i += gridDim.x * blockDim.x) {
    int t = 0;
    while (i >= g_off[t + 1]) ++t;
    dst[i] = ldsc(tab.p[t], isf, i - g_off[t]);
  }
}
__global__ __launch_bounds__(256) void convert_pos(const void* __restrict__ pos,
                                                   const int* __restrict__ flags,
                                                   float* __restrict__ posf) {
  const int isf = flags[1];
  for (int i = blockIdx.x * blockDim.x + threadIdx.x; i < NN * 3;
       i += gridDim.x * blockDim.x)
    posf[i] = ldsc(pos, isf, i);
}

static __device__ __forceinline__ int read_eattr(const void* p, int flag, int e) {
  if (flag == 1) return ((const unsigned char*)p)[e];
  if (flag == 2) return (((const float*)p)[e] != 0.f);
  if (flag == 3) return (((const u16*)p)[e] != 0);
  return ((const int*)p)[e];
}

// ---- weight swizzle for output-GEMM MFMA B-fragments ----
__global__ __launch_bounds__(256) void swizzle_w(const float* __restrict__ fp,
                                                 u16* __restrict__ wswz) {
  int idx = blockIdx.x * 256 + threadIdx.x;
  if (idx >= WSWZ_N) return;
  int jj = idx & 7;
  int lane = (idx >> 3) & 63;
  int nb = (idx >> 9) & 15;
  int s = idx >> 13;
  int kl = (lane >> 4) * 8 + jj;
  int col = nb * 16 + (lane & 15);
  float w;
  int lo;
  if (s < 48) {
    int sr = (s < 24) ? s : (s - 24);
    lo = (s >= 24);
    int K = sr * 32 + kl;
    int base = (K < 256) ? 165888 : ((K < 512) ? 231680 : 297472);
    w = fp[base + (K & 255) * 256 + col];
  } else {
    int sr = (s < 52) ? (s - 48) : (s - 52);
    lo = (s >= 52);
    int K = sr * 32 + kl;
    w = fp[364032 + K * 256 + col];
  }
  u16 hi = f2bf(w);
  wswz[idx] = lo ? f2bf(w - bf2f(hi)) : hi;
}

// ---- projection weight swizzle: 4 mats (src,mid2,mid1,dst) x hi/lo x K=128 ----
__global__ __launch_bounds__(256) void swizzle_pw(const float* __restrict__ fp,
                                                  u16* __restrict__ pswz) {
  int idx = blockIdx.x * 256 + threadIdx.x;
  if (idx >= PSWZ_N) return;
  int jj = idx & 7;
  int lane = (idx >> 3) & 63;
  int nb = (idx >> 9) & 15;
  int ks = (idx >> 13) & 3;
  int hilo = (idx >> 15) & 1;
  int mat = idx >> 16;
  const int mb[4] = {0, 98304, 65536, 32768};  // W_src, W_mid2, W_mid1, W_dst
  int K = ks * 32 + (lane >> 4) * 8 + jj;
  int col = nb * 16 + (lane & 15);
  float w = fp[mb[mat] + K * 256 + col];
  u16 hi = f2bf(w);
  pswz[idx] = hilo ? f2bf(w - bf2f(hi)) : hi;
}

// ---- x hi/lo split into Xs[NN][256] (cols 0..127 hi, 128..255 lo) ----
__global__ __launch_bounds__(256) void xsplit(const void* __restrict__ x,
                                              const int* __restrict__ flags,
                                              u16* __restrict__ Xs) {
  const int isf = flags[1];
  for (int i = blockIdx.x * blockDim.x + threadIdx.x; i < NN * FIN;
       i += gridDim.x * blockDim.x) {
    int n = i >> 7, k = i & 127;
    float v = ldsc(x, isf, i);
    u16 hi = f2bf(v);
    Xs[(size_t)n * 256 + k] = hi;
    Xs[(size_t)n * 256 + 128 + k] = f2bf(v - bf2f(hi));
  }
}

// ---- MFMA 4-way projection + sinusoidal PE ----
__global__ __launch_bounds__(256) void proj_mfma(
    const u16* __restrict__ Xs, const u16* __restrict__ pswz,
    u16* __restrict__ o0, u16* __restrict__ o1,
    u16* __restrict__ o2, u16* __restrict__ o3) {
  const int tid = threadIdx.x;
  const int wid = tid >> 6, lane = tid & 63;
  const int g = lane >> 4, l15 = lane & 15;
  const int m0 = blockIdx.x * 32;
  const int cb = wid * 64;

  int rr0 = m0 + l15; if (rr0 > NN - 1) rr0 = NN - 1;
  int rr1 = m0 + 16 + l15; if (rr1 > NN - 1) rr1 = NN - 1;
  const u16* x0p = Xs + (size_t)rr0 * 256 + g * 8;
  const u16* x1p = Xs + (size_t)rr1 * 256 + g * 8;

  bf16x8 xh0[4], xh1[4], xl0[4], xl1[4];
#pragma unroll
  for (int ks = 0; ks < 4; ++ks) {
    xh0[ks] = *reinterpret_cast<const bf16x8*>(x0p + ks * 32);
    xh1[ks] = *reinterpret_cast<const bf16x8*>(x1p + ks * 32);
    xl0[ks] = *reinterpret_cast<const bf16x8*>(x0p + 128 + ks * 32);
    xl1[ks] = *reinterpret_cast<const bf16x8*>(x1p + 128 + ks * 32);
  }

  u16* const outs[4] = {o0, o1, o2, o3};
#pragma unroll 1
  for (int mat = 0; mat < 4; ++mat) {
    f32x4 acc[2][4];
#pragma unroll
    for (int nf = 0; nf < 4; ++nf) {
      int c = cb + nf * 16 + l15;
      float dv = expf(-logf(10000.f) * (float)(c & ~1) / 256.f);
      float ang = (float)mat * dv;
      float p = (c & 1) ? cosf(ang) : sinf(ang);
      acc[0][nf] = f32x4{p, p, p, p};
      acc[1][nf] = f32x4{p, p, p, p};
    }
    const u16* wbm = pswz + (size_t)mat * 65536 + (size_t)lane * 8;
#pragma unroll
    for (int ks = 0; ks < 4; ++ks) {
#pragma unroll
      for (int nf = 0; nf < 4; ++nf) {
        const u16* bbase = wbm + (size_t)ks * 8192 + (wid * 4 + nf) * 512;
        bf16x8 bh = *reinterpret_cast<const bf16x8*>(bbase);
        bf16x8 bl = *reinterpret_cast<const bf16x8*>(bbase + 32768);
        acc[0][nf] = __builtin_amdgcn_mfma_f32_16x16x32_bf16(xh0[ks], bh, acc[0][nf], 0, 0, 0);
        acc[1][nf] = __builtin_amdgcn_mfma_f32_16x16x32_bf16(xh1[ks], bh, acc[1][nf], 0, 0, 0);
        acc[0][nf] = __builtin_amdgcn_mfma_f32_16x16x32_bf16(xh0[ks], bl, acc[0][nf], 0, 0, 0);
        acc[1][nf] = __builtin_amdgcn_mfma_f32_16x16x32_bf16(xh1[ks], bl, acc[1][nf], 0, 0, 0);
        acc[0][nf] = __builtin_amdgcn_mfma_f32_16x16x32_bf16(xl0[ks], bh, acc[0][nf], 0, 0, 0);
        acc[1][nf] = __builtin_amdgcn_mfma_f32_16x16x32_bf16(xl1[ks], bh, acc[1][nf], 0, 0, 0);
      }
    }
    u16* op = outs[mat];
#pragma unroll
    for (int nf = 0; nf < 4; ++nf) {
      int c = cb + nf * 16 + l15;
#pragma unroll
      for (int mf = 0; mf < 2; ++mf) {
#pragma unroll
        for (int reg = 0; reg < 4; ++reg) {
          int row = m0 + mf * 16 + g * 4 + reg;
          if (row < NN) op[(size_t)row * 256 + c] = f2bf(acc[mf][nf][reg]);
        }
      }
    }
  }
}

// ---- fused CSR build over the 3 hops ----
__global__ __launch_bounds__(256) void hist_all(const int* __restrict__ ed,
                                                const int* __restrict__ td,
                                                const int* __restrict__ qd,
                                                int* __restrict__ deg) {
  const int M = NE + NT + NQ;
  for (int i = blockIdx.x * blockDim.x + threadIdx.x; i < M; i += gridDim.x * blockDim.x) {
    if (i < NE) atomicAdd(&deg[ed[i]], 1);
    else if (i < NE + NT) atomicAdd(&deg[NN + td[i - NE]], 1);
    else atomicAdd(&deg[2 * NN + qd[i - NE - NT]], 1);
  }
}
__global__ __launch_bounds__(1024) void scan_all(const int* __restrict__ degall,
                                                 int* __restrict__ offall,
                                                 int* __restrict__ curall) {
  __shared__ int part[1024];
  const int b = blockIdx.x;
  const int* deg = degall + (size_t)b * NN;
  int* off = offall + (size_t)b * (NN + 1);
  int* cur = curall + (size_t)b * NN;
  const int CH = (NN + 1023) / 1024;
  const int t = threadIdx.x;
  const int base = t * CH;
  int s = 0;
  for (int i = 0; i < CH; ++i) { int idx = base + i; if (idx < NN) s += deg[idx]; }
  part[t] = s;
  __syncthreads();
  for (int d = 1; d < 1024; d <<= 1) {
    int v = (t >= d) ? part[t - d] : 0;
    __syncthreads();
    part[t] += v;
    __syncthreads();
  }
  int run = (t == 0) ? 0 : part[t - 1];
  for (int i = 0; i < CH; ++i) {
    int idx = base + i;
    if (idx < NN) { off[idx] = run; cur[idx] = run; run += deg[idx]; }
  }
  if (t == 1023) off[NN] = run;
}
__global__ __launch_bounds__(256) void fill_all(const int* __restrict__ ed,
                                                const int* __restrict__ td,
                                                const int* __restrict__ qd,
                                                int* __restrict__ cur,
                                                int* __restrict__ eid) {
  const int M = NE + NT + NQ;
  for (int i = blockIdx.x * blockDim.x + threadIdx.x; i < M; i += gridDim.x * blockDim.x) {
    if (i < NE) {
      int p = atomicAdd(&cur[ed[i]], 1);
      eid[p] = i;
    } else if (i < NE + NT) {
      int il = i - NE;
      int p = atomicAdd(&cur[NN + td[il]], 1);
      eid[NE + p] = il;
    } else {
      int il = i - NE - NT;
      int p = atomicAdd(&cur[2 * NN + qd[il]], 1);
      eid[NE + NT + p] = il;
    }
  }
}

// finalize current node's online-softmax state into Abuf, reset state
#define FINALIZE(node, hopoff)                                         \
  {                                                                    \
    float inv = 1.f / (den + 1e-16f);                                  \
    ushort4 o;                                                         \
    o.x = f2bf(acc.x * inv); o.y = f2bf(acc.y * inv);                  \
    o.z = f2bf(acc.z * inv); o.w = f2bf(acc.w * inv);                  \
    *reinterpret_cast<ushort4*>(Abuf + (size_t)(node) * 768 +          \
                                (hopoff) + c4) = o;                    \
    den = 0.f; mrun = -INFINITY;                                       \
    acc = float4{0.f, 0.f, 0.f, 0.f};                                  \
  }

// ---- fused score + per-node softmax + aggregate, node-batched ----
// 2-wave workgroups (128 threads), waves fully independent (per-wave LDS slab,
// per-wave work-steal, no barriers). Round-8 measured ~7 workgroup slots/CU
// with 1-wave blocks (22% occupancy vs 16-wave static limit) — 2 waves/slot
// should double resident waves for this latency-bound loop.
// NOTE: VGPR 112 sits just under the 128 hardware granule — adding register
// state (e.g. Wu prefetch) crosses it and HALVES occupancy (round-9 regression).
__global__ __launch_bounds__(128) void fused_score_agg(
    const float* __restrict__ pos,
    const int* __restrict__ eidx, const int* __restrict__ tdx, const int* __restrict__ qdx,
    const void* __restrict__ eattr, const int* __restrict__ flags,
    const u16* __restrict__ p_src, const u16* __restrict__ p_mid2,
    const u16* __restrict__ p_mid1, const u16* __restrict__ p_dst,
    const float* __restrict__ fp,
    const int* __restrict__ offall, const int* __restrict__ eidall,
    u32* __restrict__ gmax, u16* __restrict__ Abuf) {
  __shared__ __align__(16) float slds[2][64 * 20];
  const int lane = threadIdx.x & 63;
  float* sw = slds[(threadIdx.x >> 6) & 1];
  const int c4 = lane * 4;
  const int flag = flags[0];

  for (int it = 0; it <= NBT; ++it) {
    u32 bl = 0;
    if (lane == 0) bl = atomicAdd(gmax + 3, 1u);
    u32 b = (u32)__builtin_amdgcn_readfirstlane((int)bl);
    if (b >= NBT) break;

    if (b < NBT1) {
      // ================= hop 1: 8 nodes/batch =================
      const int n0 = (int)b * NPB1;
      const int* offp = offall;
      const int* eidp = eidall;
      int offreg = offp[n0 + ((lane <= NPB1) ? lane : NPB1)];
      const int gs = __shfl(offreg, 0, 64);
      const int ge = __shfl(offreg, NPB1, 64);
      const float* Wu = fp + 131840;
      float4 av = ld4f(fp + 363264 + c4);
      float4 bbv = ld4f(fp + 131584 + c4), buv = ld4f(fp + 142080 + c4);
      float4 bsum{bbv.x + buv.x, bbv.y + buv.y, bbv.z + buv.z, bbv.w + buv.w};
      float4 wb0 = ld4f(fp + 131072 + c4), wb1 = ld4f(fp + 131072 + DM + c4);
      int kcur = 0;
      float mrun = -INFINITY, den = 0.f;
      float4 acc{0.f, 0.f, 0.f, 0.f};
      for (int cb = gs; cb < ge; cb += 64) {
        const int cl = (ge - cb < 64) ? (ge - cb) : 64;
        const int idx = cb + lane;
        int k = 0;
#pragma unroll
        for (int kk = 1; kk < NPB1; ++kk) {
          int v = __shfl(offreg, kk, 64);
          if (idx >= v) k = kk;
        }
        if (lane < cl) {  // phase A
          int e = eidp[idx];
          int es = eidx[e];
          int ea = read_eattr(eattr, flag, e);
          F3 Ps = ldp(pos, es), Pd = ldp(pos, n0 + k);
          float d1 = norm3(sub3(Ps, Pd));
          float c[8]; int j = 0; float f0, f1;
          if (ea) {
            float dc = fminf(fmaxf(d1, 0.05f), 10.f);
            j = rbf_coef(dc, c);
            f0 = 0.f; f1 = 0.f;
          } else {
#pragma unroll
            for (int kk = 0; kk < 8; ++kk) c[kk] = 0.f;
            f0 = d1; f1 = d1 * d1;
          }
          float* sp = sw + lane * 20;
          *reinterpret_cast<int4*>(sp) = int4{es, ea, j, k};
          *reinterpret_cast<float4*>(sp + 4) = float4{c[0], c[1], c[2], c[3]};
          *reinterpret_cast<float4*>(sp + 8) = float4{c[4], c[5], c[6], c[7]};
          *reinterpret_cast<float4*>(sp + 12) = float4{f0, f1, 0.f, 0.f};
        }
        // phase B (depth-2 pipeline)
        int4 I0{0, 0, 0, 0}, I1{0, 0, 0, 0};
        ushort4 gm0{0, 0, 0, 0}, gdd0{0, 0, 0, 0}, gm1{0, 0, 0, 0}, gdd1{0, 0, 0, 0};
        if (cl > 0) {
          I0 = *reinterpret_cast<const int4*>(sw);
          gm0 = g512(p_mid1, I0.x, c4);
          gdd0 = g512(p_dst, n0 + I0.w, c4);
        }
        if (cl > 1) {
          I1 = *reinterpret_cast<const int4*>(sw + 20);
          gm1 = g512(p_mid1, I1.x, c4);
          gdd1 = g512(p_dst, n0 + I1.w, c4);
        }
#pragma unroll 1
        for (int e = 0; e < cl; ++e) {
          int4 I2{0, 0, 0, 0};
          ushort4 gm2{0, 0, 0, 0}, gdd2{0, 0, 0, 0};
          if (e + 2 < cl) {
            I2 = *reinterpret_cast<const int4*>(sw + (e + 2) * 20);
            gm2 = g512(p_mid1, I2.x, c4);
            gdd2 = g512(p_dst, n0 + I2.w, c4);
          }
          while (kcur < I0.w) { FINALIZE(n0 + kcur, 0); ++kcur; }
          const float* sp = sw + e * 20;
          float4 dm = bsum;
          if (I0.y) {
            float4 cc0 = *reinterpret_cast<const float4*>(sp + 4);
            float4 cc1 = *reinterpret_cast<const float4*>(sp + 8);
            dm = rbf_apply(Wu + I0.z * DM + c4, cc0, cc1, dm);
          } else {
            float4 f = *reinterpret_cast<const float4*>(sp + 12);
            dm.x = fmaf(f.x, wb0.x, fmaf(f.y, wb1.x, dm.x));
            dm.y = fmaf(f.x, wb0.y, fmaf(f.y, wb1.y, dm.y));
            dm.z = fmaf(f.x, wb0.z, fmaf(f.y, wb1.z, dm.z));
            dm.w = fmaf(f.x, wb0.w, fmaf(f.y, wb1.w, dm.w));
          }
          float4 mv = cvt4(gm0), dd = cvt4(gdd0);
          float t0 = lk((mv.x + dd.x) * dm.x);
          float t1 = lk((mv.y + dd.y) * dm.y);
          float t2 = lk((mv.z + dd.z) * dm.z);
          float t3 = lk((mv.w + dd.w) * dm.w);
          float part = av.x * t0 + av.y * t1 + av.z * t2 + av.w * t3;
          part += __shfl_xor(part, 1, 64);
          part += __shfl_xor(part, 2, 64);
          part += __shfl_xor(part, 4, 64);
          float mn = fmaxf(mrun, part);
          float r = __expf(mrun - mn);
          float ew = __expf(part - mn);
          den = den * r + ew;
          acc.x = fmaf(acc.x, r, ew * mv.x);
          acc.y = fmaf(acc.y, r, ew * mv.y);
          acc.z = fmaf(acc.z, r, ew * mv.z);
          acc.w = fmaf(acc.w, r, ew * mv.w);
          mrun = mn;
          I0 = I1; gm0 = gm1; gdd0 = gdd1;
          I1 = I2; gm1 = gm2; gdd1 = gdd2;
        }
      }
      while (kcur < NPB1) { FINALIZE(n0 + kcur, 0); ++kcur; }
    } else if (b < NBT1 + NBT2) {
      // ================= hop 2: 8 nodes/batch =================
      const int n0 = ((int)b - NBT1) * NPB2;
      const int* offp = offall + (NN + 1);
      const int* eidp = eidall + NE;
      int offreg = offp[n0 + ((lane <= NPB2) ? lane : NPB2)];
      const int gs = __shfl(offreg, 0, 64);
      const int ge = __shfl(offreg, NPB2, 64);
      const float* Wu1 = fp + 142336;
      float4 av = ld4f(fp + 363520 + c4);
      float4 b1v = ld4f(fp + 152576 + c4), b2v = ld4f(fp + 163840 + c4);
      float4 bsum{b1v.x + b2v.x, b1v.y + b2v.y, b1v.z + b2v.z, b1v.w + b2v.w};
      float4 wa0 = ld4f(fp + 163328 + c4), wa1 = ld4f(fp + 163328 + DM + c4);
      int kcur = 0;
      float mrun = -INFINITY, den = 0.f;
      float4 acc{0.f, 0.f, 0.f, 0.f};
      for (int cb = gs; cb < ge; cb += 64) {
        const int cl = (ge - cb < 64) ? (ge - cb) : 64;
        const int idx = cb + lane;
        int k = 0;
#pragma unroll
        for (int kk = 1; kk < NPB2; ++kk) {
          int v = __shfl(offreg, kk, 64);
          if (idx >= v) k = kk;
        }
        if (lane < cl) {  // phase A
          int t = eidp[idx];
          int ts = tdx[t], tm = tdx[NT + t];
          F3 Ps = ldp(pos, ts), Pm = ldp(pos, tm), Pd = ldp(pos, n0 + k);
          float d2 = fminf(fmaxf(norm3(sub3(Ps, Pd)), 0.05f), 10.f);
          float c[8];
          int j = rbf_coef(d2, c);
          float ang = angle_at(Ps, Pm, Pd);
          float* sp = sw + lane * 20;
          *reinterpret_cast<int4*>(sp) = int4{ts, tm, j, k};
          *reinterpret_cast<float4*>(sp + 4) = float4{c[0], c[1], c[2], c[3]};
          *reinterpret_cast<float4*>(sp + 8) = float4{c[4], c[5], c[6], c[7]};
          *reinterpret_cast<float4*>(sp + 12) = float4{ang, ang * ang, 0.f, 0.f};
        }
        // phase B (depth-2 pipeline)
        int4 I0{0, 0, 0, 0}, I1{0, 0, 0, 0};
        ushort4 g00{0, 0, 0, 0}, g10{0, 0, 0, 0}, gdd0{0, 0, 0, 0};
        ushort4 g01{0, 0, 0, 0}, g11{0, 0, 0, 0}, gdd1{0, 0, 0, 0};
        if (cl > 0) {
          I0 = *reinterpret_cast<const int4*>(sw);
          g00 = g512(p_mid2, I0.x, c4);
          g10 = g512(p_mid1, I0.y, c4);
          gdd0 = g512(p_dst, n0 + I0.w, c4);
        }
        if (cl > 1) {
          I1 = *reinterpret_cast<const int4*>(sw + 20);
          g01 = g512(p_mid2, I1.x, c4);
          g11 = g512(p_mid1, I1.y, c4);
          gdd1 = g512(p_dst, n0 + I1.w, c4);
        }
#pragma unroll 1
        for (int e = 0; e < cl; ++e) {
          int4 I2{0, 0, 0, 0};
          ushort4 g02{0, 0, 0, 0}, g12{0, 0, 0, 0}, gdd2{0, 0, 0, 0};
          if (e + 2 < cl) {
            I2 = *reinterpret_cast<const int4*>(sw + (e + 2) * 20);
            g02 = g512(p_mid2, I2.x, c4);
            g12 = g512(p_mid1, I2.y, c4);
            gdd2 = g512(p_dst, n0 + I2.w, c4);
          }
          while (kcur < I0.w) { FINALIZE(n0 + kcur, 256); ++kcur; }
          const float* sp = sw + e * 20;
          float4 cc0 = *reinterpret_cast<const float4*>(sp + 4);
          float4 cc1 = *reinterpret_cast<const float4*>(sp + 8);
          float4 f = *reinterpret_cast<const float4*>(sp + 12);
          float4 dm;
          dm.x = fmaf(f.x, wa0.x, fmaf(f.y, wa1.x, bsum.x));
          dm.y = fmaf(f.x, wa0.y, fmaf(f.y, wa1.y, bsum.y));
          dm.z = fmaf(f.x, wa0.z, fmaf(f.y, wa1.z, bsum.z));
          dm.w = fmaf(f.x, wa0.w, fmaf(f.y, wa1.w, bsum.w));
          dm = rbf_apply(Wu1 + I0.z * DM + c4, cc0, cc1, dm);
          float4 v0 = cvt4(g00), v2 = cvt4(g10), dd = cvt4(gdd0);
          float t0 = lk((v0.x + dd.x + v2.x) * dm.x);
          float t1 = lk((v0.y + dd.y + v2.y) * dm.y);
          float t2 = lk((v0.z + dd.z + v2.z) * dm.z);
          float t3 = lk((v0.w + dd.w + v2.w) * dm.w);
          float part = av.x * t0 + av.y * t1 + av.z * t2 + av.w * t3;
          part += __shfl_xor(part, 1, 64);
          part += __shfl_xor(part, 2, 64);
          part += __shfl_xor(part, 4, 64);
          float mn = fmaxf(mrun, part);
          float r = __expf(mrun - mn);
          float ew = __expf(part - mn);
          den = den * r + ew;
          acc.x = fmaf(acc.x, r, ew * v0.x);
          acc.y = fmaf(acc.y, r, ew * v0.y);
          acc.z = fmaf(acc.z, r, ew * v0.z);
          acc.w = fmaf(acc.w, r, ew * v0.w);
          mrun = mn;
          I0 = I1; g00 = g01; g10 = g11; gdd0 = gdd1;
          I1 = I2; g01 = g02; g11 = g12; gdd1 = gdd2;
        }
      }
      while (kcur < NPB2) { FINALIZE(n0 + kcur, 256); ++kcur; }
    } else {
      // ================= hop 3: 16 nodes/batch =================
      const int n0 = ((int)b - NBT1 - NBT2) * NPB3;
      const int* offp = offall + 2 * (NN + 1);
      const int* eidp = eidall + NE + NT;
      int offreg = offp[n0 + ((lane <= NPB3) ? lane : NPB3)];
      const int gs = __shfl(offreg, 0, 64);
      const int ge = __shfl(offreg, NPB3, 64);
      const float* Wu2 = fp + 152832;
      const float* Wd = fp + 164096;
      float4 av = ld4f(fp + 363776 + c4);
      float4 b1v = ld4f(fp + 163072 + c4), b2v = ld4f(fp + 165632 + c4);
      float4 bsum{b1v.x + b2v.x, b1v.y + b2v.y, b1v.z + b2v.z, b1v.w + b2v.w};
      float4 wd0 = ld4f(Wd + c4), wd1 = ld4f(Wd + DM + c4), wd2 = ld4f(Wd + 2 * DM + c4);
      float4 wd3 = ld4f(Wd + 3 * DM + c4), wd4 = ld4f(Wd + 4 * DM + c4), wd5 = ld4f(Wd + 5 * DM + c4);
      int kcur = 0;
      float mrun = -INFINITY, den = 0.f;
      float4 acc{0.f, 0.f, 0.f, 0.f};
      for (int cb = gs; cb < ge; cb += 64) {
        const int cl = (ge - cb < 64) ? (ge - cb) : 64;
        const int idx = cb + lane;
        int k = 0;
#pragma unroll
        for (int kk = 1; kk < NPB3; ++kk) {
          int v = __shfl(offreg, kk, 64);
          if (idx >= v) k = kk;
        }
        if (lane < cl) {  // phase A (k stored in int4.w; j stored in float slot)
          int q = eidp[idx];
          int qs = qdx[q], q2 = qdx[NQ + q], q1 = qdx[2 * NQ + q];
          F3 P0 = ldp(pos, qs), P1 = ldp(pos, q2), P2 = ldp(pos, q1);
          F3 Pd = ldp(pos, n0 + k);
          float d3 = fminf(fmaxf(norm3(sub3(P0, Pd)), 0.05f), 10.f);
          float c[8];
          int j = rbf_coef(d3, c);
          float a1f = angle_at(P0, P1, P2);
          float a2f = angle_at(P1, P2, Pd);
          float dh = dihedral_f(P0, P1, P2, Pd);
          float* sp = sw + lane * 20;
          *reinterpret_cast<int4*>(sp) = int4{qs, q2, q1, k};
          *reinterpret_cast<float4*>(sp + 4) = float4{c[0], c[1], c[2], c[3]};
          *reinterpret_cast<float4*>(sp + 8) = float4{c[4], c[5], c[6], c[7]};
          *reinterpret_cast<float4*>(sp + 12) = float4{a1f, a1f * a1f, a2f, a2f * a2f};
          *reinterpret_cast<float4*>(sp + 16) = float4{dh, dh * dh, __int_as_float(j), 0.f};
        }
        // phase B (depth-2 pipeline)
        int4 I0{0, 0, 0, 0}, I1{0, 0, 0, 0};
        ushort4 g00{0, 0, 0, 0}, g10{0, 0, 0, 0}, g20{0, 0, 0, 0}, gdd0{0, 0, 0, 0};
        ushort4 g01{0, 0, 0, 0}, g11{0, 0, 0, 0}, g21{0, 0, 0, 0}, gdd1{0, 0, 0, 0};
        if (cl > 0) {
          I0 = *reinterpret_cast<const int4*>(sw);
          g00 = g512(p_src, I0.x, c4);
          g10 = g512(p_mid2, I0.y, c4);
          g20 = g512(p_mid1, I0.z, c4);
          gdd0 = g512(p_dst, n0 + I0.w, c4);
        }
        if (cl > 1) {
          I1 = *reinterpret_cast<const int4*>(sw + 20);
          g01 = g512(p_src, I1.x, c4);
          g11 = g512(p_mid2, I1.y, c4);
          g21 = g512(p_mid1, I1.z, c4);
          gdd1 = g512(p_dst, n0 + I1.w, c4);
        }
#pragma unroll 1
        for (int e = 0; e < cl; ++e) {
          int4 I2{0, 0, 0, 0};
          ushort4 g02{0, 0, 0, 0}, g12{0, 0, 0, 0}, g22{0, 0, 0, 0}, gdd2{0, 0, 0, 0};
          if (e + 2 < cl) {
            I2 = *reinterpret_cast<const int4*>(sw + (e + 2) * 20);
            g02 = g512(p_src, I2.x, c4);
            g12 = g512(p_mid2, I2.y, c4);
            g22 = g512(p_mid1, I2.z, c4);
            gdd2 = g512(p_dst, n0 + I2.w, c4);
          }
          while (kcur < I0.w) { FINALIZE(n0 + kcur, 512); ++kcur; }
          const float* sp = sw + e * 20;
          float4 cc0 = *reinterpret_cast<const float4*>(sp + 4);
          float4 cc1 = *reinterpret_cast<const float4*>(sp + 8);
          float4 f = *reinterpret_cast<const float4*>(sp + 12);
          float4 fb2 = *reinterpret_cast<const float4*>(sp + 16);
          int j = __float_as_int(fb2.z);
          float4 dm;
          dm.x = bsum.x + f.x * wd0.x + f.y * wd1.x + f.z * wd2.x + f.w * wd3.x + fb2.x * wd4.x + fb2.y * wd5.x;
          dm.y = bsum.y + f.x * wd0.y + f.y * wd1.y + f.z * wd2.y + f.w * wd3.y + fb2.x * wd4.y + fb2.y * wd5.y;
          dm.z = bsum.z + f.x * wd0.z + f.y * wd1.z + f.z * wd2.z + f.w * wd3.z + fb2.x * wd4.z + fb2.y * wd5.z;
          dm.w = bsum.w + f.x * wd0.w + f.y * wd1.w + f.z * wd2.w + f.w * wd3.w + fb2.x * wd4.w + fb2.y * wd5.w;
          dm = rbf_apply(Wu2 + j * DM + c4, cc0, cc1, dm);
          float4 v0 = cvt4(g00), v1 = cvt4(g10), v2 = cvt4(g20), dd = cvt4(gdd0);
          float t0 = lk((v0.x + v1.x + v2.x + dd.x) * dm.x);
          float t1 = lk((v0.y + v1.y + v2.y + dd.y) * dm.y);
          float t2 = lk((v0.z + v1.z + v2.z + dd.z) * dm.z);
          float t3 = lk((v0.w + v1.w + v2.w + dd.w) * dm.w);
          float part = av.x * t0 + av.y * t1 + av.z * t2 + av.w * t3;
          part += __shfl_xor(part, 1, 64);
          part += __shfl_xor(part, 2, 64);
          part += __shfl_xor(part, 4, 64);
          float mn = fmaxf(mrun, part);
          float r = __expf(mrun - mn);
          float ew = __expf(part - mn);
          den = den * r + ew;
          acc.x = fmaf(acc.x, r, ew * v0.x);
          acc.y = fmaf(acc.y, r, ew * v0.y);
          acc.z = fmaf(acc.z, r, ew * v0.z);
          acc.w = fmaf(acc.w, r, ew * v0.w);
          mrun = mn;
          I0 = I1; g00 = g01; g10 = g11; g20 = g21; gdd0 = gdd1;
          I1 = I2; g01 = g02; g11 = g12; g21 = g22; gdd1 = gdd2;
        }
      }
      while (kcur < NPB3) { FINALIZE(n0 + kcur, 512); ++kcur; }
    }
  }
}

// ---- MFMA output GEMM + LayerNorm + PReLU ----
__global__ __launch_bounds__(256) void gemm_mfma_ln(
    const u16* __restrict__ Abuf, const u16* __restrict__ Xs,
    const u16* __restrict__ wswz, const float* __restrict__ fp,
    float* __restrict__ outp) {
  __shared__ float sS[4][32], sQ[4][32], sMu[32], sRs[32];
  const int tid = threadIdx.x;
  const int wid = tid >> 6, lane = tid & 63;
  const int g = lane >> 4, l15 = lane & 15;
  const int m0 = blockIdx.x * 32;
  const int cb = wid * 64;

  f32x4 acc[2][4];
#pragma unroll
  for (int nf = 0; nf < 4; ++nf) {
    int c = cb + nf * 16 + l15;
    float bs = fp[231424 + c] + fp[297216 + c] + fp[363008 + c] + fp[396800 + c];
    acc[0][nf] = f32x4{bs, bs, bs, bs};
    acc[1][nf] = f32x4{bs, bs, bs, bs};
  }
  int rr0 = m0 + l15; if (rr0 > NN - 1) rr0 = NN - 1;
  int rr1 = m0 + 16 + l15; if (rr1 > NN - 1) rr1 = NN - 1;
  const u16* a0p = Abuf + (size_t)rr0 * 768 + g * 8;
  const u16* a1p = Abuf + (size_t)rr1 * 768 + g * 8;
  const u16* x0p = Xs + (size_t)rr0 * 256 + g * 8;
  const u16* x1p = Xs + (size_t)rr1 * 256 + g * 8;
  const u16* wb = wswz + (size_t)(wid * 4 * 64 + lane) * 8;

#pragma unroll 2
  for (int ks = 0; ks < 24; ++ks) {
    bf16x8 a0 = *reinterpret_cast<const bf16x8*>(a0p + ks * 32);
    bf16x8 a1 = *reinterpret_cast<const bf16x8*>(a1p + ks * 32);
#pragma unroll
    for (int nf = 0; nf < 4; ++nf) {
      bf16x8 bh = *reinterpret_cast<const bf16x8*>(wb + (size_t)ks * 8192 + nf * 512);
      bf16x8 bl = *reinterpret_cast<const bf16x8*>(wb + (size_t)(ks + 24) * 8192 + nf * 512);
      acc[0][nf] = __builtin_amdgcn_mfma_f32_16x16x32_bf16(a0, bh, acc[0][nf], 0, 0, 0);
      acc[1][nf] = __builtin_amdgcn_mfma_f32_16x16x32_bf16(a1, bh, acc[1][nf], 0, 0, 0);
      acc[0][nf] = __builtin_amdgcn_mfma_f32_16x16x32_bf16(a0, bl, acc[0][nf], 0, 0, 0);
      acc[1][nf] = __builtin_amdgcn_mfma_f32_16x16x32_bf16(a1, bl, acc[1][nf], 0, 0, 0);
    }
  }
#pragma unroll
  for (int ks = 0; ks < 4; ++ks) {
    bf16x8 xh0 = *reinterpret_cast<const bf16x8*>(x0p + ks * 32);
    bf16x8 xh1 = *reinterpret_cast<const bf16x8*>(x1p + ks * 32);
    bf16x8 xl0 = *reinterpret_cast<const bf16x8*>(x0p + 128 + ks * 32);
    bf16x8 xl1 = *reinterpret_cast<const bf16x8*>(x1p + 128 + ks * 32);
#pragma unroll
    for (int nf = 0; nf < 4; ++nf) {
      bf16x8 bh = *reinterpret_cast<const bf16x8*>(wb + (size_t)(48 + ks) * 8192 + nf * 512);
      bf16x8 bl = *reinterpret_cast<const bf16x8*>(wb + (size_t)(52 + ks) * 8192 + nf * 512);
      acc[0][nf] = __builtin_amdgcn_mfma_f32_16x16x32_bf16(xh0, bh, acc[0][nf], 0, 0, 0);
      acc[1][nf] = __builtin_amdgcn_mfma_f32_16x16x32_bf16(xh1, bh, acc[1][nf], 0, 0, 0);
      acc[0][nf] = __builtin_amdgcn_mfma_f32_16x16x32_bf16(xh0, bl, acc[0][nf], 0, 0, 0);
      acc[1][nf] = __builtin_amdgcn_mfma_f32_16x16x32_bf16(xh1, bl, acc[1][nf], 0, 0, 0);
      acc[0][nf] = __builtin_amdgcn_mfma_f32_16x16x32_bf16(xl0, bh, acc[0][nf], 0, 0, 0);
      acc[1][nf] = __builtin_amdgcn_mfma_f32_16x16x32_bf16(xl1, bh, acc[1][nf], 0, 0, 0);
    }
  }

#pragma unroll
  for (int mf = 0; mf < 2; ++mf) {
#pragma unroll
    for (int reg = 0; reg < 4; ++reg) {
      float sp = acc[mf][0][reg] + acc[mf][1][reg] + acc[mf][2][reg] + acc[mf][3][reg];
      float qp = acc[mf][0][reg] * acc[mf][0][reg] + acc[mf][1][reg] * acc[mf][1][reg] +
                 acc[mf][2][reg] * acc[mf][2][reg] + acc[mf][3][reg] * acc[mf][3][reg];
      for (int m = 8; m; m >>= 1) {
        sp += __shfl_xor(sp, m, 64);
        qp += __shfl_xor(qp, m, 64);
      }
      if (l15 == 0) {
        sS[wid][mf * 16 + g * 4 + reg] = sp;
        sQ[wid][mf * 16 + g * 4 + reg] = qp;
      }
    }
  }
  __syncthreads();
  if (tid < 32) {
    float S = sS[0][tid] + sS[1][tid] + sS[2][tid] + sS[3][tid];
    float Q = sQ[0][tid] + sQ[1][tid] + sQ[2][tid] + sQ[3][tid];
    float mu = S * (1.f / 256.f);
    float var = fmaxf(Q * (1.f / 256.f) - mu * mu, 0.f);
    sMu[tid] = mu;
    sRs[tid] = rsqrtf(var + 1e-5f);
  }
  __syncthreads();
  float pw = fp[397568];
#pragma unroll
  for (int nf = 0; nf < 4; ++nf) {
    int c = cb + nf * 16 + l15;
    float gc = fp[397056 + c], bc = fp[397312 + c];
#pragma unroll
    for (int mf = 0; mf < 2; ++mf) {
#pragma unroll
      for (int reg = 0; reg < 4; ++reg) {
        int rl = mf * 16 + g * 4 + reg;
        int row = m0 + rl;
        if (row < NN) {
          float y = (acc[mf][nf][reg] - sMu[rl]) * sRs[rl] * gc + bc;
          outp[(size_t)row * 256 + c] = (y >= 0.f) ? y : pw * y;
        }
      }
    }
  }
}

extern "C" void kernel_launch(void* const* d_in, const int* in_sizes, int n_in,
                              void* d_out, int out_size, void* d_ws, size_t ws_size,
                              hipStream_t stream) {
  const void* x = d_in[0];
  const void* pos = d_in[1];
  const int* eidx = (const int*)d_in[2];
  const int* tdx = (const int*)d_in[3];
  const int* qdx = (const int*)d_in[4];
  const void* eattr = d_in[5];
  float* outp = (float*)d_out;

  // workspace layout (~214 MB; proven safe <= ~221 MB)
  u16* p_src = (u16*)d_ws;
  u16* p_mid2 = p_src + (size_t)NN * DM;
  u16* p_mid1 = p_mid2 + (size_t)NN * DM;
  u16* p_dst = p_mid1 + (size_t)NN * DM;
  u16* Abuf = p_dst + (size_t)NN * DM;                // NN x 768 bf16 (A1|A2|A3)
  u16* Xs = Abuf + (size_t)NN * 768;                  // NN x 256 bf16 (xhi|xlo)
  float* posf = (float*)(Xs + (size_t)NN * 256);      // NN*3
  float* fp = posf + (size_t)NN * 3;                  // staged params
  u16* wswz = (u16*)(fp + TOTALP + 3);                // out-GEMM swizzled W
  u16* pswz = wswz + WSWZ_N;                          // proj swizzled W
  int* deg = (int*)(pswz + PSWZ_N);                   // 3*NN
  int* off = deg + 3 * NN;                            // 3*(NN+1)
  int* cur = off + 3 * (NN + 1);                      // 3*NN
  int* eid = cur + 3 * NN;                            // NE+NT+NQ
  u32* gmax = (u32*)(eid + NE + NT + NQ);
  int* flags = (int*)(gmax + 4);

  init_detect<<<1, 256, 0, stream>>>((const u32*)eattr, (const u32*)d_in[33], gmax, flags);

  PtrTab tab;
  for (int i = 0; i < 30; ++i) tab.p[i] = d_in[6 + i];
  convert_params<<<512, 256, 0, stream>>>(tab, flags, fp);
  convert_pos<<<587, 256, 0, stream>>>(pos, flags, posf);
  swizzle_w<<<WSWZ_N / 256, 256, 0, stream>>>(fp, wswz);
  swizzle_pw<<<PSWZ_N / 256, 256, 0, stream>>>(fp, pswz);

  // x hi/lo split (dedicated buffer; feeds both proj_mfma and gemm_mfma_ln)
  xsplit<<<2048, 256, 0, stream>>>(x, flags, Xs);

  // MFMA 4-way projection + PE
  proj_mfma<<<(NN + 31) / 32, 256, 0, stream>>>(Xs, pswz, p_src, p_mid2, p_mid1, p_dst);

  // CSR for all 3 hops
  hipMemsetAsync(deg, 0, (size_t)3 * NN * 4, stream);
  hist_all<<<1024, 256, 0, stream>>>(eidx + NE, tdx + 2 * NT, qdx + 3 * NQ, deg);
  scan_all<<<3, 1024, 0, stream>>>(deg, off, cur);
  fill_all<<<1024, 256, 0, stream>>>(eidx + NE, tdx + 2 * NT, qdx + 3 * NQ, cur, eid);

  // fused score + per-node softmax + aggregate (2-wave workgroups)
  fused_score_agg<<<4096, 128, 0, stream>>>(posf, eidx, tdx, qdx, eattr, flags,
                                            p_src, p_mid2, p_mid1, p_dst, fp,
                                            off, eid, gmax, Abuf);

  // MFMA output GEMM + LN + PReLU
  gemm_mfma_ln<<<(NN + 31) / 32, 256, 0, stream>>>(Abuf, Xs, wswz, fp, outp);
}

// Round 12
// 1098.540 us; speedup vs baseline: 1.1986x; 1.0034x over previous
//
#include <hip/hip_runtime.h>

#define NN 50000
#define NE 400000
#define NT 300000
#define NQ 200000
#define DM 256
#define FIN 128
#define NRBF 40
#define BETA_RBF 40.0f
#define TOTALP 397569

#define WSWZ_N (56 * 16 * 64 * 8)  // 458752 u16 swizzled-weight elements (out GEMM)
#define PSWZ_N (4 * 2 * 4 * 16 * 64 * 8)  // 262144 u16 swizzled proj weights

// fused-pass batching: consecutive nodes per wave, ~64 edges/batch
#define NPB1 8
#define NPB2 8
#define NPB3 16
#define NBT1 (NN / NPB1)          // 6250
#define NBT2 (NN / NPB2)          // 6250
#define NBT3 (NN / NPB3)          // 3125
#define NBT (NBT1 + NBT2 + NBT3)  // 15625

typedef unsigned int u32;
typedef unsigned short u16;
typedef __attribute__((ext_vector_type(8))) short bf16x8;
typedef __attribute__((ext_vector_type(4))) float f32x4;

// ---- bf16 helpers ----
static __device__ __forceinline__ float bf2f(u16 h) {
  return __uint_as_float(((u32)h) << 16);
}
static __device__ __forceinline__ u16 f2bf(float f) {
  u32 u = __float_as_uint(f);
  u32 r = (u + 0x7FFFu + ((u >> 16) & 1u)) >> 16;  // RNE
  return (u16)r;
}
static __device__ __forceinline__ float4 ld4f(const float* p) {
  return *reinterpret_cast<const float4*>(p);
}
static __device__ __forceinline__ float ldsc(const void* p, int isf, size_t i) {
  return isf ? ((const float*)p)[i] : bf2f(((const u16*)p)[i]);
}
static __device__ __forceinline__ float lk(float t) { return t >= 0.f ? t : 0.2f * t; }
static __device__ __forceinline__ u32 f2o(float f) {
  u32 u = __float_as_uint(f);
  return (u & 0x80000000u) ? ~u : (u | 0x80000000u);
}

struct F3 { float x, y, z; };
static __device__ __forceinline__ F3 ldp(const float* pos, int i) {
  return F3{pos[3 * i], pos[3 * i + 1], pos[3 * i + 2]};
}
static __device__ __forceinline__ F3 sub3(F3 a, F3 b) { return F3{a.x - b.x, a.y - b.y, a.z - b.z}; }
static __device__ __forceinline__ float dot3(F3 a, F3 b) { return a.x * b.x + a.y * b.y + a.z * b.z; }
static __device__ __forceinline__ F3 cross3(F3 a, F3 b) {
  return F3{a.y * b.z - a.z * b.y, a.z * b.x - a.x * b.z, a.x * b.y - a.y * b.x};
}
static __device__ __forceinline__ float norm3(F3 v) { return sqrtf(dot3(v, v) + 1e-12f); }
static __device__ __forceinline__ float angle_at(F3 a, F3 m, F3 b) {
  F3 u = sub3(a, m), v = sub3(b, m);
  float c = dot3(u, v) / (norm3(u) * norm3(v) + 1e-12f);
  c = fminf(fmaxf(c, -1.f + 1e-7f), 1.f - 1e-7f);
  return acosf(c);
}
static __device__ __forceinline__ float dihedral_f(F3 p0, F3 p1, F3 p2, F3 p3) {
  F3 b1 = sub3(p1, p0), b2 = sub3(p2, p1), b3 = sub3(p3, p2);
  F3 n1 = cross3(b1, b2), n2 = cross3(b2, b3);
  float nb2 = norm3(b2) + 1e-12f;
  F3 b2n{b2.x / nb2, b2.y / nb2, b2.z / nb2};
  F3 m1 = cross3(n1, b2n);
  return atan2f(dot3(m1, n2), dot3(n1, n2) + 1e-12f);
}

// phase A: scalar RBF window + 8 coefficients for ONE edge (per lane).
static __device__ __forceinline__ int rbf_coef(float d, float* c) {
  int j = (int)floorf(d * 4.0f) - 3;
  j = (j < 0) ? 0 : ((j > NRBF - 8) ? (NRBF - 8) : j);
  float t0 = d - 0.25f * (float)j;
#pragma unroll
  for (int k = 0; k < 8; ++k) {
    float t = t0 - 0.25f * (float)k;
    c[k] = __expf(-BETA_RBF * t * t);
  }
  return j;
}

// phase B: dm += sum_k c_k * Wu[j+k][c4..c4+3]
static __device__ __forceinline__ float4 rbf_apply(const float* __restrict__ base,
                                                   float4 c0, float4 c1, float4 dm) {
  float4 w;
  w = ld4f(base + 0 * DM);
  dm.x = fmaf(c0.x, w.x, dm.x); dm.y = fmaf(c0.x, w.y, dm.y);
  dm.z = fmaf(c0.x, w.z, dm.z); dm.w = fmaf(c0.x, w.w, dm.w);
  w = ld4f(base + 1 * DM);
  dm.x = fmaf(c0.y, w.x, dm.x); dm.y = fmaf(c0.y, w.y, dm.y);
  dm.z = fmaf(c0.y, w.z, dm.z); dm.w = fmaf(c0.y, w.w, dm.w);
  w = ld4f(base + 2 * DM);
  dm.x = fmaf(c0.z, w.x, dm.x); dm.y = fmaf(c0.z, w.y, dm.y);
  dm.z = fmaf(c0.z, w.z, dm.z); dm.w = fmaf(c0.z, w.w, dm.w);
  w = ld4f(base + 3 * DM);
  dm.x = fmaf(c0.w, w.x, dm.x); dm.y = fmaf(c0.w, w.y, dm.y);
  dm.z = fmaf(c0.w, w.z, dm.z); dm.w = fmaf(c0.w, w.w, dm.w);
  w = ld4f(base + 4 * DM);
  dm.x = fmaf(c1.x, w.x, dm.x); dm.y = fmaf(c1.x, w.y, dm.y);
  dm.z = fmaf(c1.x, w.z, dm.z); dm.w = fmaf(c1.x, w.w, dm.w);
  w = ld4f(base + 5 * DM);
  dm.x = fmaf(c1.y, w.x, dm.x); dm.y = fmaf(c1.y, w.y, dm.y);
  dm.z = fmaf(c1.y, w.z, dm.z); dm.w = fmaf(c1.y, w.w, dm.w);
  w = ld4f(base + 6 * DM);
  dm.x = fmaf(c1.z, w.x, dm.x); dm.y = fmaf(c1.z, w.y, dm.y);
  dm.z = fmaf(c1.z, w.z, dm.z); dm.w = fmaf(c1.z, w.w, dm.w);
  w = ld4f(base + 7 * DM);
  dm.x = fmaf(c1.w, w.x, dm.x); dm.y = fmaf(c1.w, w.y, dm.y);
  dm.z = fmaf(c1.w, w.z, dm.z); dm.w = fmaf(c1.w, w.w, dm.w);
  return dm;
}

static __device__ __forceinline__ ushort4 g512(const u16* p, int idx, int c4) {
  return *reinterpret_cast<const ushort4*>(p + (size_t)(u32)idx * DM + c4);
}
static __device__ __forceinline__ float4 cvt4(ushort4 v) {
  return float4{bf2f(v.x), bf2f(v.y), bf2f(v.z), bf2f(v.w)};
}

// param staging table: 30 tensors, cumulative offsets
__device__ const int g_off[31] = {
  0, 32768, 65536, 98304, 131072, 131584, 131840, 142080, 142336, 152576,
  152832, 163072, 163328, 163840, 164096, 165632, 165888, 231424, 231680,
  297216, 297472, 363008, 363264, 363520, 363776, 364032, 396800, 397056,
  397312, 397568, 397569};
struct PtrTab { const void* p[30]; };

// ---- init ----
__global__ __launch_bounds__(256) void init_detect(const u32* __restrict__ aw,
                                                   const u32* __restrict__ lng,
                                                   u32* __restrict__ gmax,
                                                   int* __restrict__ flags) {
  __shared__ int s_int, s_f32, s_bf;
  if (threadIdx.x == 0) { s_int = 1; s_f32 = 1; s_bf = 1; }
  __syncthreads();
  int li = 1, lf = 1, lb = 1;
  for (int i = threadIdx.x; i < 1024; i += 256) {
    u32 w = aw[i];
    if (w > 1u) li = 0;
    if (w != 0u && w != 0x3F800000u) lf = 0;
    u32 h0 = w & 0xFFFFu, h1 = w >> 16;
    if ((h0 != 0u && h0 != 0x3F80u) || (h1 != 0u && h1 != 0x3F80u)) lb = 0;
  }
  if (!li) atomicAnd(&s_int, 0);
  if (!lf) atomicAnd(&s_f32, 0);
  if (!lb) atomicAnd(&s_bf, 0);
  __syncthreads();
  if (threadIdx.x == 0) {
    flags[0] = s_int ? 0 : (s_f32 ? 2 : (s_bf ? 3 : 1));
    flags[1] = ((lng[0] & 0xFFFFu) == 0x3F80u) ? 0 : 1;  // 1 = fp32 inputs
    gmax[0] = f2o(-INFINITY);
    gmax[1] = f2o(-INFINITY);
    gmax[2] = f2o(-INFINITY);
    gmax[3] = 0u;  // fused-pass work-steal counter
  }
}

__global__ __launch_bounds__(256) void convert_params(PtrTab tab,
                                                      const int* __restrict__ flags,
                                                      float* __restrict__ dst) {
  const int isf = flags[1];
  for (int i = blockIdx.x * blockDim.x + threadIdx.x; i < TOTALP;
       i += gridDim.x * blockDim.x) {
    int t = 0;
    while (i >= g_off[t + 1]) ++t;
    dst[i] = ldsc(tab.p[t], isf, i - g_off[t]);
  }
}
__global__ __launch_bounds__(256) void convert_pos(const void* __restrict__ pos,
                                                   const int* __restrict__ flags,
                                                   float* __restrict__ posf) {
  const int isf = flags[1];
  for (int i = blockIdx.x * blockDim.x + threadIdx.x; i < NN * 3;
       i += gridDim.x * blockDim.x)
    posf[i] = ldsc(pos, isf, i);
}

static __device__ __forceinline__ int read_eattr(const void* p, int flag, int e) {
  if (flag == 1) return ((const unsigned char*)p)[e];
  if (flag == 2) return (((const float*)p)[e] != 0.f);
  if (flag == 3) return (((const u16*)p)[e] != 0);
  return ((const int*)p)[e];
}

// ---- weight swizzle for output-GEMM MFMA B-fragments ----
__global__ __launch_bounds__(256) void swizzle_w(const float* __restrict__ fp,
                                                 u16* __restrict__ wswz) {
  int idx = blockIdx.x * 256 + threadIdx.x;
  if (idx >= WSWZ_N) return;
  int jj = idx & 7;
  int lane = (idx >> 3) & 63;
  int nb = (idx >> 9) & 15;
  int s = idx >> 13;
  int kl = (lane >> 4) * 8 + jj;
  int col = nb * 16 + (lane & 15);
  float w;
  int lo;
  if (s < 48) {
    int sr = (s < 24) ? s : (s - 24);
    lo = (s >= 24);
    int K = sr * 32 + kl;
    int base = (K < 256) ? 165888 : ((K < 512) ? 231680 : 297472);
    w = fp[base + (K & 255) * 256 + col];
  } else {
    int sr = (s < 52) ? (s - 48) : (s - 52);
    lo = (s >= 52);
    int K = sr * 32 + kl;
    w = fp[364032 + K * 256 + col];
  }
  u16 hi = f2bf(w);
  wswz[idx] = lo ? f2bf(w - bf2f(hi)) : hi;
}

// ---- projection weight swizzle: 4 mats (src,mid2,mid1,dst) x hi/lo x K=128 ----
__global__ __launch_bounds__(256) void swizzle_pw(const float* __restrict__ fp,
                                                  u16* __restrict__ pswz) {
  int idx = blockIdx.x * 256 + threadIdx.x;
  if (idx >= PSWZ_N) return;
  int jj = idx & 7;
  int lane = (idx >> 3) & 63;
  int nb = (idx >> 9) & 15;
  int ks = (idx >> 13) & 3;
  int hilo = (idx >> 15) & 1;
  int mat = idx >> 16;
  const int mb[4] = {0, 98304, 65536, 32768};  // W_src, W_mid2, W_mid1, W_dst
  int K = ks * 32 + (lane >> 4) * 8 + jj;
  int col = nb * 16 + (lane & 15);
  float w = fp[mb[mat] + K * 256 + col];
  u16 hi = f2bf(w);
  pswz[idx] = hilo ? f2bf(w - bf2f(hi)) : hi;
}

// ---- x hi/lo split into Xs[NN][256] (cols 0..127 hi, 128..255 lo) ----
__global__ __launch_bounds__(256) void xsplit(const void* __restrict__ x,
                                              const int* __restrict__ flags,
                                              u16* __restrict__ Xs) {
  const int isf = flags[1];
  for (int i = blockIdx.x * blockDim.x + threadIdx.x; i < NN * FIN;
       i += gridDim.x * blockDim.x) {
    int n = i >> 7, k = i & 127;
    float v = ldsc(x, isf, i);
    u16 hi = f2bf(v);
    Xs[(size_t)n * 256 + k] = hi;
    Xs[(size_t)n * 256 + 128 + k] = f2bf(v - bf2f(hi));
  }
}

// ---- MFMA 4-way projection + sinusoidal PE ----
__global__ __launch_bounds__(256) void proj_mfma(
    const u16* __restrict__ Xs, const u16* __restrict__ pswz,
    u16* __restrict__ o0, u16* __restrict__ o1,
    u16* __restrict__ o2, u16* __restrict__ o3) {
  const int tid = threadIdx.x;
  const int wid = tid >> 6, lane = tid & 63;
  const int g = lane >> 4, l15 = lane & 15;
  const int m0 = blockIdx.x * 32;
  const int cb = wid * 64;

  int rr0 = m0 + l15; if (rr0 > NN - 1) rr0 = NN - 1;
  int rr1 = m0 + 16 + l15; if (rr1 > NN - 1) rr1 = NN - 1;
  const u16* x0p = Xs + (size_t)rr0 * 256 + g * 8;
  const u16* x1p = Xs + (size_t)rr1 * 256 + g * 8;

  bf16x8 xh0[4], xh1[4], xl0[4], xl1[4];
#pragma unroll
  for (int ks = 0; ks < 4; ++ks) {
    xh0[ks] = *reinterpret_cast<const bf16x8*>(x0p + ks * 32);
    xh1[ks] = *reinterpret_cast<const bf16x8*>(x1p + ks * 32);
    xl0[ks] = *reinterpret_cast<const bf16x8*>(x0p + 128 + ks * 32);
    xl1[ks] = *reinterpret_cast<const bf16x8*>(x1p + 128 + ks * 32);
  }

  u16* const outs[4] = {o0, o1, o2, o3};
#pragma unroll 1
  for (int mat = 0; mat < 4; ++mat) {
    f32x4 acc[2][4];
#pragma unroll
    for (int nf = 0; nf < 4; ++nf) {
      int c = cb + nf * 16 + l15;
      float dv = expf(-logf(10000.f) * (float)(c & ~1) / 256.f);
      float ang = (float)mat * dv;
      float p = (c & 1) ? cosf(ang) : sinf(ang);
      acc[0][nf] = f32x4{p, p, p, p};
      acc[1][nf] = f32x4{p, p, p, p};
    }
    const u16* wbm = pswz + (size_t)mat * 65536 + (size_t)lane * 8;
#pragma unroll
    for (int ks = 0; ks < 4; ++ks) {
#pragma unroll
      for (int nf = 0; nf < 4; ++nf) {
        const u16* bbase = wbm + (size_t)ks * 8192 + (wid * 4 + nf) * 512;
        bf16x8 bh = *reinterpret_cast<const bf16x8*>(bbase);
        bf16x8 bl = *reinterpret_cast<const bf16x8*>(bbase + 32768);
        acc[0][nf] = __builtin_amdgcn_mfma_f32_16x16x32_bf16(xh0[ks], bh, acc[0][nf], 0, 0, 0);
        acc[1][nf] = __builtin_amdgcn_mfma_f32_16x16x32_bf16(xh1[ks], bh, acc[1][nf], 0, 0, 0);
        acc[0][nf] = __builtin_amdgcn_mfma_f32_16x16x32_bf16(xh0[ks], bl, acc[0][nf], 0, 0, 0);
        acc[1][nf] = __builtin_amdgcn_mfma_f32_16x16x32_bf16(xh1[ks], bl, acc[1][nf], 0, 0, 0);
        acc[0][nf] = __builtin_amdgcn_mfma_f32_16x16x32_bf16(xl0[ks], bh, acc[0][nf], 0, 0, 0);
        acc[1][nf] = __builtin_amdgcn_mfma_f32_16x16x32_bf16(xl1[ks], bh, acc[1][nf], 0, 0, 0);
      }
    }
    u16* op = outs[mat];
#pragma unroll
    for (int nf = 0; nf < 4; ++nf) {
      int c = cb + nf * 16 + l15;
#pragma unroll
      for (int mf = 0; mf < 2; ++mf) {
#pragma unroll
        for (int reg = 0; reg < 4; ++reg) {
          int row = m0 + mf * 16 + g * 4 + reg;
          if (row < NN) op[(size_t)row * 256 + c] = f2bf(acc[mf][nf][reg]);
        }
      }
    }
  }
}

// ---- fused CSR build over the 3 hops ----
__global__ __launch_bounds__(256) void hist_all(const int* __restrict__ ed,
                                                const int* __restrict__ td,
                                                const int* __restrict__ qd,
                                                int* __restrict__ deg) {
  const int M = NE + NT + NQ;
  for (int i = blockIdx.x * blockDim.x + threadIdx.x; i < M; i += gridDim.x * blockDim.x) {
    if (i < NE) atomicAdd(&deg[ed[i]], 1);
    else if (i < NE + NT) atomicAdd(&deg[NN + td[i - NE]], 1);
    else atomicAdd(&deg[2 * NN + qd[i - NE - NT]], 1);
  }
}
__global__ __launch_bounds__(1024) void scan_all(const int* __restrict__ degall,
                                                 int* __restrict__ offall,
                                                 int* __restrict__ curall) {
  __shared__ int part[1024];
  const int b = blockIdx.x;
  const int* deg = degall + (size_t)b * NN;
  int* off = offall + (size_t)b * (NN + 1);
  int* cur = curall + (size_t)b * NN;
  const int CH = (NN + 1023) / 1024;
  const int t = threadIdx.x;
  const int base = t * CH;
  int s = 0;
  for (int i = 0; i < CH; ++i) { int idx = base + i; if (idx < NN) s += deg[idx]; }
  part[t] = s;
  __syncthreads();
  for (int d = 1; d < 1024; d <<= 1) {
    int v = (t >= d) ? part[t - d] : 0;
    __syncthreads();
    part[t] += v;
    __syncthreads();
  }
  int run = (t == 0) ? 0 : part[t - 1];
  for (int i = 0; i < CH; ++i) {
    int idx = base + i;
    if (idx < NN) { off[idx] = run; cur[idx] = run; run += deg[idx]; }
  }
  if (t == 1023) off[NN] = run;
}
__global__ __launch_bounds__(256) void fill_all(const int* __restrict__ ed,
                                                const int* __restrict__ td,
                                                const int* __restrict__ qd,
                                                int* __restrict__ cur,
                                                int* __restrict__ eid) {
  const int M = NE + NT + NQ;
  for (int i = blockIdx.x * blockDim.x + threadIdx.x; i < M; i += gridDim.x * blockDim.x) {
    if (i < NE) {
      int p = atomicAdd(&cur[ed[i]], 1);
      eid[p] = i;
    } else if (i < NE + NT) {
      int il = i - NE;
      int p = atomicAdd(&cur[NN + td[il]], 1);
      eid[NE + p] = il;
    } else {
      int il = i - NE - NT;
      int p = atomicAdd(&cur[2 * NN + qd[il]], 1);
      eid[NE + NT + p] = il;
    }
  }
}

// finalize current node's online-softmax state into Abuf, reset state
#define FINALIZE(node, hopoff)                                         \
  {                                                                    \
    float inv = 1.f / (den + 1e-16f);                                  \
    ushort4 o;                                                         \
    o.x = f2bf(acc.x * inv); o.y = f2bf(acc.y * inv);                  \
    o.z = f2bf(acc.z * inv); o.w = f2bf(acc.w * inv);                  \
    *reinterpret_cast<ushort4*>(Abuf + (size_t)(node) * 768 +          \
                                (hopoff) + c4) = o;                    \
    den = 0.f; mrun = -INFINITY;                                       \
    acc = float4{0.f, 0.f, 0.f, 0.f};                                  \
  }

// ---- fused score + per-node softmax + aggregate, node-batched ----
// 4-wave workgroups (256 threads), waves fully independent (per-wave LDS slab,
// per-wave work-steal, no barriers). NO min-waves clause in launch_bounds —
// round-7's (256,4) capped VGPR at 64 and strangled the depth-2 pipeline;
// letting VGPR float to 112 (rounds 8/11) is worth ~65 us. Measured trend:
// 592 (4w/VGPR64) -> 527 (1w/112) -> 484 (2w/112); this tests 4w/112.
// NOTE: VGPR 112 sits just under the 128 hardware granule — adding register
// state (e.g. Wu prefetch) crosses it and HALVES occupancy (round-9 regression).
__global__ __launch_bounds__(256) void fused_score_agg(
    const float* __restrict__ pos,
    const int* __restrict__ eidx, const int* __restrict__ tdx, const int* __restrict__ qdx,
    const void* __restrict__ eattr, const int* __restrict__ flags,
    const u16* __restrict__ p_src, const u16* __restrict__ p_mid2,
    const u16* __restrict__ p_mid1, const u16* __restrict__ p_dst,
    const float* __restrict__ fp,
    const int* __restrict__ offall, const int* __restrict__ eidall,
    u32* __restrict__ gmax, u16* __restrict__ Abuf) {
  __shared__ __align__(16) float slds[4][64 * 20];
  const int lane = threadIdx.x & 63;
  float* sw = slds[(threadIdx.x >> 6) & 3];
  const int c4 = lane * 4;
  const int flag = flags[0];

  for (int it = 0; it <= NBT; ++it) {
    u32 bl = 0;
    if (lane == 0) bl = atomicAdd(gmax + 3, 1u);
    u32 b = (u32)__builtin_amdgcn_readfirstlane((int)bl);
    if (b >= NBT) break;

    if (b < NBT1) {
      // ================= hop 1: 8 nodes/batch =================
      const int n0 = (int)b * NPB1;
      const int* offp = offall;
      const int* eidp = eidall;
      int offreg = offp[n0 + ((lane <= NPB1) ? lane : NPB1)];
      const int gs = __shfl(offreg, 0, 64);
      const int ge = __shfl(offreg, NPB1, 64);
      const float* Wu = fp + 131840;
      float4 av = ld4f(fp + 363264 + c4);
      float4 bbv = ld4f(fp + 131584 + c4), buv = ld4f(fp + 142080 + c4);
      float4 bsum{bbv.x + buv.x, bbv.y + buv.y, bbv.z + buv.z, bbv.w + buv.w};
      float4 wb0 = ld4f(fp + 131072 + c4), wb1 = ld4f(fp + 131072 + DM + c4);
      int kcur = 0;
      float mrun = -INFINITY, den = 0.f;
      float4 acc{0.f, 0.f, 0.f, 0.f};
      for (int cb = gs; cb < ge; cb += 64) {
        const int cl = (ge - cb < 64) ? (ge - cb) : 64;
        const int idx = cb + lane;
        int k = 0;
#pragma unroll
        for (int kk = 1; kk < NPB1; ++kk) {
          int v = __shfl(offreg, kk, 64);
          if (idx >= v) k = kk;
        }
        if (lane < cl) {  // phase A
          int e = eidp[idx];
          int es = eidx[e];
          int ea = read_eattr(eattr, flag, e);
          F3 Ps = ldp(pos, es), Pd = ldp(pos, n0 + k);
          float d1 = norm3(sub3(Ps, Pd));
          float c[8]; int j = 0; float f0, f1;
          if (ea) {
            float dc = fminf(fmaxf(d1, 0.05f), 10.f);
            j = rbf_coef(dc, c);
            f0 = 0.f; f1 = 0.f;
          } else {
#pragma unroll
            for (int kk = 0; kk < 8; ++kk) c[kk] = 0.f;
            f0 = d1; f1 = d1 * d1;
          }
          float* sp = sw + lane * 20;
          *reinterpret_cast<int4*>(sp) = int4{es, ea, j, k};
          *reinterpret_cast<float4*>(sp + 4) = float4{c[0], c[1], c[2], c[3]};
          *reinterpret_cast<float4*>(sp + 8) = float4{c[4], c[5], c[6], c[7]};
          *reinterpret_cast<float4*>(sp + 12) = float4{f0, f1, 0.f, 0.f};
        }
        // phase B (depth-2 pipeline)
        int4 I0{0, 0, 0, 0}, I1{0, 0, 0, 0};
        ushort4 gm0{0, 0, 0, 0}, gdd0{0, 0, 0, 0}, gm1{0, 0, 0, 0}, gdd1{0, 0, 0, 0};
        if (cl > 0) {
          I0 = *reinterpret_cast<const int4*>(sw);
          gm0 = g512(p_mid1, I0.x, c4);
          gdd0 = g512(p_dst, n0 + I0.w, c4);
        }
        if (cl > 1) {
          I1 = *reinterpret_cast<const int4*>(sw + 20);
          gm1 = g512(p_mid1, I1.x, c4);
          gdd1 = g512(p_dst, n0 + I1.w, c4);
        }
#pragma unroll 1
        for (int e = 0; e < cl; ++e) {
          int4 I2{0, 0, 0, 0};
          ushort4 gm2{0, 0, 0, 0}, gdd2{0, 0, 0, 0};
          if (e + 2 < cl) {
            I2 = *reinterpret_cast<const int4*>(sw + (e + 2) * 20);
            gm2 = g512(p_mid1, I2.x, c4);
            gdd2 = g512(p_dst, n0 + I2.w, c4);
          }
          while (kcur < I0.w) { FINALIZE(n0 + kcur, 0); ++kcur; }
          const float* sp = sw + e * 20;
          float4 dm = bsum;
          if (I0.y) {
            float4 cc0 = *reinterpret_cast<const float4*>(sp + 4);
            float4 cc1 = *reinterpret_cast<const float4*>(sp + 8);
            dm = rbf_apply(Wu + I0.z * DM + c4, cc0, cc1, dm);
          } else {
            float4 f = *reinterpret_cast<const float4*>(sp + 12);
            dm.x = fmaf(f.x, wb0.x, fmaf(f.y, wb1.x, dm.x));
            dm.y = fmaf(f.x, wb0.y, fmaf(f.y, wb1.y, dm.y));
            dm.z = fmaf(f.x, wb0.z, fmaf(f.y, wb1.z, dm.z));
            dm.w = fmaf(f.x, wb0.w, fmaf(f.y, wb1.w, dm.w));
          }
          float4 mv = cvt4(gm0), dd = cvt4(gdd0);
          float t0 = lk((mv.x + dd.x) * dm.x);
          float t1 = lk((mv.y + dd.y) * dm.y);
          float t2 = lk((mv.z + dd.z) * dm.z);
          float t3 = lk((mv.w + dd.w) * dm.w);
          float part = av.x * t0 + av.y * t1 + av.z * t2 + av.w * t3;
          part += __shfl_xor(part, 1, 64);
          part += __shfl_xor(part, 2, 64);
          part += __shfl_xor(part, 4, 64);
          float mn = fmaxf(mrun, part);
          float r = __expf(mrun - mn);
          float ew = __expf(part - mn);
          den = den * r + ew;
          acc.x = fmaf(acc.x, r, ew * mv.x);
          acc.y = fmaf(acc.y, r, ew * mv.y);
          acc.z = fmaf(acc.z, r, ew * mv.z);
          acc.w = fmaf(acc.w, r, ew * mv.w);
          mrun = mn;
          I0 = I1; gm0 = gm1; gdd0 = gdd1;
          I1 = I2; gm1 = gm2; gdd1 = gdd2;
        }
      }
      while (kcur < NPB1) { FINALIZE(n0 + kcur, 0); ++kcur; }
    } else if (b < NBT1 + NBT2) {
      // ================= hop 2: 8 nodes/batch =================
      const int n0 = ((int)b - NBT1) * NPB2;
      const int* offp = offall + (NN + 1);
      const int* eidp = eidall + NE;
      int offreg = offp[n0 + ((lane <= NPB2) ? lane : NPB2)];
      const int gs = __shfl(offreg, 0, 64);
      const int ge = __shfl(offreg, NPB2, 64);
      const float* Wu1 = fp + 142336;
      float4 av = ld4f(fp + 363520 + c4);
      float4 b1v = ld4f(fp + 152576 + c4), b2v = ld4f(fp + 163840 + c4);
      float4 bsum{b1v.x + b2v.x, b1v.y + b2v.y, b1v.z + b2v.z, b1v.w + b2v.w};
      float4 wa0 = ld4f(fp + 163328 + c4), wa1 = ld4f(fp + 163328 + DM + c4);
      int kcur = 0;
      float mrun = -INFINITY, den = 0.f;
      float4 acc{0.f, 0.f, 0.f, 0.f};
      for (int cb = gs; cb < ge; cb += 64) {
        const int cl = (ge - cb < 64) ? (ge - cb) : 64;
        const int idx = cb + lane;
        int k = 0;
#pragma unroll
        for (int kk = 1; kk < NPB2; ++kk) {
          int v = __shfl(offreg, kk, 64);
          if (idx >= v) k = kk;
        }
        if (lane < cl) {  // phase A
          int t = eidp[idx];
          int ts = tdx[t], tm = tdx[NT + t];
          F3 Ps = ldp(pos, ts), Pm = ldp(pos, tm), Pd = ldp(pos, n0 + k);
          float d2 = fminf(fmaxf(norm3(sub3(Ps, Pd)), 0.05f), 10.f);
          float c[8];
          int j = rbf_coef(d2, c);
          float ang = angle_at(Ps, Pm, Pd);
          float* sp = sw + lane * 20;
          *reinterpret_cast<int4*>(sp) = int4{ts, tm, j, k};
          *reinterpret_cast<float4*>(sp + 4) = float4{c[0], c[1], c[2], c[3]};
          *reinterpret_cast<float4*>(sp + 8) = float4{c[4], c[5], c[6], c[7]};
          *reinterpret_cast<float4*>(sp + 12) = float4{ang, ang * ang, 0.f, 0.f};
        }
        // phase B (depth-2 pipeline)
        int4 I0{0, 0, 0, 0}, I1{0, 0, 0, 0};
        ushort4 g00{0, 0, 0, 0}, g10{0, 0, 0, 0}, gdd0{0, 0, 0, 0};
        ushort4 g01{0, 0, 0, 0}, g11{0, 0, 0, 0}, gdd1{0, 0, 0, 0};
        if (cl > 0) {
          I0 = *reinterpret_cast<const int4*>(sw);
          g00 = g512(p_mid2, I0.x, c4);
          g10 = g512(p_mid1, I0.y, c4);
          gdd0 = g512(p_dst, n0 + I0.w, c4);
        }
        if (cl > 1) {
          I1 = *reinterpret_cast<const int4*>(sw + 20);
          g01 = g512(p_mid2, I1.x, c4);
          g11 = g512(p_mid1, I1.y, c4);
          gdd1 = g512(p_dst, n0 + I1.w, c4);
        }
#pragma unroll 1
        for (int e = 0; e < cl; ++e) {
          int4 I2{0, 0, 0, 0};
          ushort4 g02{0, 0, 0, 0}, g12{0, 0, 0, 0}, gdd2{0, 0, 0, 0};
          if (e + 2 < cl) {
            I2 = *reinterpret_cast<const int4*>(sw + (e + 2) * 20);
            g02 = g512(p_mid2, I2.x, c4);
            g12 = g512(p_mid1, I2.y, c4);
            gdd2 = g512(p_dst, n0 + I2.w, c4);
          }
          while (kcur < I0.w) { FINALIZE(n0 + kcur, 256); ++kcur; }
          const float* sp = sw + e * 20;
          float4 cc0 = *reinterpret_cast<const float4*>(sp + 4);
          float4 cc1 = *reinterpret_cast<const float4*>(sp + 8);
          float4 f = *reinterpret_cast<const float4*>(sp + 12);
          float4 dm;
          dm.x = fmaf(f.x, wa0.x, fmaf(f.y, wa1.x, bsum.x));
          dm.y = fmaf(f.x, wa0.y, fmaf(f.y, wa1.y, bsum.y));
          dm.z = fmaf(f.x, wa0.z, fmaf(f.y, wa1.z, bsum.z));
          dm.w = fmaf(f.x, wa0.w, fmaf(f.y, wa1.w, bsum.w));
          dm = rbf_apply(Wu1 + I0.z * DM + c4, cc0, cc1, dm);
          float4 v0 = cvt4(g00), v2 = cvt4(g10), dd = cvt4(gdd0);
          float t0 = lk((v0.x + dd.x + v2.x) * dm.x);
          float t1 = lk((v0.y + dd.y + v2.y) * dm.y);
          float t2 = lk((v0.z + dd.z + v2.z) * dm.z);
          float t3 = lk((v0.w + dd.w + v2.w) * dm.w);
          float part = av.x * t0 + av.y * t1 + av.z * t2 + av.w * t3;
          part += __shfl_xor(part, 1, 64);
          part += __shfl_xor(part, 2, 64);
          part += __shfl_xor(part, 4, 64);
          float mn = fmaxf(mrun, part);
          float r = __expf(mrun - mn);
          float ew = __expf(part - mn);
          den = den * r + ew;
          acc.x = fmaf(acc.x, r, ew * v0.x);
          acc.y = fmaf(acc.y, r, ew * v0.y);
          acc.z = fmaf(acc.z, r, ew * v0.z);
          acc.w = fmaf(acc.w, r, ew * v0.w);
          mrun = mn;
          I0 = I1; g00 = g01; g10 = g11; gdd0 = gdd1;
          I1 = I2; g01 = g02; g11 = g12; gdd1 = gdd2;
        }
      }
      while (kcur < NPB2) { FINALIZE(n0 + kcur, 256); ++kcur; }
    } else {
      // ================= hop 3: 16 nodes/batch =================
      const int n0 = ((int)b - NBT1 - NBT2) * NPB3;
      const int* offp = offall + 2 * (NN + 1);
      const int* eidp = eidall + NE + NT;
      int offreg = offp[n0 + ((lane <= NPB3) ? lane : NPB3)];
      const int gs = __shfl(offreg, 0, 64);
      const int ge = __shfl(offreg, NPB3, 64);
      const float* Wu2 = fp + 152832;
      const float* Wd = fp + 164096;
      float4 av = ld4f(fp + 363776 + c4);
      float4 b1v = ld4f(fp + 163072 + c4), b2v = ld4f(fp + 165632 + c4);
      float4 bsum{b1v.x + b2v.x, b1v.y + b2v.y, b1v.z + b2v.z, b1v.w + b2v.w};
      float4 wd0 = ld4f(Wd + c4), wd1 = ld4f(Wd + DM + c4), wd2 = ld4f(Wd + 2 * DM + c4);
      float4 wd3 = ld4f(Wd + 3 * DM + c4), wd4 = ld4f(Wd + 4 * DM + c4), wd5 = ld4f(Wd + 5 * DM + c4);
      int kcur = 0;
      float mrun = -INFINITY, den = 0.f;
      float4 acc{0.f, 0.f, 0.f, 0.f};
      for (int cb = gs; cb < ge; cb += 64) {
        const int cl = (ge - cb < 64) ? (ge - cb) : 64;
        const int idx = cb + lane;
        int k = 0;
#pragma unroll
        for (int kk = 1; kk < NPB3; ++kk) {
          int v = __shfl(offreg, kk, 64);
          if (idx >= v) k = kk;
        }
        if (lane < cl) {  // phase A (k stored in int4.w; j stored in float slot)
          int q = eidp[idx];
          int qs = qdx[q], q2 = qdx[NQ + q], q1 = qdx[2 * NQ + q];
          F3 P0 = ldp(pos, qs), P1 = ldp(pos, q2), P2 = ldp(pos, q1);
          F3 Pd = ldp(pos, n0 + k);
          float d3 = fminf(fmaxf(norm3(sub3(P0, Pd)), 0.05f), 10.f);
          float c[8];
          int j = rbf_coef(d3, c);
          float a1f = angle_at(P0, P1, P2);
          float a2f = angle_at(P1, P2, Pd);
          float dh = dihedral_f(P0, P1, P2, Pd);
          float* sp = sw + lane * 20;
          *reinterpret_cast<int4*>(sp) = int4{qs, q2, q1, k};
          *reinterpret_cast<float4*>(sp + 4) = float4{c[0], c[1], c[2], c[3]};
          *reinterpret_cast<float4*>(sp + 8) = float4{c[4], c[5], c[6], c[7]};
          *reinterpret_cast<float4*>(sp + 12) = float4{a1f, a1f * a1f, a2f, a2f * a2f};
          *reinterpret_cast<float4*>(sp + 16) = float4{dh, dh * dh, __int_as_float(j), 0.f};
        }
        // phase B (depth-2 pipeline)
        int4 I0{0, 0, 0, 0}, I1{0, 0, 0, 0};
        ushort4 g00{0, 0, 0, 0}, g10{0, 0, 0, 0}, g20{0, 0, 0, 0}, gdd0{0, 0, 0, 0};
        ushort4 g01{0, 0, 0, 0}, g11{0, 0, 0, 0}, g21{0, 0, 0, 0}, gdd1{0, 0, 0, 0};
        if (cl > 0) {
          I0 = *reinterpret_cast<const int4*>(sw);
          g00 = g512(p_src, I0.x, c4);
          g10 = g512(p_mid2, I0.y, c4);
          g20 = g512(p_mid1, I0.z, c4);
          gdd0 = g512(p_dst, n0 + I0.w, c4);
        }
        if (cl > 1) {
          I1 = *reinterpret_cast<const int4*>(sw + 20);
          g01 = g512(p_src, I1.x, c4);
          g11 = g512(p_mid2, I1.y, c4);
          g21 = g512(p_mid1, I1.z, c4);
          gdd1 = g512(p_dst, n0 + I1.w, c4);
        }
#pragma unroll 1
        for (int e = 0; e < cl; ++e) {
          int4 I2{0, 0, 0, 0};
          ushort4 g02{0, 0, 0, 0}, g12{0, 0, 0, 0}, g22{0, 0, 0, 0}, gdd2{0, 0, 0, 0};
          if (e + 2 < cl) {
            I2 = *reinterpret_cast<const int4*>(sw + (e + 2) * 20);
            g02 = g512(p_src, I2.x, c4);
            g12 = g512(p_mid2, I2.y, c4);
            g22 = g512(p_mid1, I2.z, c4);
            gdd2 = g512(p_dst, n0 + I2.w, c4);
          }
          while (kcur < I0.w) { FINALIZE(n0 + kcur, 512); ++kcur; }
          const float* sp = sw + e * 20;
          float4 cc0 = *reinterpret_cast<const float4*>(sp + 4);
          float4 cc1 = *reinterpret_cast<const float4*>(sp + 8);
          float4 f = *reinterpret_cast<const float4*>(sp + 12);
          float4 fb2 = *reinterpret_cast<const float4*>(sp + 16);
          int j = __float_as_int(fb2.z);
          float4 dm;
          dm.x = bsum.x + f.x * wd0.x + f.y * wd1.x + f.z * wd2.x + f.w * wd3.x + fb2.x * wd4.x + fb2.y * wd5.x;
          dm.y = bsum.y + f.x * wd0.y + f.y * wd1.y + f.z * wd2.y + f.w * wd3.y + fb2.x * wd4.y + fb2.y * wd5.y;
          dm.z = bsum.z + f.x * wd0.z + f.y * wd1.z + f.z * wd2.z + f.w * wd3.z + fb2.x * wd4.z + fb2.y * wd5.z;
          dm.w = bsum.w + f.x * wd0.w + f.y * wd1.w + f.z * wd2.w + f.w * wd3.w + fb2.x * wd4.w + fb2.y * wd5.w;
          dm = rbf_apply(Wu2 + j * DM + c4, cc0, cc1, dm);
          float4 v0 = cvt4(g00), v1 = cvt4(g10), v2 = cvt4(g20), dd = cvt4(gdd0);
          float t0 = lk((v0.x + v1.x + v2.x + dd.x) * dm.x);
          float t1 = lk((v0.y + v1.y + v2.y + dd.y) * dm.y);
          float t2 = lk((v0.z + v1.z + v2.z + dd.z) * dm.z);
          float t3 = lk((v0.w + v1.w + v2.w + dd.w) * dm.w);
          float part = av.x * t0 + av.y * t1 + av.z * t2 + av.w * t3;
          part += __shfl_xor(part, 1, 64);
          part += __shfl_xor(part, 2, 64);
          part += __shfl_xor(part, 4, 64);
          float mn = fmaxf(mrun, part);
          float r = __expf(mrun - mn);
          float ew = __expf(part - mn);
          den = den * r + ew;
          acc.x = fmaf(acc.x, r, ew * v0.x);
          acc.y = fmaf(acc.y, r, ew * v0.y);
          acc.z = fmaf(acc.z, r, ew * v0.z);
          acc.w = fmaf(acc.w, r, ew * v0.w);
          mrun = mn;
          I0 = I1; g00 = g01; g10 = g11; g20 = g21; gdd0 = gdd1;
          I1 = I2; g01 = g02; g11 = g12; g21 = g22; gdd1 = gdd2;
        }
      }
      while (kcur < NPB3) { FINALIZE(n0 + kcur, 512); ++kcur; }
    }
  }
}

// ---- MFMA output GEMM + LayerNorm + PReLU ----
__global__ __launch_bounds__(256) void gemm_mfma_ln(
    const u16* __restrict__ Abuf, const u16* __restrict__ Xs,
    const u16* __restrict__ wswz, const float* __restrict__ fp,
    float* __restrict__ outp) {
  __shared__ float sS[4][32], sQ[4][32], sMu[32], sRs[32];
  const int tid = threadIdx.x;
  const int wid = tid >> 6, lane = tid & 63;
  const int g = lane >> 4, l15 = lane & 15;
  const int m0 = blockIdx.x * 32;
  const int cb = wid * 64;

  f32x4 acc[2][4];
#pragma unroll
  for (int nf = 0; nf < 4; ++nf) {
    int c = cb + nf * 16 + l15;
    float bs = fp[231424 + c] + fp[297216 + c] + fp[363008 + c] + fp[396800 + c];
    acc[0][nf] = f32x4{bs, bs, bs, bs};
    acc[1][nf] = f32x4{bs, bs, bs, bs};
  }
  int rr0 = m0 + l15; if (rr0 > NN - 1) rr0 = NN - 1;
  int rr1 = m0 + 16 + l15; if (rr1 > NN - 1) rr1 = NN - 1;
  const u16* a0p = Abuf + (size_t)rr0 * 768 + g * 8;
  const u16* a1p = Abuf + (size_t)rr1 * 768 + g * 8;
  const u16* x0p = Xs + (size_t)rr0 * 256 + g * 8;
  const u16* x1p = Xs + (size_t)rr1 * 256 + g * 8;
  const u16* wb = wswz + (size_t)(wid * 4 * 64 + lane) * 8;

#pragma unroll 2
  for (int ks = 0; ks < 24; ++ks) {
    bf16x8 a0 = *reinterpret_cast<const bf16x8*>(a0p + ks * 32);
    bf16x8 a1 = *reinterpret_cast<const bf16x8*>(a1p + ks * 32);
#pragma unroll
    for (int nf = 0; nf < 4; ++nf) {
      bf16x8 bh = *reinterpret_cast<const bf16x8*>(wb + (size_t)ks * 8192 + nf * 512);
      bf16x8 bl = *reinterpret_cast<const bf16x8*>(wb + (size_t)(ks + 24) * 8192 + nf * 512);
      acc[0][nf] = __builtin_amdgcn_mfma_f32_16x16x32_bf16(a0, bh, acc[0][nf], 0, 0, 0);
      acc[1][nf] = __builtin_amdgcn_mfma_f32_16x16x32_bf16(a1, bh, acc[1][nf], 0, 0, 0);
      acc[0][nf] = __builtin_amdgcn_mfma_f32_16x16x32_bf16(a0, bl, acc[0][nf], 0, 0, 0);
      acc[1][nf] = __builtin_amdgcn_mfma_f32_16x16x32_bf16(a1, bl, acc[1][nf], 0, 0, 0);
    }
  }
#pragma unroll
  for (int ks = 0; ks < 4; ++ks) {
    bf16x8 xh0 = *reinterpret_cast<const bf16x8*>(x0p + ks * 32);
    bf16x8 xh1 = *reinterpret_cast<const bf16x8*>(x1p + ks * 32);
    bf16x8 xl0 = *reinterpret_cast<const bf16x8*>(x0p + 128 + ks * 32);
    bf16x8 xl1 = *reinterpret_cast<const bf16x8*>(x1p + 128 + ks * 32);
#pragma unroll
    for (int nf = 0; nf < 4; ++nf) {
      bf16x8 bh = *reinterpret_cast<const bf16x8*>(wb + (size_t)(48 + ks) * 8192 + nf * 512);
      bf16x8 bl = *reinterpret_cast<const bf16x8*>(wb + (size_t)(52 + ks) * 8192 + nf * 512);
      acc[0][nf] = __builtin_amdgcn_mfma_f32_16x16x32_bf16(xh0, bh, acc[0][nf], 0, 0, 0);
      acc[1][nf] = __builtin_amdgcn_mfma_f32_16x16x32_bf16(xh1, bh, acc[1][nf], 0, 0, 0);
      acc[0][nf] = __builtin_amdgcn_mfma_f32_16x16x32_bf16(xh0, bl, acc[0][nf], 0, 0, 0);
      acc[1][nf] = __builtin_amdgcn_mfma_f32_16x16x32_bf16(xh1, bl, acc[1][nf], 0, 0, 0);
      acc[0][nf] = __builtin_amdgcn_mfma_f32_16x16x32_bf16(xl0, bh, acc[0][nf], 0, 0, 0);
      acc[1][nf] = __builtin_amdgcn_mfma_f32_16x16x32_bf16(xl1, bh, acc[1][nf], 0, 0, 0);
    }
  }

#pragma unroll
  for (int mf = 0; mf < 2; ++mf) {
#pragma unroll
    for (int reg = 0; reg < 4; ++reg) {
      float sp = acc[mf][0][reg] + acc[mf][1][reg] + acc[mf][2][reg] + acc[mf][3][reg];
      float qp = acc[mf][0][reg] * acc[mf][0][reg] + acc[mf][1][reg] * acc[mf][1][reg] +
                 acc[mf][2][reg] * acc[mf][2][reg] + acc[mf][3][reg] * acc[mf][3][reg];
      for (int m = 8; m; m >>= 1) {
        sp += __shfl_xor(sp, m, 64);
        qp += __shfl_xor(qp, m, 64);
      }
      if (l15 == 0) {
        sS[wid][mf * 16 + g * 4 + reg] = sp;
        sQ[wid][mf * 16 + g * 4 + reg] = qp;
      }
    }
  }
  __syncthreads();
  if (tid < 32) {
    float S = sS[0][tid] + sS[1][tid] + sS[2][tid] + sS[3][tid];
    float Q = sQ[0][tid] + sQ[1][tid] + sQ[2][tid] + sQ[3][tid];
    float mu = S * (1.f / 256.f);
    float var = fmaxf(Q * (1.f / 256.f) - mu * mu, 0.f);
    sMu[tid] = mu;
    sRs[tid] = rsqrtf(var + 1e-5f);
  }
  __syncthreads();
  float pw = fp[397568];
#pragma unroll
  for (int nf = 0; nf < 4; ++nf) {
    int c = cb + nf * 16 + l15;
    float gc = fp[397056 + c], bc = fp[397312 + c];
#pragma unroll
    for (int mf = 0; mf < 2; ++mf) {
#pragma unroll
      for (int reg = 0; reg < 4; ++reg) {
        int rl = mf * 16 + g * 4 + reg;
        int row = m0 + rl;
        if (row < NN) {
          float y = (acc[mf][nf][reg] - sMu[rl]) * sRs[rl] * gc + bc;
          outp[(size_t)row * 256 + c] = (y >= 0.f) ? y : pw * y;
        }
      }
    }
  }
}

extern "C" void kernel_launch(void* const* d_in, const int* in_sizes, int n_in,
                              void* d_out, int out_size, void* d_ws, size_t ws_size,
                              hipStream_t stream) {
  const void* x = d_in[0];
  const void* pos = d_in[1];
  const int* eidx = (const int*)d_in[2];
  const int* tdx = (const int*)d_in[3];
  const int* qdx = (const int*)d_in[4];
  const void* eattr = d_in[5];
  float* outp = (float*)d_out;

  // workspace layout (~214 MB; proven safe <= ~221 MB)
  u16* p_src = (u16*)d_ws;
  u16* p_mid2 = p_src + (size_t)NN * DM;
  u16* p_mid1 = p_mid2 + (size_t)NN * DM;
  u16* p_dst = p_mid1 + (size_t)NN * DM;
  u16* Abuf = p_dst + (size_t)NN * DM;                // NN x 768 bf16 (A1|A2|A3)
  u16* Xs = Abuf + (size_t)NN * 768;                  // NN x 256 bf16 (xhi|xlo)
  float* posf = (float*)(Xs + (size_t)NN * 256);      // NN*3
  float* fp = posf + (size_t)NN * 3;                  // staged params
  u16* wswz = (u16*)(fp + TOTALP + 3);                // out-GEMM swizzled W
  u16* pswz = wswz + WSWZ_N;                          // proj swizzled W
  int* deg = (int*)(pswz + PSWZ_N);                   // 3*NN
  int* off = deg + 3 * NN;                            // 3*(NN+1)
  int* cur = off + 3 * (NN + 1);                      // 3*NN
  int* eid = cur + 3 * NN;                            // NE+NT+NQ
  u32* gmax = (u32*)(eid + NE + NT + NQ);
  int* flags = (int*)(gmax + 4);

  init_detect<<<1, 256, 0, stream>>>((const u32*)eattr, (const u32*)d_in[33], gmax, flags);

  PtrTab tab;
  for (int i = 0; i < 30; ++i) tab.p[i] = d_in[6 + i];
  convert_params<<<512, 256, 0, stream>>>(tab, flags, fp);
  convert_pos<<<587, 256, 0, stream>>>(pos, flags, posf);
  swizzle_w<<<WSWZ_N / 256, 256, 0, stream>>>(fp, wswz);
  swizzle_pw<<<PSWZ_N / 256, 256, 0, stream>>>(fp, pswz);

  // x hi/lo split (dedicated buffer; feeds both proj_mfma and gemm_mfma_ln)
  xsplit<<<2048, 256, 0, stream>>>(x, flags, Xs);

  // MFMA 4-way projection + PE
  proj_mfma<<<(NN + 31) / 32, 256, 0, stream>>>(Xs, pswz, p_src, p_mid2, p_mid1, p_dst);

  // CSR for all 3 hops
  hipMemsetAsync(deg, 0, (size_t)3 * NN * 4, stream);
  hist_all<<<1024, 256, 0, stream>>>(eidx + NE, tdx + 2 * NT, qdx + 3 * NQ, deg);
  scan_all<<<3, 1024, 0, stream>>>(deg, off, cur);
  fill_all<<<1024, 256, 0, stream>>>(eidx + NE, tdx + 2 * NT, qdx + 3 * NQ, cur, eid);

  // fused score + per-node softmax + aggregate (4-wave workgroups, VGPR free)
  fused_score_agg<<<2048, 256, 0, stream>>>(posf, eidx, tdx, qdx, eattr, flags,
                                            p_src, p_mid2, p_mid1, p_dst, fp,
                                            off, eid, gmax, Abuf);

  // MFMA output GEMM + LN + PReLU
  gemm_mfma_ln<<<(NN + 31) / 32, 256, 0, stream>>>(Abuf, Xs, wswz, fp, outp);
}